// Round 1
// 1270.863 us; speedup vs baseline: 1.0590x; 1.0590x over previous
//
#include <hip/hip_runtime.h>
#include <float.h>
#include <math.h>

// Problem constants
#define BB 256
#define DD 512
#define NN 50000
#define KK 32
#define NS_ITERS 11
#define PARTS 8
#define PCH 6250

// Workspace layout (float offsets)
#define OFF_G     0         // 1M-float region: UUT(65536) + TcTc(65536) + w(256) + m(50000); NS Pm reuses +0
#define OFF_SC    262144    // 64 scalars: 0=sumTc2 1=trCX 2=S_total 3=knn 4=wreg 5=s_ns
#define OFF_CS    262208    // 512 colsum X
#define OFF_CSS   262720    // 512 colsumsq X
#define ZERO_F    263232    // floats to memset
#define OFF_T     263232    // 256*512
#define OFF_TC    394304    // 256*512 Tc; later NS Y/Z
#define OFF_P     525376    // 256*512: top-k cand buffers; later NS Y2/Z2
#define OFF_H     656448    // 256*256
#define OFF_MUT   722496    // 512
#define OFF_XSQ   723008    // 50000
#define OFF_RUNI  781200    // 256*32 (int)
#define OFF_PW    789392    // 256*32 post_w
#define OFF_PRW   797584    // 256*32 pre_w normalized
#define OFF_D2    805776    // V = T@X^T  (256*50000)

#define OFF_UUT   (OFF_G)
#define OFF_TCTC  (OFF_G + 65536)
#define OFF_W     (OFF_G + 131072)
#define OFF_M     (OFF_G + 131328)

typedef __attribute__((ext_vector_type(8))) short bf16x8;
typedef __attribute__((ext_vector_type(4))) float f32x4;

__device__ __forceinline__ float waveSum(float v) {
#pragma unroll
  for (int off = 32; off > 0; off >>= 1) v += __shfl_xor(v, off);
  return v;
}

// split fp32x4 -> bf16 hi/lo, write packed pairs to LDS at short-offset sa (16B-aligned rows)
__device__ __forceinline__ void cvt_write(float4 v, unsigned short* hi, unsigned short* lo, int sa) {
  unsigned int b0 = __float_as_uint(v.x), b1 = __float_as_uint(v.y);
  unsigned int b2 = __float_as_uint(v.z), b3 = __float_as_uint(v.w);
  unsigned int h0 = b0 & 0xffff0000u, h1 = b1 & 0xffff0000u;
  unsigned int h2 = b2 & 0xffff0000u, h3 = b3 & 0xffff0000u;
  float l0 = v.x - __uint_as_float(h0), l1 = v.y - __uint_as_float(h1);
  float l2 = v.z - __uint_as_float(h2), l3 = v.w - __uint_as_float(h3);
  *(unsigned int*)&hi[sa]     = (h0 >> 16) | h1;
  *(unsigned int*)&hi[sa + 2] = (h2 >> 16) | h3;
  *(unsigned int*)&lo[sa]     = (__float_as_uint(l0) >> 16) | (__float_as_uint(l1) & 0xffff0000u);
  *(unsigned int*)&lo[sa + 2] = (__float_as_uint(l2) >> 16) | (__float_as_uint(l3) & 0xffff0000u);
}

// ---------------- generic 64x64-tile GEMM, C = scale * A @ B (nn) ----------------
__global__ void __launch_bounds__(256) k_g64_nn(const float* __restrict__ A,
                                                const float* __restrict__ B,
                                                float* __restrict__ C,
                                                int K, int lda, int ldb, int ldc, float scale) {
  __shared__ float As[64][65], Bs[64][65];
  int m0 = blockIdx.y * 64, n0 = blockIdx.x * 64;
  int t = threadIdx.x, tr = t >> 4, tc = t & 15;
  float acc[4][4] = {{0.f}};
  for (int k0 = 0; k0 < K; k0 += 64) {
#pragma unroll
    for (int p = 0; p < 16; ++p) {
      int l = t + 256 * p;
      int r = l >> 6, c = l & 63;
      As[r][c] = A[(m0 + r) * lda + k0 + c];
      Bs[r][c] = B[(k0 + r) * ldb + n0 + c];
    }
    __syncthreads();
#pragma unroll 16
    for (int kk = 0; kk < 64; ++kk) {
      float a[4], b[4];
#pragma unroll
      for (int u = 0; u < 4; ++u) a[u] = As[tr + 16 * u][kk];
#pragma unroll
      for (int v = 0; v < 4; ++v) b[v] = Bs[kk][tc + 16 * v];
#pragma unroll
      for (int u = 0; u < 4; ++u)
#pragma unroll
        for (int v = 0; v < 4; ++v) acc[u][v] += a[u] * b[v];
    }
    __syncthreads();
  }
#pragma unroll
  for (int u = 0; u < 4; ++u)
#pragma unroll
    for (int v = 0; v < 4; ++v)
      C[(m0 + tr + 16 * u) * ldc + n0 + tc + 16 * v] = acc[u][v] * scale;
}

// ---------------- generic 64x64-tile GEMM, C = scale * A @ B^T (nt) ----------------
__global__ void __launch_bounds__(256) k_g64_nt(const float* __restrict__ A,
                                                const float* __restrict__ B,
                                                float* __restrict__ C,
                                                int K, int lda, int ldb, int ldc, float scale) {
  __shared__ float As[64][65], Bs[64][65];
  int m0 = blockIdx.y * 64, n0 = blockIdx.x * 64;
  int t = threadIdx.x, tr = t >> 4, tc = t & 15;
  float acc[4][4] = {{0.f}};
  for (int k0 = 0; k0 < K; k0 += 64) {
#pragma unroll
    for (int p = 0; p < 16; ++p) {
      int l = t + 256 * p;
      int r = l >> 6, c = l & 63;
      As[r][c] = A[(m0 + r) * lda + k0 + c];
      Bs[r][c] = B[(n0 + r) * ldb + k0 + c];
    }
    __syncthreads();
#pragma unroll 16
    for (int kk = 0; kk < 64; ++kk) {
      float a[4], b[4];
#pragma unroll
      for (int u = 0; u < 4; ++u) a[u] = As[tr + 16 * u][kk];
#pragma unroll
      for (int v = 0; v < 4; ++v) b[v] = Bs[tc + 16 * v][kk];
#pragma unroll
      for (int u = 0; u < 4; ++u)
#pragma unroll
        for (int v = 0; v < 4; ++v) acc[u][v] += a[u] * b[v];
    }
    __syncthreads();
  }
#pragma unroll
  for (int u = 0; u < 4; ++u)
#pragma unroll
    for (int v = 0; v < 4; ++v)
      C[(m0 + tr + 16 * u) * ldc + n0 + tc + 16 * v] = acc[u][v] * scale;
}

// ---------------- V = T @ X^T  (MFMA bf16-split, on-the-fly conversion) ----------------
__global__ void __launch_bounds__(256) k_vgemm(const float* __restrict__ T,
                                               const float* __restrict__ X,
                                               float* __restrict__ V) {
  __shared__ unsigned short Ah[128 * 72], Al[128 * 72], Bh[128 * 72], Bl[128 * 72];
  int bj = blockIdx.x, bi = blockIdx.y;
  int t = threadIdx.x;
  int wave = t >> 6, lane = t & 63;
  int m0 = (wave >> 1) * 64, n0 = (wave & 1) * 64;
  int lrow = lane & 15, lq = lane >> 4;
  f32x4 acc[4][4] = {};
  for (int kc = 0; kc < 512; kc += 64) {
#pragma unroll
    for (int f = 0; f < 8; ++f) {
      int lin = f * 256 + t;
      int r = lin >> 4, c4 = lin & 15;
      int sa = r * 72 + c4 * 4;
      float4 va = *(const float4*)&T[(bi * 128 + r) * 512 + kc + c4 * 4];
      cvt_write(va, Ah, Al, sa);
      int jg = bj * 128 + r;
      float4 vb = {0.f, 0.f, 0.f, 0.f};
      if (jg < NN) vb = *(const float4*)&X[(size_t)jg * 512 + kc + c4 * 4];
      cvt_write(vb, Bh, Bl, sa);
    }
    __syncthreads();
#pragma unroll
    for (int ks = 0; ks < 2; ++ks) {
      int kb = ks * 32 + lq * 8;
      bf16x8 ah[4], al[4], bh[4], bl[4];
#pragma unroll
      for (int mi = 0; mi < 4; ++mi) {
        int ro = (m0 + mi * 16 + lrow) * 72 + kb;
        ah[mi] = *(const bf16x8*)&Ah[ro];
        al[mi] = *(const bf16x8*)&Al[ro];
      }
#pragma unroll
      for (int nj = 0; nj < 4; ++nj) {
        int ro = (n0 + nj * 16 + lrow) * 72 + kb;
        bh[nj] = *(const bf16x8*)&Bh[ro];
        bl[nj] = *(const bf16x8*)&Bl[ro];
      }
#pragma unroll
      for (int mi = 0; mi < 4; ++mi)
#pragma unroll
        for (int nj = 0; nj < 4; ++nj) {
          acc[mi][nj] = __builtin_amdgcn_mfma_f32_16x16x32_bf16(ah[mi], bh[nj], acc[mi][nj], 0, 0, 0);
          acc[mi][nj] = __builtin_amdgcn_mfma_f32_16x16x32_bf16(ah[mi], bl[nj], acc[mi][nj], 0, 0, 0);
          acc[mi][nj] = __builtin_amdgcn_mfma_f32_16x16x32_bf16(al[mi], bh[nj], acc[mi][nj], 0, 0, 0);
        }
    }
    __syncthreads();
  }
#pragma unroll
  for (int mi = 0; mi < 4; ++mi)
#pragma unroll
    for (int nj = 0; nj < 4; ++nj)
#pragma unroll
      for (int r = 0; r < 4; ++r) {
        int row = bi * 128 + m0 + mi * 16 + lq * 4 + r;
        int col = bj * 128 + n0 + nj * 16 + lrow;
        if (col < NN) V[(size_t)row * NN + col] = acc[mi][nj][r];
      }
}

// ---------------- UUT += U @ U^T, U = V - m (MFMA bf16-split, split-K atomic) ----------------
__global__ void __launch_bounds__(256) k_uut(const float* __restrict__ V,
                                             const float* __restrict__ m,
                                             float* __restrict__ UUT) {
  __shared__ unsigned short Ah[128 * 72], Al[128 * 72], Bh[128 * 72], Bl[128 * 72];
  const int pi_[3] = {0, 0, 1}, pj_[3] = {0, 1, 1};
  int bi = pi_[blockIdx.x], bj = pj_[blockIdx.x];
  int j0 = blockIdx.y * 1000, jlim = j0 + 1000;
  int t = threadIdx.x;
  int wave = t >> 6, lane = t & 63;
  int m0 = (wave >> 1) * 64, n0 = (wave & 1) * 64;
  int lrow = lane & 15, lq = lane >> 4;
  f32x4 acc[4][4] = {};
  for (int ch = 0; ch < 16; ++ch) {
    int jc = j0 + ch * 64;
#pragma unroll
    for (int f = 0; f < 8; ++f) {
      int lin = f * 256 + t;
      int r = lin >> 4, c4 = lin & 15;
      int sa = r * 72 + c4 * 4;
      int jb = jc + c4 * 4;
      float4 va = {0.f, 0.f, 0.f, 0.f}, vb = {0.f, 0.f, 0.f, 0.f};
      if (jb < jlim) {
        float4 mm = *(const float4*)&m[jb];
        va = *(const float4*)&V[(size_t)(bi * 128 + r) * NN + jb];
        vb = *(const float4*)&V[(size_t)(bj * 128 + r) * NN + jb];
        va.x -= mm.x; va.y -= mm.y; va.z -= mm.z; va.w -= mm.w;
        vb.x -= mm.x; vb.y -= mm.y; vb.z -= mm.z; vb.w -= mm.w;
      }
      cvt_write(va, Ah, Al, sa);
      cvt_write(vb, Bh, Bl, sa);
    }
    __syncthreads();
#pragma unroll
    for (int ks = 0; ks < 2; ++ks) {
      int kb = ks * 32 + lq * 8;
      bf16x8 ah[4], al[4], bh[4], bl[4];
#pragma unroll
      for (int mi = 0; mi < 4; ++mi) {
        int ro = (m0 + mi * 16 + lrow) * 72 + kb;
        ah[mi] = *(const bf16x8*)&Ah[ro];
        al[mi] = *(const bf16x8*)&Al[ro];
      }
#pragma unroll
      for (int nj = 0; nj < 4; ++nj) {
        int ro = (n0 + nj * 16 + lrow) * 72 + kb;
        bh[nj] = *(const bf16x8*)&Bh[ro];
        bl[nj] = *(const bf16x8*)&Bl[ro];
      }
#pragma unroll
      for (int mi = 0; mi < 4; ++mi)
#pragma unroll
        for (int nj = 0; nj < 4; ++nj) {
          acc[mi][nj] = __builtin_amdgcn_mfma_f32_16x16x32_bf16(ah[mi], bh[nj], acc[mi][nj], 0, 0, 0);
          acc[mi][nj] = __builtin_amdgcn_mfma_f32_16x16x32_bf16(ah[mi], bl[nj], acc[mi][nj], 0, 0, 0);
          acc[mi][nj] = __builtin_amdgcn_mfma_f32_16x16x32_bf16(al[mi], bh[nj], acc[mi][nj], 0, 0, 0);
        }
    }
    __syncthreads();
  }
#pragma unroll
  for (int mi = 0; mi < 4; ++mi)
#pragma unroll
    for (int nj = 0; nj < 4; ++nj)
#pragma unroll
      for (int r = 0; r < 4; ++r) {
        int row = bi * 128 + m0 + mi * 16 + lq * 4 + r;
        int col = bj * 128 + n0 + nj * 16 + lrow;
        atomicAdd(&UUT[row * 256 + col], acc[mi][nj][r]);
      }
}

// ---------------- column sums & sumsq of X (atomic) ----------------
__global__ void k_colstatX(const float* __restrict__ X, float* __restrict__ colsum,
                           float* __restrict__ colss) {
  int b = blockIdx.x, t = threadIdx.x;
  int r0 = b * 196;
  int r1 = r0 + 196; if (r1 > NN) r1 = NN;
  float s1 = 0, ss1 = 0, s2 = 0, ss2 = 0;
  for (int r = r0; r < r1; ++r) {
    float v1 = X[(size_t)r * 512 + t], v2 = X[(size_t)r * 512 + t + 256];
    s1 += v1; ss1 += v1 * v1; s2 += v2; ss2 += v2 * v2;
  }
  atomicAdd(&colsum[t], s1);       atomicAdd(&colss[t], ss1);
  atomicAdd(&colsum[t + 256], s2); atomicAdd(&colss[t + 256], ss2);
}

// ---------------- per-row squared norm of X ----------------
__global__ void k_xsq(const float* __restrict__ X, float* __restrict__ xsq) {
  int row = blockIdx.x * 4 + (threadIdx.x >> 6);
  int lane = threadIdx.x & 63;
  const float* Xr = X + (size_t)row * 512;
  float s = 0.f;
#pragma unroll
  for (int d = 0; d < 8; ++d) { float v = Xr[lane + 64 * d]; s += v * v; }
  s = waveSum(s);
  if (lane == 0) xsq[row] = s;
}

// ---------------- column means of T ----------------
__global__ void k_colmeanT(const float* __restrict__ T, float* __restrict__ mu) {
  int c = threadIdx.x;
  float s = 0.f;
  for (int r = 0; r < 256; ++r) s += T[r * 512 + c];
  mu[c] = s * (1.0f / 256.0f);
}

// ---------------- Tc = T - mu, accumulate sum(Tc^2) ----------------
__global__ void k_centerT(const float* __restrict__ T, const float* __restrict__ mu,
                          float* __restrict__ Tc, float* __restrict__ scal) {
  __shared__ float red[4];
  int t = threadIdx.x;
  int base = blockIdx.x * 1024;
  float ss = 0.f;
#pragma unroll
  for (int p = 0; p < 4; ++p) {
    int l = base + p * 256 + t;
    float v = T[l] - mu[l & 511];
    Tc[l] = v;
    ss += v * v;
  }
  ss = waveSum(ss);
  if ((t & 63) == 0) red[t >> 6] = ss;
  __syncthreads();
  if (t == 0) atomicAdd(&scal[0], red[0] + red[1] + red[2] + red[3]);
}

// ---------------- trace of cov(X) ----------------
__global__ void k_trCX(const float* __restrict__ colsum, const float* __restrict__ colss,
                       float* __restrict__ scal) {
  __shared__ float red[8];
  int t = threadIdx.x;  // 512
  float mu = colsum[t] * (1.0f / 50000.0f);
  float v = (colss[t] - 50000.0f * mu * mu) * (1.0f / 49999.0f);
  v = waveSum(v);
  if ((t & 63) == 0) red[t >> 6] = v;
  __syncthreads();
  if (t == 0) {
    float s = 0;
    for (int i = 0; i < 8; ++i) s += red[i];
    scal[1] = s;
  }
}

// ---------------- colmeans of V -> m ----------------
__global__ void k_vstats(const float* __restrict__ V, float* __restrict__ m) {
  int j = blockIdx.x * 256 + threadIdx.x;
  if (j >= NN) return;
  float s = 0.f;
  for (int i = 0; i < 256; ++i) s += V[(size_t)i * NN + j];
  m[j] = s * (1.0f / 256.0f);
}

// ---------------- w_i = Tc_i . muX ----------------
__global__ void __launch_bounds__(256) k_wvec(const float* __restrict__ T,
                                              const float* __restrict__ colsum,
                                              float* __restrict__ w) {
  __shared__ float cs[512];
  __shared__ float red[4];
  int t = threadIdx.x;
  cs[t] = colsum[t] * (1.0f / 50000.0f);
  cs[t + 256] = colsum[t + 256] * (1.0f / 50000.0f);
  __syncthreads();
  float a = 0.f;
  for (int c = 0; c < 512; ++c) a += T[t * 512 + c] * cs[c];
  float s = waveSum(a);
  if ((t & 63) == 0) red[t >> 6] = s;
  __syncthreads();
  float mean = (red[0] + red[1] + red[2] + red[3]) * (1.0f / 256.0f);
  w[t] = a - mean;
}

// ---------------- H = (UUT - N w w^T)/(49999*255) + rhoX * TcTc/255 ----------------
__global__ void k_hfix(const float* __restrict__ UUT, const float* __restrict__ TcTc,
                       const float* __restrict__ w, const float* __restrict__ scal,
                       float* __restrict__ H) {
  int l = blockIdx.x * 256 + threadIdx.x;
  int i = l >> 8, j = l & 255;
  float u = (i >= 128 && j < 128) ? UUT[j * 256 + i] : UUT[i * 256 + j];
  float rho = scal[1] * (1e-3f / 512.0f);
  H[l] = (u - 50000.0f * w[i] * w[j]) * (1.0f / (49999.0f * 255.0f))
       + rho * TcTc[i * 256 + j] * (1.0f / 255.0f);
}

// ---------------- power iteration: scal[5] = safe lambda_max bound of H' ----------------
__global__ void __launch_bounds__(256) k_power(const float* __restrict__ H,
                                               float* __restrict__ scal) {
  __shared__ float v[256], nv[256], red[4];
  int t = threadIdx.x;
  float rt = scal[0] * (1.0f / 255.0f) * (1e-3f / 512.0f);
  v[t] = 1.0f;
  __syncthreads();
  float n2 = 256.0f, n3 = 256.0f;
  for (int it = 0; it < 3; ++it) {
    float s = rt * v[t];
    for (int j = 0; j < 256; ++j) s += H[t * 256 + j] * v[j];
    nv[t] = s;
    float ss = waveSum(s * s);
    if ((t & 63) == 0) red[t >> 6] = ss;
    __syncthreads();
    float norm2 = red[0] + red[1] + red[2] + red[3];
    if (it == 1) n2 = norm2;
    if (it == 2) n3 = norm2;
    v[t] = nv[t];
    __syncthreads();
  }
  float d = H[t * 256 + t] + rt;
#pragma unroll
  for (int off = 32; off > 0; off >>= 1) d = fmaxf(d, __shfl_xor(d, off));
  if ((t & 63) == 0) red[t >> 6] = d;
  __syncthreads();
  if (t == 0) {
    float lam = sqrtf(n3 / n2);
    float md = fmaxf(fmaxf(red[0], red[1]), fmaxf(red[2], red[3]));
    scal[5] = fmaxf(1.3f * lam, md);
  }
}

// ---------------- Y0 = (H + rt I)/s, Z0 = I ----------------
__global__ void k_nsinit(const float* __restrict__ H, const float* __restrict__ scal,
                         float* __restrict__ Y, float* __restrict__ Z) {
  int l = blockIdx.x * 256 + threadIdx.x;
  int i = l >> 8, j = l & 255;
  float rt = scal[0] * (1.0f / 255.0f) * (1e-3f / 512.0f);
  float inv = 1.0f / scal[5];
  Y[l] = (H[l] + ((i == j) ? rt : 0.f)) * inv;
  Z[l] = (i == j) ? 1.0f : 0.f;
}

// ---------------- NS update ----------------
__global__ void __launch_bounds__(256) k_ns_upd(const float* __restrict__ Y, const float* __restrict__ Z,
                                                const float* __restrict__ P,
                                                float* __restrict__ Yn, float* __restrict__ Zn) {
  __shared__ float As[64][65], Bs[64][65];
  int bi = blockIdx.x, bj = blockIdx.y, zz = blockIdx.z;
  const float* A = zz ? P : Y;
  const float* B = zz ? Z : P;
  const float* D = zz ? Z : Y;
  float* O = zz ? Zn : Yn;
  int t = threadIdx.x;
  int tr = t >> 4, tc = t & 15;
  float acc[4][4] = {{0.f}};
  for (int k0 = 0; k0 < 256; k0 += 64) {
#pragma unroll
    for (int p = 0; p < 16; ++p) {
      int l = t + 256 * p;
      int r = l >> 6, c = l & 63;
      As[r][c] = A[(bi * 64 + r) * 256 + k0 + c];
      Bs[r][c] = B[(k0 + r) * 256 + bj * 64 + c];
    }
    __syncthreads();
#pragma unroll 16
    for (int kk = 0; kk < 64; ++kk) {
      float a[4], b[4];
#pragma unroll
      for (int u = 0; u < 4; ++u) a[u] = As[tr + 16 * u][kk];
#pragma unroll
      for (int v = 0; v < 4; ++v) b[v] = Bs[kk][tc + 16 * v];
#pragma unroll
      for (int u = 0; u < 4; ++u)
#pragma unroll
        for (int v = 0; v < 4; ++v) acc[u][v] += a[u] * b[v];
    }
    __syncthreads();
  }
#pragma unroll
  for (int u = 0; u < 4; ++u)
#pragma unroll
    for (int v = 0; v < 4; ++v) {
      int idx = (bi * 64 + tr + 16 * u) * 256 + bj * 64 + tc + 16 * v;
      O[idx] = 1.5f * D[idx] - 0.5f * acc[u][v];
    }
}

// ---------------- S_total = sqrt(s)*tr(Y) + 256*sqrt(rt) ----------------
__global__ void k_ns_trace(const float* __restrict__ Y, float* __restrict__ scal) {
  __shared__ float red[4];
  int t = threadIdx.x;  // 256
  float v = Y[t * 256 + t];
  v = waveSum(v);
  if ((t & 63) == 0) red[t >> 6] = v;
  __syncthreads();
  if (t == 0) {
    float tr = red[0] + red[1] + red[2] + red[3];
    float rt = scal[0] * (1.0f / 255.0f) * (1e-3f / 512.0f);
    scal[2] = sqrtf(scal[5]) * tr + 256.0f * sqrtf(rt);
  }
}

// ---------------- stage 1: threshold-filter exact top-32 per (query, 1/8-slice) ----------------
// 256 threads; LDS candidate buffer (512) + running (tau_v, tau_i) = 32nd-best-so-far.
__global__ void __launch_bounds__(256) k_topk_part(const float* __restrict__ V,
                                                   const float* __restrict__ xsq,
                                                   float* __restrict__ candv,
                                                   int* __restrict__ candi) {
  __shared__ float bufv[512];
  __shared__ int bufi[512];
  __shared__ int lcount;
  __shared__ float tvs;
  __shared__ int tis;
  int part = blockIdx.x, q = blockIdx.y, t = threadIdx.x;
  int base = part * PCH;
  int lane = t & 63;
  if (t == 0) { lcount = 0; tvs = FLT_MAX; tis = 0x7fffffff; }
  __syncthreads();
  const float* rowV = V + (size_t)q * NN + base;
  const float* xs = xsq + base;

  auto flush = [&]() {
    __syncthreads();
    int c = lcount;
    for (int s = c + t; s < 512; s += 256) { bufv[s] = FLT_MAX; bufi[s] = 0x7fffffff; }
    __syncthreads();
    for (int ssz = 2; ssz <= 512; ssz <<= 1) {
      for (int st = ssz >> 1; st > 0; st >>= 1) {
        int i = 2 * t - (t & (st - 1));
        int j = i + st;
        bool up = ((i & ssz) == 0);
        float a = bufv[i], b = bufv[j];
        int ai = bufi[i], bi2 = bufi[j];
        bool agtb = (a > b) || (a == b && ai > bi2);
        if (agtb == up) { bufv[i] = b; bufv[j] = a; bufi[i] = bi2; bufi[j] = ai; }
        __syncthreads();
      }
    }
    if (t == 0) { lcount = 32; tvs = bufv[31]; tis = bufi[31]; }
    __syncthreads();
  };

  int ntile = (PCH + 255) >> 8;
  for (int tile = 0; tile < ntile; ++tile) {
    int j = tile * 256 + t;
    float val = 0.f; int idx = 0;
    bool pred = false;
    if (j < PCH) {
      val = xs[j] - 2.0f * rowV[j];
      idx = base + j;
      float tv = tvs; int ti = tis;
      pred = (val < tv) || (val == tv && idx < ti);
    }
    unsigned long long mask = __ballot(pred);
    if (mask) {
      int lead = __ffsll((unsigned long long)mask) - 1;
      int cnt = __popcll(mask);
      int basep = 0;
      if (lane == lead) basep = atomicAdd(&lcount, cnt);
      basep = __shfl(basep, lead);
      if (pred) {
        int off = __popcll(mask & ((1ull << lane) - 1ull));
        int slot = basep + off;
        bufv[slot] = val; bufi[slot] = idx;
      }
    }
    __syncthreads();
    if (lcount >= 256) flush();
  }
  flush();
  if (t < 32) {
    candv[(q * PARTS + part) * 32 + t] = bufv[t];
    candi[(q * PARTS + part) * 32 + t] = bufi[t];
  }
}

// ---------------- stage 2: bitonic-sort 256 candidates, emit top-32 indices ----------------
__global__ void __launch_bounds__(128) k_topk_final(const float* __restrict__ candv,
                                                    const int* __restrict__ candi,
                                                    int* __restrict__ runi) {
  __shared__ float v[256];
  __shared__ int ix[256];
  int q = blockIdx.x, t = threadIdx.x;
  v[t] = candv[q * 256 + t];
  v[t + 128] = candv[q * 256 + t + 128];
  ix[t] = candi[q * 256 + t];
  ix[t + 128] = candi[q * 256 + t + 128];
  __syncthreads();
  for (int ssz = 2; ssz <= 256; ssz <<= 1) {
    for (int st = ssz >> 1; st > 0; st >>= 1) {
      int i = 2 * t - (t & (st - 1));
      int j = i + st;
      bool up = ((i & ssz) == 0);
      float a = v[i], b = v[j];
      int ai = ix[i], bi = ix[j];
      bool agtb = (a > b) || (a == b && ai > bi);
      if (agtb == up) { v[i] = b; v[j] = a; ix[i] = bi; ix[j] = ai; }
      __syncthreads();
    }
  }
  if (t < 32) runi[q * 32 + t] = ix[t];
}

// ---------------- l2 to neighbors, softmax post_w, normalized pre_w ----------------
__global__ void __launch_bounds__(64) k_l2soft(const float* __restrict__ T, const float* __restrict__ X,
                                               const int* __restrict__ runi, const int* __restrict__ qidx,
                                               const float* __restrict__ prew, float* __restrict__ postw,
                                               float* __restrict__ prewn) {
  __shared__ float l2s[32];
  int b = blockIdx.x, lane = threadIdx.x;
  int qi = qidx[b];
  float pwv = (lane < 32) ? fmaxf(prew[qi * 32 + lane], 1e-8f) : 0.f;
  float psum = waveSum(pwv);
  if (lane < 32) prewn[b * 32 + lane] = pwv / psum;
  const float* Tb = T + b * 512;
  for (int n = 0; n < 32; ++n) {
    int nb = runi[b * 32 + n];
    const float* Xr = X + (size_t)nb * 512;
    float acc = 0.f;
#pragma unroll
    for (int d = 0; d < 8; ++d) {
      float df = Tb[lane + 64 * d] - Xr[lane + 64 * d];
      acc += df * df;
    }
    acc = waveSum(acc);
    if (lane == 0) l2s[n] = acc;
  }
  __syncthreads();
  float lg = (lane < 32) ? (-l2s[lane] * 10.0f) : -FLT_MAX;
  float mx = lg;
#pragma unroll
  for (int off = 32; off > 0; off >>= 1) mx = fmaxf(mx, __shfl_xor(mx, off));
  float e = (lane < 32) ? expf(lg - mx) : 0.f;
  float es = waveSum(e);
  float wv = e / es;
  wv = fmaxf(wv, 1e-8f);
  float ws2 = (lane < 32) ? wv : 0.f;
  ws2 = waveSum(ws2);
  if (lane < 32) postw[b * 32 + lane] = wv / ws2;
}

// ---------------- fused per-batch: Gram -> C -> median -> Sinkhorn(200) -> loss ----------------
// Sinkhorn exploits p mass only on slots [0,32) and q mass only on [32,64):
// u[32:] == 0 and v[:32] == 0 exactly after step 0, so the iteration collapses to the
// 32x32 block Kt = K[0:32,32:64]. Wave 0 runs the entire 200-iter chain in registers
// (row + column of Kt per lane, u/v one-per-lane, __shfl broadcasts) with ZERO barriers.
// Median: C symmetric with zero diagonal -> median(4096) = 0.5*(U[991]+U[992]) where
// U = ascending-sorted 2016 upper-triangle values (sort 2048 instead of 4096).
__global__ void __launch_bounds__(256) k_batch(const float* __restrict__ X, const int* __restrict__ qidx,
                                               const int* __restrict__ pre_idx, const int* __restrict__ runi,
                                               const float* __restrict__ prewn, const float* __restrict__ postw,
                                               float* __restrict__ scal) {
  __shared__ float G[64][65];
  __shared__ float Cm[64][65];
  __shared__ float SB[4160];
  __shared__ int supp[64];
  __shared__ float uuS[32], vvS[32];
  __shared__ float red[4];
  __shared__ float medsh;
  int b = blockIdx.x, t = threadIdx.x;
  if (t < 32) supp[t] = pre_idx[qidx[b] * 32 + t];
  else if (t < 64) supp[t] = runi[b * 32 + t - 32];
  __syncthreads();
  // ---- Gram G = S @ S^T ----
  int tr = t >> 4, tc = t & 15;
  float acc[4][4] = {{0.f}};
  for (int kc = 0; kc < 512; kc += 64) {
    __syncthreads();
#pragma unroll
    for (int p2 = 0; p2 < 16; ++p2) {
      int l = t + 256 * p2;
      int r = l >> 6, c = l & 63;
      SB[r * 65 + c] = X[(size_t)supp[r] * 512 + kc + c];
    }
    __syncthreads();
#pragma unroll 8
    for (int kk = 0; kk < 64; ++kk) {
      float a[4], bb[4];
#pragma unroll
      for (int u = 0; u < 4; ++u) a[u] = SB[(tr * 4 + u) * 65 + kk];
#pragma unroll
      for (int v = 0; v < 4; ++v) bb[v] = SB[(tc * 4 + v) * 65 + kk];
#pragma unroll
      for (int u = 0; u < 4; ++u)
#pragma unroll
        for (int v = 0; v < 4; ++v) acc[u][v] += a[u] * bb[v];
    }
  }
  __syncthreads();
#pragma unroll
  for (int u = 0; u < 4; ++u)
#pragma unroll
    for (int v = 0; v < 4; ++v) G[tr * 4 + u][tc * 4 + v] = acc[u][v];
  __syncthreads();
  // ---- C build + upper-triangle gather into SB (rank-compacted, 2016 values) ----
  for (int l = t; l < 4096; l += 256) {
    int i = l >> 6, j = l & 63;
    float cc = fmaxf(G[i][i] + G[j][j] - 2.0f * G[i][j], 0.f);
    Cm[i][j] = cc;
    if (i < j) {
      int rk = i * 63 - ((i * (i - 1)) >> 1) + j - i - 1;
      SB[rk] = cc;
    }
  }
  for (int l = 2016 + t; l < 2048; l += 256) SB[l] = FLT_MAX;  // pad (t < 32)
  // ---- bitonic sort 2048 ----
  for (int ssz = 2; ssz <= 2048; ssz <<= 1) {
    for (int st = ssz >> 1; st > 0; st >>= 1) {
      __syncthreads();
      for (int l = t; l < 1024; l += 256) {
        int i = 2 * l - (l & (st - 1));
        int j = i + st;
        bool up = ((i & ssz) == 0);
        float a = SB[i], b2 = SB[j];
        if ((a > b2) == up) { SB[i] = b2; SB[j] = a; }
      }
    }
  }
  __syncthreads();
  if (t == 0) medsh = 0.5f * (SB[991] + SB[992]) + 1e-8f;
  __syncthreads();
  float inv = 1.0f / medsh;
  for (int l = t; l < 4096; l += 256) {
    int i = l >> 6, j = l & 63;
    float cn = Cm[i][j] * inv;
    Cm[i][j] = cn;
    G[i][j] = expf(-cn * 10.0f);
  }
  __syncthreads();
  // ---- Sinkhorn 200 iters, wave 0 only, fully in registers, no barriers ----
  if ((t >> 6) == 0) {
    int l = t & 31;  // lanes 32..63 mirror 0..31 (harmless duplicate work)
    float p_l = prewn[b * 32 + l];
    float q_l = postw[b * 32 + l];
    float Kr[32], Kt[32];
#pragma unroll
    for (int j = 0; j < 32; ++j) Kr[j] = G[l][32 + j];   // row l of K-tilde
#pragma unroll
    for (int i = 0; i < 32; ++i) Kt[i] = G[i][32 + l];   // col l of K-tilde
    float r0 = 0.f;
#pragma unroll
    for (int j = 0; j < 64; ++j) r0 += G[l][j];          // full row sum (step-0 u, v=ones)
    float u = p_l / (r0 + 1e-16f);
    float s0 = 0.f, s1 = 0.f, s2 = 0.f, s3 = 0.f;
#pragma unroll
    for (int i = 0; i < 32; i += 4) {
      s0 += Kt[i]     * __shfl(u, i);
      s1 += Kt[i + 1] * __shfl(u, i + 1);
      s2 += Kt[i + 2] * __shfl(u, i + 2);
      s3 += Kt[i + 3] * __shfl(u, i + 3);
    }
    float v = q_l / ((s0 + s1) + (s2 + s3) + 1e-16f);
    for (int it = 1; it < 200; ++it) {
      float a0 = 0.f, a1 = 0.f, a2 = 0.f, a3 = 0.f;
#pragma unroll
      for (int j = 0; j < 32; j += 4) {
        a0 += Kr[j]     * __shfl(v, j);
        a1 += Kr[j + 1] * __shfl(v, j + 1);
        a2 += Kr[j + 2] * __shfl(v, j + 2);
        a3 += Kr[j + 3] * __shfl(v, j + 3);
      }
      u = p_l / ((a0 + a1) + (a2 + a3) + 1e-16f);
      a0 = 0.f; a1 = 0.f; a2 = 0.f; a3 = 0.f;
#pragma unroll
      for (int i = 0; i < 32; i += 4) {
        a0 += Kt[i]     * __shfl(u, i);
        a1 += Kt[i + 1] * __shfl(u, i + 1);
        a2 += Kt[i + 2] * __shfl(u, i + 2);
        a3 += Kt[i + 3] * __shfl(u, i + 3);
      }
      v = q_l / ((a0 + a1) + (a2 + a3) + 1e-16f);
    }
    if (t < 32) { uuS[t] = u; vvS[t] = v; }
  }
  __syncthreads();
  // ---- loss over the nonzero 32x32 block ----
  float lacc = 0.f;
#pragma unroll
  for (int q8 = 0; q8 < 4; ++q8) {
    int l = q8 * 256 + t;
    int i = l >> 5, j = l & 31;
    lacc += uuS[i] * G[i][32 + j] * vvS[j] * Cm[i][32 + j];
  }
  lacc = waveSum(lacc);
  if ((t & 63) == 0) red[t >> 6] = lacc;
  __syncthreads();
  if (t == 0)
    atomicAdd(&scal[3], (red[0] + red[1] + red[2] + red[3]) * (1.0f / 256.0f));
}

// ---------------- sum(W^2) ----------------
__global__ void k_wreg(const float* __restrict__ W, float* __restrict__ scal) {
  __shared__ float red[4];
  int t = threadIdx.x;
  int base = blockIdx.x * 2048;
  float ss = 0.f;
#pragma unroll
  for (int p = 0; p < 8; ++p) {
    float v = W[base + p * 256 + t];
    ss += v * v;
  }
  ss = waveSum(ss);
  if ((t & 63) == 0) red[t >> 6] = ss;
  __syncthreads();
  if (t == 0) atomicAdd(&scal[4], red[0] + red[1] + red[2] + red[3]);
}

// ---------------- final combine ----------------
__global__ void k_combine(const float* __restrict__ mu_t, const float* __restrict__ colsum,
                          const float* __restrict__ scal, float* __restrict__ out) {
  __shared__ float red[8];
  int t = threadIdx.x;  // 512
  float dm = mu_t[t] - colsum[t] * (1.0f / 50000.0f);
  float v = dm * dm;
  v = waveSum(v);
  if ((t & 63) == 0) red[t >> 6] = v;
  __syncthreads();
  if (t == 0) {
    float term_mean = 0.f;
    for (int i = 0; i < 8; ++i) term_mean += red[i];
    float trCT = scal[0] * (1.0f / 255.0f);
    float trCX = scal[1];
    float S = scal[2];
    float term_cov = trCX * 1.001f + trCT * 1.001f - 2.0f * S;
    term_cov = fmaxf(term_cov, 0.f);
    float loss_dist = term_mean + term_cov;
    float loss_knn = scal[3];
    float loss_reg = 0.5f * scal[4];
    out[0] = loss_dist + loss_knn + 1e-4f * loss_reg;
    out[1] = loss_dist;
    out[2] = loss_knn;
  }
}

extern "C" void kernel_launch(void* const* d_in, const int* in_sizes, int n_in,
                              void* d_out, int out_size, void* d_ws, size_t ws_size,
                              hipStream_t stream) {
  const float* q = (const float*)d_in[0];
  const int* qidx = (const int*)d_in[1];
  const float* W = (const float*)d_in[2];
  const float* X = (const float*)d_in[3];
  const int* pre_idx = (const int*)d_in[4];
  const float* prew = (const float*)d_in[5];
  float* out = (float*)d_out;
  float* ws = (float*)d_ws;

  float* scal = ws + OFF_SC;
  float* colsum = ws + OFF_CS;
  float* colss = ws + OFF_CSS;
  float* T = ws + OFF_T;
  float* Tc = ws + OFF_TC;
  float* H = ws + OFF_H;
  float* mu_t = ws + OFF_MUT;
  float* xsq = ws + OFF_XSQ;
  int* runi = (int*)(ws + OFF_RUNI);
  float* postw = ws + OFF_PW;
  float* prewn = ws + OFF_PRW;
  float* V = ws + OFF_D2;
  float* UUT = ws + OFF_UUT;
  float* TcTc = ws + OFF_TCTC;
  float* wv = ws + OFF_W;
  float* m = ws + OFF_M;
  float* candv = ws + OFF_P;              // 256*256 floats; dead before NS Y2/Z2
  int* candi = (int*)(ws + OFF_P + 65536);

  hipMemsetAsync(d_ws, 0, (size_t)ZERO_F * 4, stream);

  // T = q @ W
  k_g64_nn<<<dim3(8, 4), 256, 0, stream>>>(q, W, T, 512, 512, 512, 512, 1.0f);
  // X stats
  k_colstatX<<<256, 256, 0, stream>>>(X, colsum, colss);
  k_xsq<<<12500, 256, 0, stream>>>(X, xsq);
  // T stats
  k_colmeanT<<<1, 512, 0, stream>>>(T, mu_t);
  k_centerT<<<128, 256, 0, stream>>>(T, mu_t, Tc, scal);
  k_trCX<<<1, 512, 0, stream>>>(colsum, colss, scal);
  // V = T @ X^T (MFMA)
  k_vgemm<<<dim3(391, 2), 256, 0, stream>>>(T, X, V);
  k_vstats<<<196, 256, 0, stream>>>(V, m);
  // kNN top-32 from d2 = xsq - 2V (threshold-filter)
  k_topk_part<<<dim3(PARTS, 256), 256, 0, stream>>>(V, xsq, candv, candi);
  k_topk_final<<<256, 128, 0, stream>>>(candv, candi, runi);
  // H assembly
  k_g64_nt<<<dim3(4, 4), 256, 0, stream>>>(Tc, Tc, TcTc, 512, 512, 512, 256, 1.0f);
  k_wvec<<<1, 256, 0, stream>>>(T, colsum, wv);
  k_uut<<<dim3(3, 50), 256, 0, stream>>>(V, m, UUT);
  k_hfix<<<256, 256, 0, stream>>>(UUT, TcTc, wv, scal, H);
  // spectral sum via coupled Newton-Schulz, power-iter scaling
  {
    float* Y = ws + OFF_TC;
    float* Z = ws + OFF_TC + 65536;
    float* Y2 = ws + OFF_P;
    float* Z2 = ws + OFF_P + 65536;
    float* Pm = ws + OFF_G;
    k_power<<<1, 256, 0, stream>>>(H, scal);
    k_nsinit<<<256, 256, 0, stream>>>(H, scal, Y, Z);
    for (int it = 0; it < NS_ITERS; ++it) {
      k_g64_nn<<<dim3(4, 4), 256, 0, stream>>>(Z, Y, Pm, 256, 256, 256, 256, 1.0f);
      k_ns_upd<<<dim3(4, 4, 2), 256, 0, stream>>>(Y, Z, Pm, Y2, Z2);
      float* tmp = Y; Y = Y2; Y2 = tmp;
      tmp = Z; Z = Z2; Z2 = tmp;
    }
    k_ns_trace<<<1, 256, 0, stream>>>(Y, scal);
  }
  // kNN OT loss
  k_l2soft<<<256, 64, 0, stream>>>(T, X, runi, qidx, prew, postw, prewn);
  k_batch<<<256, 256, 0, stream>>>(X, qidx, pre_idx, runi, prewn, postw, scal);
  k_wreg<<<128, 256, 0, stream>>>(W, scal);
  k_combine<<<1, 512, 0, stream>>>(mu_t, colsum, scal, out);
}

// Round 2
// 1210.698 us; speedup vs baseline: 1.1117x; 1.0497x over previous
//
#include <hip/hip_runtime.h>
#include <float.h>
#include <math.h>

// Problem constants
#define BB 256
#define DD 512
#define NN 50000
#define KK 32
#define NS_ITERS 11
#define PARTS 8
#define PCH 6250

// Workspace layout (float offsets)
#define OFF_G     0         // 1M-float region: UUT(65536) + TcTc(65536) + w(256) + m(50000); NS Pm reuses +0
#define OFF_SC    262144    // 64 scalars: 0=sumTc2 1=trCX 2=S_total 3=knn 4=wreg 5=s_ns
#define OFF_CS    262208    // 512 colsum X
#define OFF_CSS   262720    // 512 colsumsq X
#define ZERO_F    263232    // floats to memset
#define OFF_T     263232    // 256*512
#define OFF_TC    394304    // 256*512 Tc; later NS Y/Z
#define OFF_P     525376    // 256*512: top-k cand buffers; later NS Y2/Z2
#define OFF_H     656448    // 256*256
#define OFF_MUT   722496    // 512
#define OFF_XSQ   723008    // 50000
#define OFF_RUNI  781200    // 256*32 (int)
#define OFF_PW    789392    // 256*32 post_w
#define OFF_PRW   797584    // 256*32 pre_w normalized
#define OFF_D2    805776    // V = T@X^T  (256*50000)

#define OFF_UUT   (OFF_G)
#define OFF_TCTC  (OFF_G + 65536)
#define OFF_W     (OFF_G + 131072)
#define OFF_M     (OFF_G + 131328)

typedef __attribute__((ext_vector_type(8))) short bf16x8;
typedef __attribute__((ext_vector_type(4))) float f32x4;

__device__ __forceinline__ float waveSum(float v) {
#pragma unroll
  for (int off = 32; off > 0; off >>= 1) v += __shfl_xor(v, off);
  return v;
}

// split fp32x4 -> bf16 hi/lo, write packed pairs to LDS at short-offset sa (16B-aligned rows)
__device__ __forceinline__ void cvt_write(float4 v, unsigned short* hi, unsigned short* lo, int sa) {
  unsigned int b0 = __float_as_uint(v.x), b1 = __float_as_uint(v.y);
  unsigned int b2 = __float_as_uint(v.z), b3 = __float_as_uint(v.w);
  unsigned int h0 = b0 & 0xffff0000u, h1 = b1 & 0xffff0000u;
  unsigned int h2 = b2 & 0xffff0000u, h3 = b3 & 0xffff0000u;
  float l0 = v.x - __uint_as_float(h0), l1 = v.y - __uint_as_float(h1);
  float l2 = v.z - __uint_as_float(h2), l3 = v.w - __uint_as_float(h3);
  *(unsigned int*)&hi[sa]     = (h0 >> 16) | h1;
  *(unsigned int*)&hi[sa + 2] = (h2 >> 16) | h3;
  *(unsigned int*)&lo[sa]     = (__float_as_uint(l0) >> 16) | (__float_as_uint(l1) & 0xffff0000u);
  *(unsigned int*)&lo[sa + 2] = (__float_as_uint(l2) >> 16) | (__float_as_uint(l3) & 0xffff0000u);
}

// ---------------- generic 64x64-tile GEMM, C = scale * A @ B (nn) ----------------
__global__ void __launch_bounds__(256) k_g64_nn(const float* __restrict__ A,
                                                const float* __restrict__ B,
                                                float* __restrict__ C,
                                                int K, int lda, int ldb, int ldc, float scale) {
  __shared__ float As[64][65], Bs[64][65];
  int m0 = blockIdx.y * 64, n0 = blockIdx.x * 64;
  int t = threadIdx.x, tr = t >> 4, tc = t & 15;
  float acc[4][4] = {{0.f}};
  for (int k0 = 0; k0 < K; k0 += 64) {
#pragma unroll
    for (int p = 0; p < 16; ++p) {
      int l = t + 256 * p;
      int r = l >> 6, c = l & 63;
      As[r][c] = A[(m0 + r) * lda + k0 + c];
      Bs[r][c] = B[(k0 + r) * ldb + n0 + c];
    }
    __syncthreads();
#pragma unroll 16
    for (int kk = 0; kk < 64; ++kk) {
      float a[4], b[4];
#pragma unroll
      for (int u = 0; u < 4; ++u) a[u] = As[tr + 16 * u][kk];
#pragma unroll
      for (int v = 0; v < 4; ++v) b[v] = Bs[kk][tc + 16 * v];
#pragma unroll
      for (int u = 0; u < 4; ++u)
#pragma unroll
        for (int v = 0; v < 4; ++v) acc[u][v] += a[u] * b[v];
    }
    __syncthreads();
  }
#pragma unroll
  for (int u = 0; u < 4; ++u)
#pragma unroll
    for (int v = 0; v < 4; ++v)
      C[(m0 + tr + 16 * u) * ldc + n0 + tc + 16 * v] = acc[u][v] * scale;
}

// ---------------- generic 64x64-tile GEMM, C = scale * A @ B^T (nt) ----------------
__global__ void __launch_bounds__(256) k_g64_nt(const float* __restrict__ A,
                                                const float* __restrict__ B,
                                                float* __restrict__ C,
                                                int K, int lda, int ldb, int ldc, float scale) {
  __shared__ float As[64][65], Bs[64][65];
  int m0 = blockIdx.y * 64, n0 = blockIdx.x * 64;
  int t = threadIdx.x, tr = t >> 4, tc = t & 15;
  float acc[4][4] = {{0.f}};
  for (int k0 = 0; k0 < K; k0 += 64) {
#pragma unroll
    for (int p = 0; p < 16; ++p) {
      int l = t + 256 * p;
      int r = l >> 6, c = l & 63;
      As[r][c] = A[(m0 + r) * lda + k0 + c];
      Bs[r][c] = B[(n0 + r) * ldb + k0 + c];
    }
    __syncthreads();
#pragma unroll 16
    for (int kk = 0; kk < 64; ++kk) {
      float a[4], b[4];
#pragma unroll
      for (int u = 0; u < 4; ++u) a[u] = As[tr + 16 * u][kk];
#pragma unroll
      for (int v = 0; v < 4; ++v) b[v] = Bs[tc + 16 * v][kk];
#pragma unroll
      for (int u = 0; u < 4; ++u)
#pragma unroll
        for (int v = 0; v < 4; ++v) acc[u][v] += a[u] * b[v];
    }
    __syncthreads();
  }
#pragma unroll
  for (int u = 0; u < 4; ++u)
#pragma unroll
    for (int v = 0; v < 4; ++v)
      C[(m0 + tr + 16 * u) * ldc + n0 + tc + 16 * v] = acc[u][v] * scale;
}

// ---------------- V = T @ X^T  (MFMA bf16-split, on-the-fly conversion) ----------------
__global__ void __launch_bounds__(256) k_vgemm(const float* __restrict__ T,
                                               const float* __restrict__ X,
                                               float* __restrict__ V) {
  __shared__ unsigned short Ah[128 * 72], Al[128 * 72], Bh[128 * 72], Bl[128 * 72];
  int bj = blockIdx.x, bi = blockIdx.y;
  int t = threadIdx.x;
  int wave = t >> 6, lane = t & 63;
  int m0 = (wave >> 1) * 64, n0 = (wave & 1) * 64;
  int lrow = lane & 15, lq = lane >> 4;
  f32x4 acc[4][4] = {};
  for (int kc = 0; kc < 512; kc += 64) {
#pragma unroll
    for (int f = 0; f < 8; ++f) {
      int lin = f * 256 + t;
      int r = lin >> 4, c4 = lin & 15;
      int sa = r * 72 + c4 * 4;
      float4 va = *(const float4*)&T[(bi * 128 + r) * 512 + kc + c4 * 4];
      cvt_write(va, Ah, Al, sa);
      int jg = bj * 128 + r;
      float4 vb = {0.f, 0.f, 0.f, 0.f};
      if (jg < NN) vb = *(const float4*)&X[(size_t)jg * 512 + kc + c4 * 4];
      cvt_write(vb, Bh, Bl, sa);
    }
    __syncthreads();
#pragma unroll
    for (int ks = 0; ks < 2; ++ks) {
      int kb = ks * 32 + lq * 8;
      bf16x8 ah[4], al[4], bh[4], bl[4];
#pragma unroll
      for (int mi = 0; mi < 4; ++mi) {
        int ro = (m0 + mi * 16 + lrow) * 72 + kb;
        ah[mi] = *(const bf16x8*)&Ah[ro];
        al[mi] = *(const bf16x8*)&Al[ro];
      }
#pragma unroll
      for (int nj = 0; nj < 4; ++nj) {
        int ro = (n0 + nj * 16 + lrow) * 72 + kb;
        bh[nj] = *(const bf16x8*)&Bh[ro];
        bl[nj] = *(const bf16x8*)&Bl[ro];
      }
#pragma unroll
      for (int mi = 0; mi < 4; ++mi)
#pragma unroll
        for (int nj = 0; nj < 4; ++nj) {
          acc[mi][nj] = __builtin_amdgcn_mfma_f32_16x16x32_bf16(ah[mi], bh[nj], acc[mi][nj], 0, 0, 0);
          acc[mi][nj] = __builtin_amdgcn_mfma_f32_16x16x32_bf16(ah[mi], bl[nj], acc[mi][nj], 0, 0, 0);
          acc[mi][nj] = __builtin_amdgcn_mfma_f32_16x16x32_bf16(al[mi], bh[nj], acc[mi][nj], 0, 0, 0);
        }
    }
    __syncthreads();
  }
#pragma unroll
  for (int mi = 0; mi < 4; ++mi)
#pragma unroll
    for (int nj = 0; nj < 4; ++nj)
#pragma unroll
      for (int r = 0; r < 4; ++r) {
        int row = bi * 128 + m0 + mi * 16 + lq * 4 + r;
        int col = bj * 128 + n0 + nj * 16 + lrow;
        if (col < NN) V[(size_t)row * NN + col] = acc[mi][nj][r];
      }
}

// ---------------- UUT += U @ U^T, U = V - m (MFMA bf16-split, split-K atomic) ----------------
__global__ void __launch_bounds__(256) k_uut(const float* __restrict__ V,
                                             const float* __restrict__ m,
                                             float* __restrict__ UUT) {
  __shared__ unsigned short Ah[128 * 72], Al[128 * 72], Bh[128 * 72], Bl[128 * 72];
  const int pi_[3] = {0, 0, 1}, pj_[3] = {0, 1, 1};
  int bi = pi_[blockIdx.x], bj = pj_[blockIdx.x];
  int j0 = blockIdx.y * 1000, jlim = j0 + 1000;
  int t = threadIdx.x;
  int wave = t >> 6, lane = t & 63;
  int m0 = (wave >> 1) * 64, n0 = (wave & 1) * 64;
  int lrow = lane & 15, lq = lane >> 4;
  f32x4 acc[4][4] = {};
  for (int ch = 0; ch < 16; ++ch) {
    int jc = j0 + ch * 64;
#pragma unroll
    for (int f = 0; f < 8; ++f) {
      int lin = f * 256 + t;
      int r = lin >> 4, c4 = lin & 15;
      int sa = r * 72 + c4 * 4;
      int jb = jc + c4 * 4;
      float4 va = {0.f, 0.f, 0.f, 0.f}, vb = {0.f, 0.f, 0.f, 0.f};
      if (jb < jlim) {
        float4 mm = *(const float4*)&m[jb];
        va = *(const float4*)&V[(size_t)(bi * 128 + r) * NN + jb];
        vb = *(const float4*)&V[(size_t)(bj * 128 + r) * NN + jb];
        va.x -= mm.x; va.y -= mm.y; va.z -= mm.z; va.w -= mm.w;
        vb.x -= mm.x; vb.y -= mm.y; vb.z -= mm.z; vb.w -= mm.w;
      }
      cvt_write(va, Ah, Al, sa);
      cvt_write(vb, Bh, Bl, sa);
    }
    __syncthreads();
#pragma unroll
    for (int ks = 0; ks < 2; ++ks) {
      int kb = ks * 32 + lq * 8;
      bf16x8 ah[4], al[4], bh[4], bl[4];
#pragma unroll
      for (int mi = 0; mi < 4; ++mi) {
        int ro = (m0 + mi * 16 + lrow) * 72 + kb;
        ah[mi] = *(const bf16x8*)&Ah[ro];
        al[mi] = *(const bf16x8*)&Al[ro];
      }
#pragma unroll
      for (int nj = 0; nj < 4; ++nj) {
        int ro = (n0 + nj * 16 + lrow) * 72 + kb;
        bh[nj] = *(const bf16x8*)&Bh[ro];
        bl[nj] = *(const bf16x8*)&Bl[ro];
      }
#pragma unroll
      for (int mi = 0; mi < 4; ++mi)
#pragma unroll
        for (int nj = 0; nj < 4; ++nj) {
          acc[mi][nj] = __builtin_amdgcn_mfma_f32_16x16x32_bf16(ah[mi], bh[nj], acc[mi][nj], 0, 0, 0);
          acc[mi][nj] = __builtin_amdgcn_mfma_f32_16x16x32_bf16(ah[mi], bl[nj], acc[mi][nj], 0, 0, 0);
          acc[mi][nj] = __builtin_amdgcn_mfma_f32_16x16x32_bf16(al[mi], bh[nj], acc[mi][nj], 0, 0, 0);
        }
    }
    __syncthreads();
  }
#pragma unroll
  for (int mi = 0; mi < 4; ++mi)
#pragma unroll
    for (int nj = 0; nj < 4; ++nj)
#pragma unroll
      for (int r = 0; r < 4; ++r) {
        int row = bi * 128 + m0 + mi * 16 + lq * 4 + r;
        int col = bj * 128 + n0 + nj * 16 + lrow;
        atomicAdd(&UUT[row * 256 + col], acc[mi][nj][r]);
      }
}

// ---------------- column sums & sumsq of X (atomic) ----------------
__global__ void k_colstatX(const float* __restrict__ X, float* __restrict__ colsum,
                           float* __restrict__ colss) {
  int b = blockIdx.x, t = threadIdx.x;
  int r0 = b * 196;
  int r1 = r0 + 196; if (r1 > NN) r1 = NN;
  float s1 = 0, ss1 = 0, s2 = 0, ss2 = 0;
  for (int r = r0; r < r1; ++r) {
    float v1 = X[(size_t)r * 512 + t], v2 = X[(size_t)r * 512 + t + 256];
    s1 += v1; ss1 += v1 * v1; s2 += v2; ss2 += v2 * v2;
  }
  atomicAdd(&colsum[t], s1);       atomicAdd(&colss[t], ss1);
  atomicAdd(&colsum[t + 256], s2); atomicAdd(&colss[t + 256], ss2);
}

// ---------------- per-row squared norm of X ----------------
__global__ void k_xsq(const float* __restrict__ X, float* __restrict__ xsq) {
  int row = blockIdx.x * 4 + (threadIdx.x >> 6);
  int lane = threadIdx.x & 63;
  const float* Xr = X + (size_t)row * 512;
  float s = 0.f;
#pragma unroll
  for (int d = 0; d < 8; ++d) { float v = Xr[lane + 64 * d]; s += v * v; }
  s = waveSum(s);
  if (lane == 0) xsq[row] = s;
}

// ---------------- column means of T ----------------
__global__ void k_colmeanT(const float* __restrict__ T, float* __restrict__ mu) {
  int c = threadIdx.x;
  float s = 0.f;
  for (int r = 0; r < 256; ++r) s += T[r * 512 + c];
  mu[c] = s * (1.0f / 256.0f);
}

// ---------------- Tc = T - mu, accumulate sum(Tc^2) ----------------
__global__ void k_centerT(const float* __restrict__ T, const float* __restrict__ mu,
                          float* __restrict__ Tc, float* __restrict__ scal) {
  __shared__ float red[4];
  int t = threadIdx.x;
  int base = blockIdx.x * 1024;
  float ss = 0.f;
#pragma unroll
  for (int p = 0; p < 4; ++p) {
    int l = base + p * 256 + t;
    float v = T[l] - mu[l & 511];
    Tc[l] = v;
    ss += v * v;
  }
  ss = waveSum(ss);
  if ((t & 63) == 0) red[t >> 6] = ss;
  __syncthreads();
  if (t == 0) atomicAdd(&scal[0], red[0] + red[1] + red[2] + red[3]);
}

// ---------------- trace of cov(X) ----------------
__global__ void k_trCX(const float* __restrict__ colsum, const float* __restrict__ colss,
                       float* __restrict__ scal) {
  __shared__ float red[8];
  int t = threadIdx.x;  // 512
  float mu = colsum[t] * (1.0f / 50000.0f);
  float v = (colss[t] - 50000.0f * mu * mu) * (1.0f / 49999.0f);
  v = waveSum(v);
  if ((t & 63) == 0) red[t >> 6] = v;
  __syncthreads();
  if (t == 0) {
    float s = 0;
    for (int i = 0; i < 8; ++i) s += red[i];
    scal[1] = s;
  }
}

// ---------------- colmeans of V -> m ----------------
__global__ void k_vstats(const float* __restrict__ V, float* __restrict__ m) {
  int j = blockIdx.x * 256 + threadIdx.x;
  if (j >= NN) return;
  float s = 0.f;
  for (int i = 0; i < 256; ++i) s += V[(size_t)i * NN + j];
  m[j] = s * (1.0f / 256.0f);
}

// ---------------- w_i = Tc_i . muX ----------------
__global__ void __launch_bounds__(256) k_wvec(const float* __restrict__ T,
                                              const float* __restrict__ colsum,
                                              float* __restrict__ w) {
  __shared__ float cs[512];
  __shared__ float red[4];
  int t = threadIdx.x;
  cs[t] = colsum[t] * (1.0f / 50000.0f);
  cs[t + 256] = colsum[t + 256] * (1.0f / 50000.0f);
  __syncthreads();
  float a = 0.f;
  for (int c = 0; c < 512; ++c) a += T[t * 512 + c] * cs[c];
  float s = waveSum(a);
  if ((t & 63) == 0) red[t >> 6] = s;
  __syncthreads();
  float mean = (red[0] + red[1] + red[2] + red[3]) * (1.0f / 256.0f);
  w[t] = a - mean;
}

// ---------------- H = (UUT - N w w^T)/(49999*255) + rhoX * TcTc/255 ----------------
__global__ void k_hfix(const float* __restrict__ UUT, const float* __restrict__ TcTc,
                       const float* __restrict__ w, const float* __restrict__ scal,
                       float* __restrict__ H) {
  int l = blockIdx.x * 256 + threadIdx.x;
  int i = l >> 8, j = l & 255;
  float u = (i >= 128 && j < 128) ? UUT[j * 256 + i] : UUT[i * 256 + j];
  float rho = scal[1] * (1e-3f / 512.0f);
  H[l] = (u - 50000.0f * w[i] * w[j]) * (1.0f / (49999.0f * 255.0f))
       + rho * TcTc[i * 256 + j] * (1.0f / 255.0f);
}

// ---------------- power iteration: scal[5] = safe lambda_max bound of H' ----------------
__global__ void __launch_bounds__(256) k_power(const float* __restrict__ H,
                                               float* __restrict__ scal) {
  __shared__ float v[256], nv[256], red[4];
  int t = threadIdx.x;
  float rt = scal[0] * (1.0f / 255.0f) * (1e-3f / 512.0f);
  v[t] = 1.0f;
  __syncthreads();
  float n2 = 256.0f, n3 = 256.0f;
  for (int it = 0; it < 3; ++it) {
    float s = rt * v[t];
    for (int j = 0; j < 256; ++j) s += H[t * 256 + j] * v[j];
    nv[t] = s;
    float ss = waveSum(s * s);
    if ((t & 63) == 0) red[t >> 6] = ss;
    __syncthreads();
    float norm2 = red[0] + red[1] + red[2] + red[3];
    if (it == 1) n2 = norm2;
    if (it == 2) n3 = norm2;
    v[t] = nv[t];
    __syncthreads();
  }
  float d = H[t * 256 + t] + rt;
#pragma unroll
  for (int off = 32; off > 0; off >>= 1) d = fmaxf(d, __shfl_xor(d, off));
  if ((t & 63) == 0) red[t >> 6] = d;
  __syncthreads();
  if (t == 0) {
    float lam = sqrtf(n3 / n2);
    float md = fmaxf(fmaxf(red[0], red[1]), fmaxf(red[2], red[3]));
    scal[5] = fmaxf(1.3f * lam, md);
  }
}

// ---------------- Y0 = (H + rt I)/s, Z0 = I ----------------
__global__ void k_nsinit(const float* __restrict__ H, const float* __restrict__ scal,
                         float* __restrict__ Y, float* __restrict__ Z) {
  int l = blockIdx.x * 256 + threadIdx.x;
  int i = l >> 8, j = l & 255;
  float rt = scal[0] * (1.0f / 255.0f) * (1e-3f / 512.0f);
  float inv = 1.0f / scal[5];
  Y[l] = (H[l] + ((i == j) ? rt : 0.f)) * inv;
  Z[l] = (i == j) ? 1.0f : 0.f;
}

// ---------------- NS update ----------------
__global__ void __launch_bounds__(256) k_ns_upd(const float* __restrict__ Y, const float* __restrict__ Z,
                                                const float* __restrict__ P,
                                                float* __restrict__ Yn, float* __restrict__ Zn) {
  __shared__ float As[64][65], Bs[64][65];
  int bi = blockIdx.x, bj = blockIdx.y, zz = blockIdx.z;
  const float* A = zz ? P : Y;
  const float* B = zz ? Z : P;
  const float* D = zz ? Z : Y;
  float* O = zz ? Zn : Yn;
  int t = threadIdx.x;
  int tr = t >> 4, tc = t & 15;
  float acc[4][4] = {{0.f}};
  for (int k0 = 0; k0 < 256; k0 += 64) {
#pragma unroll
    for (int p = 0; p < 16; ++p) {
      int l = t + 256 * p;
      int r = l >> 6, c = l & 63;
      As[r][c] = A[(bi * 64 + r) * 256 + k0 + c];
      Bs[r][c] = B[(k0 + r) * 256 + bj * 64 + c];
    }
    __syncthreads();
#pragma unroll 16
    for (int kk = 0; kk < 64; ++kk) {
      float a[4], b[4];
#pragma unroll
      for (int u = 0; u < 4; ++u) a[u] = As[tr + 16 * u][kk];
#pragma unroll
      for (int v = 0; v < 4; ++v) b[v] = Bs[kk][tc + 16 * v];
#pragma unroll
      for (int u = 0; u < 4; ++u)
#pragma unroll
        for (int v = 0; v < 4; ++v) acc[u][v] += a[u] * b[v];
    }
    __syncthreads();
  }
#pragma unroll
  for (int u = 0; u < 4; ++u)
#pragma unroll
    for (int v = 0; v < 4; ++v) {
      int idx = (bi * 64 + tr + 16 * u) * 256 + bj * 64 + tc + 16 * v;
      O[idx] = 1.5f * D[idx] - 0.5f * acc[u][v];
    }
}

// ---------------- S_total = sqrt(s)*tr(Y) + 256*sqrt(rt) ----------------
__global__ void k_ns_trace(const float* __restrict__ Y, float* __restrict__ scal) {
  __shared__ float red[4];
  int t = threadIdx.x;  // 256
  float v = Y[t * 256 + t];
  v = waveSum(v);
  if ((t & 63) == 0) red[t >> 6] = v;
  __syncthreads();
  if (t == 0) {
    float tr = red[0] + red[1] + red[2] + red[3];
    float rt = scal[0] * (1.0f / 255.0f) * (1e-3f / 512.0f);
    scal[2] = sqrtf(scal[5]) * tr + 256.0f * sqrtf(rt);
  }
}

// ---------------- stage 1: threshold-filter exact top-32 per (query, 1/8-slice) ----------------
// 256 threads; LDS candidate buffer (512) + running (tau_v, tau_i) = 32nd-best-so-far.
__global__ void __launch_bounds__(256) k_topk_part(const float* __restrict__ V,
                                                   const float* __restrict__ xsq,
                                                   float* __restrict__ candv,
                                                   int* __restrict__ candi) {
  __shared__ float bufv[512];
  __shared__ int bufi[512];
  __shared__ int lcount;
  __shared__ float tvs;
  __shared__ int tis;
  int part = blockIdx.x, q = blockIdx.y, t = threadIdx.x;
  int base = part * PCH;
  int lane = t & 63;
  if (t == 0) { lcount = 0; tvs = FLT_MAX; tis = 0x7fffffff; }
  __syncthreads();
  const float* rowV = V + (size_t)q * NN + base;
  const float* xs = xsq + base;

  auto flush = [&]() {
    __syncthreads();
    int c = lcount;
    for (int s = c + t; s < 512; s += 256) { bufv[s] = FLT_MAX; bufi[s] = 0x7fffffff; }
    __syncthreads();
    for (int ssz = 2; ssz <= 512; ssz <<= 1) {
      for (int st = ssz >> 1; st > 0; st >>= 1) {
        int i = 2 * t - (t & (st - 1));
        int j = i + st;
        bool up = ((i & ssz) == 0);
        float a = bufv[i], b = bufv[j];
        int ai = bufi[i], bi2 = bufi[j];
        bool agtb = (a > b) || (a == b && ai > bi2);
        if (agtb == up) { bufv[i] = b; bufv[j] = a; bufi[i] = bi2; bufi[j] = ai; }
        __syncthreads();
      }
    }
    if (t == 0) { lcount = 32; tvs = bufv[31]; tis = bufi[31]; }
    __syncthreads();
  };

  int ntile = (PCH + 255) >> 8;
  for (int tile = 0; tile < ntile; ++tile) {
    int j = tile * 256 + t;
    float val = 0.f; int idx = 0;
    bool pred = false;
    if (j < PCH) {
      val = xs[j] - 2.0f * rowV[j];
      idx = base + j;
      float tv = tvs; int ti = tis;
      pred = (val < tv) || (val == tv && idx < ti);
    }
    unsigned long long mask = __ballot(pred);
    if (mask) {
      int lead = __ffsll((unsigned long long)mask) - 1;
      int cnt = __popcll(mask);
      int basep = 0;
      if (lane == lead) basep = atomicAdd(&lcount, cnt);
      basep = __shfl(basep, lead);
      if (pred) {
        int off = __popcll(mask & ((1ull << lane) - 1ull));
        int slot = basep + off;
        bufv[slot] = val; bufi[slot] = idx;
      }
    }
    __syncthreads();
    if (lcount >= 256) flush();
  }
  flush();
  if (t < 32) {
    candv[(q * PARTS + part) * 32 + t] = bufv[t];
    candi[(q * PARTS + part) * 32 + t] = bufi[t];
  }
}

// ---------------- stage 2: bitonic-sort 256 candidates, emit top-32 indices ----------------
__global__ void __launch_bounds__(128) k_topk_final(const float* __restrict__ candv,
                                                    const int* __restrict__ candi,
                                                    int* __restrict__ runi) {
  __shared__ float v[256];
  __shared__ int ix[256];
  int q = blockIdx.x, t = threadIdx.x;
  v[t] = candv[q * 256 + t];
  v[t + 128] = candv[q * 256 + t + 128];
  ix[t] = candi[q * 256 + t];
  ix[t + 128] = candi[q * 256 + t + 128];
  __syncthreads();
  for (int ssz = 2; ssz <= 256; ssz <<= 1) {
    for (int st = ssz >> 1; st > 0; st >>= 1) {
      int i = 2 * t - (t & (st - 1));
      int j = i + st;
      bool up = ((i & ssz) == 0);
      float a = v[i], b = v[j];
      int ai = ix[i], bi = ix[j];
      bool agtb = (a > b) || (a == b && ai > bi);
      if (agtb == up) { v[i] = b; v[j] = a; ix[i] = bi; ix[j] = ai; }
      __syncthreads();
    }
  }
  if (t < 32) runi[q * 32 + t] = ix[t];
}

// ---------------- l2 to neighbors, softmax post_w, normalized pre_w ----------------
__global__ void __launch_bounds__(64) k_l2soft(const float* __restrict__ T, const float* __restrict__ X,
                                               const int* __restrict__ runi, const int* __restrict__ qidx,
                                               const float* __restrict__ prew, float* __restrict__ postw,
                                               float* __restrict__ prewn) {
  __shared__ float l2s[32];
  int b = blockIdx.x, lane = threadIdx.x;
  int qi = qidx[b];
  float pwv = (lane < 32) ? fmaxf(prew[qi * 32 + lane], 1e-8f) : 0.f;
  float psum = waveSum(pwv);
  if (lane < 32) prewn[b * 32 + lane] = pwv / psum;
  const float* Tb = T + b * 512;
  for (int n = 0; n < 32; ++n) {
    int nb = runi[b * 32 + n];
    const float* Xr = X + (size_t)nb * 512;
    float acc = 0.f;
#pragma unroll
    for (int d = 0; d < 8; ++d) {
      float df = Tb[lane + 64 * d] - Xr[lane + 64 * d];
      acc += df * df;
    }
    acc = waveSum(acc);
    if (lane == 0) l2s[n] = acc;
  }
  __syncthreads();
  float lg = (lane < 32) ? (-l2s[lane] * 10.0f) : -FLT_MAX;
  float mx = lg;
#pragma unroll
  for (int off = 32; off > 0; off >>= 1) mx = fmaxf(mx, __shfl_xor(mx, off));
  float e = (lane < 32) ? expf(lg - mx) : 0.f;
  float es = waveSum(e);
  float wv = e / es;
  wv = fmaxf(wv, 1e-8f);
  float ws2 = (lane < 32) ? wv : 0.f;
  ws2 = waveSum(ws2);
  if (lane < 32) postw[b * 32 + lane] = wv / ws2;
}

// ---------------- fused per-batch: Gram(MFMA) -> C -> median(radix-select) -> Sinkhorn -> loss ----
// Gram uses the bf16-split MFMA path (A=B, one staging buffer).
// Median: ranks 992/993 (1-indexed) of the 2016 upper-tri values via 4-pass 8-bit radix select
// (float bits are monotone for non-negative values; -0 normalized via &0x7fffffff).
// Sinkhorn: collapsed 32x32 subproblem; HALF-WAVE SPLIT: lanes (l, l+32) each own 16 columns of
// row l (and 16 rows of col l), 16 bpermute + cross-half shfl_xor combine per matvec.
// Early exit when (u,v) reach a bitwise fixed point (further iterations are identities).
__global__ void __launch_bounds__(256) k_batch(const float* __restrict__ X, const int* __restrict__ qidx,
                                               const int* __restrict__ pre_idx, const int* __restrict__ runi,
                                               const float* __restrict__ prewn, const float* __restrict__ postw,
                                               float* __restrict__ scal) {
  __shared__ float G[64][65];
  __shared__ float Cm[64][65];
  __shared__ unsigned short Ah[64 * 72], Al[64 * 72];
  __shared__ int supp[64];
  __shared__ float uuS[32], vvS[32];
  __shared__ float red[4];
  __shared__ float medsh;
  __shared__ unsigned int hist[256];
  __shared__ unsigned int wtot[4];
  __shared__ unsigned int selp;
  __shared__ int selk;
  __shared__ unsigned int cw[4], mw[4];
  int b = blockIdx.x, t = threadIdx.x;
  int wave = t >> 6, lane = t & 63;
  if (t < 32) supp[t] = pre_idx[qidx[b] * 32 + t];
  else if (t < 64) supp[t] = runi[b * 32 + t - 32];
  if (t == 0) { selp = 0u; selk = 992; }
  __syncthreads();
  // ---- Gram G = S @ S^T via MFMA bf16-split (A = B) ----
  {
    int m0 = (wave >> 1) * 32, n0 = (wave & 1) * 32;
    int lrow = lane & 15, lq = lane >> 4;
    f32x4 acc[2][2] = {};
    for (int kc = 0; kc < 512; kc += 64) {
#pragma unroll
      for (int f = 0; f < 4; ++f) {
        int lin = f * 256 + t;
        int r = lin >> 4, c4 = lin & 15;
        float4 va = *(const float4*)&X[(size_t)supp[r] * 512 + kc + c4 * 4];
        cvt_write(va, Ah, Al, r * 72 + c4 * 4);
      }
      __syncthreads();
#pragma unroll
      for (int ks = 0; ks < 2; ++ks) {
        int kb = ks * 32 + lq * 8;
        bf16x8 ah[2], al[2], bh[2], bl[2];
#pragma unroll
        for (int mi = 0; mi < 2; ++mi) {
          int ro = (m0 + mi * 16 + lrow) * 72 + kb;
          ah[mi] = *(const bf16x8*)&Ah[ro];
          al[mi] = *(const bf16x8*)&Al[ro];
        }
#pragma unroll
        for (int nj = 0; nj < 2; ++nj) {
          int ro = (n0 + nj * 16 + lrow) * 72 + kb;
          bh[nj] = *(const bf16x8*)&Ah[ro];
          bl[nj] = *(const bf16x8*)&Al[ro];
        }
#pragma unroll
        for (int mi = 0; mi < 2; ++mi)
#pragma unroll
          for (int nj = 0; nj < 2; ++nj) {
            acc[mi][nj] = __builtin_amdgcn_mfma_f32_16x16x32_bf16(ah[mi], bh[nj], acc[mi][nj], 0, 0, 0);
            acc[mi][nj] = __builtin_amdgcn_mfma_f32_16x16x32_bf16(ah[mi], bl[nj], acc[mi][nj], 0, 0, 0);
            acc[mi][nj] = __builtin_amdgcn_mfma_f32_16x16x32_bf16(al[mi], bh[nj], acc[mi][nj], 0, 0, 0);
          }
      }
      __syncthreads();
    }
#pragma unroll
    for (int mi = 0; mi < 2; ++mi)
#pragma unroll
      for (int nj = 0; nj < 2; ++nj)
#pragma unroll
        for (int r = 0; r < 4; ++r)
          G[m0 + mi * 16 + lq * 4 + r][n0 + nj * 16 + lrow] = acc[mi][nj][r];
  }
  __syncthreads();
  // ---- C build (raw, unnormalized) ----
  for (int l = t; l < 4096; l += 256) {
    int i = l >> 6, j = l & 63;
    Cm[i][j] = fmaxf(G[i][i] + G[j][j] - 2.0f * G[i][j], 0.f);
  }
  __syncthreads();
  // ---- radix-select ranks 992 & 993 over upper triangle (2016 values) ----
  for (int pass = 0; pass < 4; ++pass) {
    int shift = 24 - 8 * pass;
    hist[t] = 0u;
    __syncthreads();
    for (int l = t; l < 4096; l += 256) {
      int i = l >> 6, j = l & 63;
      if (i < j) {
        unsigned int u = __float_as_uint(Cm[i][j]) & 0x7fffffffu;
        bool match = (pass == 0) || (((u ^ selp) >> (shift + 8)) == 0u);
        if (match) atomicAdd(&hist[(u >> shift) & 255], 1u);
      }
    }
    __syncthreads();
    unsigned int h = hist[t];
    unsigned int c = h;
#pragma unroll
    for (int off = 1; off < 64; off <<= 1) {
      unsigned int n = __shfl_up(c, off);
      if ((t & 63) >= off) c += n;
    }
    if ((t & 63) == 63) wtot[t >> 6] = c;
    __syncthreads();
    unsigned int offw = 0;
    for (int w2 = 0; w2 < (t >> 6); ++w2) offw += wtot[w2];
    c += offw;
    int k = selk;
    if ((int)c >= k && (int)(c - h) < k) {
      selk = k - (int)(c - h);
      selp = selp | ((unsigned int)t << shift);
    }
    __syncthreads();
  }
  {
    unsigned int target = selp;
    unsigned int cnt = 0, mn = 0xffffffffu;
    for (int l = t; l < 4096; l += 256) {
      int i = l >> 6, j = l & 63;
      if (i < j) {
        unsigned int u = __float_as_uint(Cm[i][j]) & 0x7fffffffu;
        if (u <= target) cnt++;
        else mn = (u < mn) ? u : mn;
      }
    }
#pragma unroll
    for (int off = 32; off > 0; off >>= 1) {
      cnt += __shfl_xor(cnt, off);
      unsigned int m2 = __shfl_xor(mn, off);
      mn = (m2 < mn) ? m2 : mn;
    }
    if (lane == 0) { cw[wave] = cnt; mw[wave] = mn; }
    __syncthreads();
    if (t == 0) {
      unsigned int ct = cw[0] + cw[1] + cw[2] + cw[3];
      unsigned int mt = mw[0];
      mt = (mw[1] < mt) ? mw[1] : mt;
      mt = (mw[2] < mt) ? mw[2] : mt;
      mt = (mw[3] < mt) ? mw[3] : mt;
      float v992 = __uint_as_float(target);
      float v993 = (ct >= 993u) ? v992 : __uint_as_float(mt);
      medsh = 0.5f * (v992 + v993) + 1e-8f;
    }
    __syncthreads();
  }
  // ---- normalize C, build K = exp(-10*C) ----
  float inv = 1.0f / medsh;
  for (int l = t; l < 4096; l += 256) {
    int i = l >> 6, j = l & 63;
    float cn = Cm[i][j] * inv;
    Cm[i][j] = cn;
    G[i][j] = expf(-cn * 10.0f);
  }
  __syncthreads();
  // ---- Sinkhorn, wave 0, half-wave split, early exit on bitwise fixed point ----
  if (wave == 0) {
    int half = lane >> 5;
    int l = lane & 31;
    int cb = half * 16;
    float p_l = prewn[b * 32 + l];
    float q_l = postw[b * 32 + l];
    float Kr16[16], Kt16[16];
#pragma unroll
    for (int c2 = 0; c2 < 16; ++c2) Kr16[c2] = G[l][32 + cb + c2];
#pragma unroll
    for (int r2 = 0; r2 < 16; ++r2) Kt16[r2] = G[cb + r2][32 + l];
    // step 0: u = p / rowsum64(K) (v = ones over all 64 slots)
    float r0 = 0.f;
#pragma unroll
    for (int c2 = 0; c2 < 32; ++c2) r0 += G[l][half * 32 + c2];
    r0 += __shfl_xor(r0, 32);
    float u = p_l / (r0 + 1e-16f);
    float s0 = 0.f, s1 = 0.f, s2 = 0.f, s3 = 0.f;
#pragma unroll
    for (int r2 = 0; r2 < 16; r2 += 4) {
      s0 += Kt16[r2]     * __shfl(u, cb + r2);
      s1 += Kt16[r2 + 1] * __shfl(u, cb + r2 + 1);
      s2 += Kt16[r2 + 2] * __shfl(u, cb + r2 + 2);
      s3 += Kt16[r2 + 3] * __shfl(u, cb + r2 + 3);
    }
    float sv = (s0 + s1) + (s2 + s3);
    sv += __shfl_xor(sv, 32);
    float v = q_l / (sv + 1e-16f);
    for (int it = 1; it < 200; ++it) {
      float uprev = u, vprev = v;
      float a0 = 0.f, a1 = 0.f, a2 = 0.f, a3 = 0.f;
#pragma unroll
      for (int c2 = 0; c2 < 16; c2 += 4) {
        a0 += Kr16[c2]     * __shfl(v, cb + c2);
        a1 += Kr16[c2 + 1] * __shfl(v, cb + c2 + 1);
        a2 += Kr16[c2 + 2] * __shfl(v, cb + c2 + 2);
        a3 += Kr16[c2 + 3] * __shfl(v, cb + c2 + 3);
      }
      float au = (a0 + a1) + (a2 + a3);
      au += __shfl_xor(au, 32);
      u = p_l / (au + 1e-16f);
      a0 = 0.f; a1 = 0.f; a2 = 0.f; a3 = 0.f;
#pragma unroll
      for (int r2 = 0; r2 < 16; r2 += 4) {
        a0 += Kt16[r2]     * __shfl(u, cb + r2);
        a1 += Kt16[r2 + 1] * __shfl(u, cb + r2 + 1);
        a2 += Kt16[r2 + 2] * __shfl(u, cb + r2 + 2);
        a3 += Kt16[r2 + 3] * __shfl(u, cb + r2 + 3);
      }
      float bv = (a0 + a1) + (a2 + a3);
      bv += __shfl_xor(bv, 32);
      v = q_l / (bv + 1e-16f);
      if (__all(u == uprev && v == vprev)) break;
    }
    if (t < 32) { uuS[t] = u; vvS[t] = v; }
  }
  __syncthreads();
  // ---- loss over the nonzero 32x32 block ----
  float lacc = 0.f;
#pragma unroll
  for (int q8 = 0; q8 < 4; ++q8) {
    int l = q8 * 256 + t;
    int i = l >> 5, j = l & 31;
    lacc += uuS[i] * G[i][32 + j] * vvS[j] * Cm[i][32 + j];
  }
  lacc = waveSum(lacc);
  if ((t & 63) == 0) red[t >> 6] = lacc;
  __syncthreads();
  if (t == 0)
    atomicAdd(&scal[3], (red[0] + red[1] + red[2] + red[3]) * (1.0f / 256.0f));
}

// ---------------- sum(W^2) ----------------
__global__ void k_wreg(const float* __restrict__ W, float* __restrict__ scal) {
  __shared__ float red[4];
  int t = threadIdx.x;
  int base = blockIdx.x * 2048;
  float ss = 0.f;
#pragma unroll
  for (int p = 0; p < 8; ++p) {
    float v = W[base + p * 256 + t];
    ss += v * v;
  }
  ss = waveSum(ss);
  if ((t & 63) == 0) red[t >> 6] = ss;
  __syncthreads();
  if (t == 0) atomicAdd(&scal[4], red[0] + red[1] + red[2] + red[3]);
}

// ---------------- final combine ----------------
__global__ void k_combine(const float* __restrict__ mu_t, const float* __restrict__ colsum,
                          const float* __restrict__ scal, float* __restrict__ out) {
  __shared__ float red[8];
  int t = threadIdx.x;  // 512
  float dm = mu_t[t] - colsum[t] * (1.0f / 50000.0f);
  float v = dm * dm;
  v = waveSum(v);
  if ((t & 63) == 0) red[t >> 6] = v;
  __syncthreads();
  if (t == 0) {
    float term_mean = 0.f;
    for (int i = 0; i < 8; ++i) term_mean += red[i];
    float trCT = scal[0] * (1.0f / 255.0f);
    float trCX = scal[1];
    float S = scal[2];
    float term_cov = trCX * 1.001f + trCT * 1.001f - 2.0f * S;
    term_cov = fmaxf(term_cov, 0.f);
    float loss_dist = term_mean + term_cov;
    float loss_knn = scal[3];
    float loss_reg = 0.5f * scal[4];
    out[0] = loss_dist + loss_knn + 1e-4f * loss_reg;
    out[1] = loss_dist;
    out[2] = loss_knn;
  }
}

extern "C" void kernel_launch(void* const* d_in, const int* in_sizes, int n_in,
                              void* d_out, int out_size, void* d_ws, size_t ws_size,
                              hipStream_t stream) {
  const float* q = (const float*)d_in[0];
  const int* qidx = (const int*)d_in[1];
  const float* W = (const float*)d_in[2];
  const float* X = (const float*)d_in[3];
  const int* pre_idx = (const int*)d_in[4];
  const float* prew = (const float*)d_in[5];
  float* out = (float*)d_out;
  float* ws = (float*)d_ws;

  float* scal = ws + OFF_SC;
  float* colsum = ws + OFF_CS;
  float* colss = ws + OFF_CSS;
  float* T = ws + OFF_T;
  float* Tc = ws + OFF_TC;
  float* H = ws + OFF_H;
  float* mu_t = ws + OFF_MUT;
  float* xsq = ws + OFF_XSQ;
  int* runi = (int*)(ws + OFF_RUNI);
  float* postw = ws + OFF_PW;
  float* prewn = ws + OFF_PRW;
  float* V = ws + OFF_D2;
  float* UUT = ws + OFF_UUT;
  float* TcTc = ws + OFF_TCTC;
  float* wv = ws + OFF_W;
  float* m = ws + OFF_M;
  float* candv = ws + OFF_P;              // 256*256 floats; dead before NS Y2/Z2
  int* candi = (int*)(ws + OFF_P + 65536);

  hipMemsetAsync(d_ws, 0, (size_t)ZERO_F * 4, stream);

  // T = q @ W
  k_g64_nn<<<dim3(8, 4), 256, 0, stream>>>(q, W, T, 512, 512, 512, 512, 1.0f);
  // X stats
  k_colstatX<<<256, 256, 0, stream>>>(X, colsum, colss);
  k_xsq<<<12500, 256, 0, stream>>>(X, xsq);
  // T stats
  k_colmeanT<<<1, 512, 0, stream>>>(T, mu_t);
  k_centerT<<<128, 256, 0, stream>>>(T, mu_t, Tc, scal);
  k_trCX<<<1, 512, 0, stream>>>(colsum, colss, scal);
  // V = T @ X^T (MFMA)
  k_vgemm<<<dim3(391, 2), 256, 0, stream>>>(T, X, V);
  k_vstats<<<196, 256, 0, stream>>>(V, m);
  // kNN top-32 from d2 = xsq - 2V (threshold-filter)
  k_topk_part<<<dim3(PARTS, 256), 256, 0, stream>>>(V, xsq, candv, candi);
  k_topk_final<<<256, 128, 0, stream>>>(candv, candi, runi);
  // H assembly
  k_g64_nt<<<dim3(4, 4), 256, 0, stream>>>(Tc, Tc, TcTc, 512, 512, 512, 256, 1.0f);
  k_wvec<<<1, 256, 0, stream>>>(T, colsum, wv);
  k_uut<<<dim3(3, 50), 256, 0, stream>>>(V, m, UUT);
  k_hfix<<<256, 256, 0, stream>>>(UUT, TcTc, wv, scal, H);
  // spectral sum via coupled Newton-Schulz, power-iter scaling
  {
    float* Y = ws + OFF_TC;
    float* Z = ws + OFF_TC + 65536;
    float* Y2 = ws + OFF_P;
    float* Z2 = ws + OFF_P + 65536;
    float* Pm = ws + OFF_G;
    k_power<<<1, 256, 0, stream>>>(H, scal);
    k_nsinit<<<256, 256, 0, stream>>>(H, scal, Y, Z);
    for (int it = 0; it < NS_ITERS; ++it) {
      k_g64_nn<<<dim3(4, 4), 256, 0, stream>>>(Z, Y, Pm, 256, 256, 256, 256, 1.0f);
      k_ns_upd<<<dim3(4, 4, 2), 256, 0, stream>>>(Y, Z, Pm, Y2, Z2);
      float* tmp = Y; Y = Y2; Y2 = tmp;
      tmp = Z; Z = Z2; Z2 = tmp;
    }
    k_ns_trace<<<1, 256, 0, stream>>>(Y, scal);
  }
  // kNN OT loss
  k_l2soft<<<256, 64, 0, stream>>>(T, X, runi, qidx, prew, postw, prewn);
  k_batch<<<256, 256, 0, stream>>>(X, qidx, pre_idx, runi, prewn, postw, scal);
  k_wreg<<<128, 256, 0, stream>>>(W, scal);
  k_combine<<<1, 512, 0, stream>>>(mu_t, colsum, scal, out);
}

// Round 3
// 1015.902 us; speedup vs baseline: 1.3248x; 1.1917x over previous
//
#include <hip/hip_runtime.h>
#include <float.h>
#include <math.h>

// Problem constants
#define BB 256
#define DD 512
#define NN 50000
#define KK 32
#define NS_ITERS 11
#define PARTS 8
#define PCH 6250

// Workspace layout (float offsets)
#define OFF_G     0         // 1M-float region: UUT(65536) + TcTc(65536) + w(256) + m(50000); NS Pm reuses +0
#define OFF_SC    262144    // 64 scalars: 0=sumTc2 1=trCX 2=S_total 3=knn 4=wreg 5=s_ns 6=wsum
#define OFF_CS    262208    // 512 colsum X
#define OFF_CSS   262720    // 512 colsumsq X
#define ZERO_F    263232    // floats to memset
#define OFF_T     263232    // 256*512
#define OFF_TC    394304    // 256*512 Tc; later NS Y/Z
#define OFF_P     525376    // 256*512: top-k cand buffers; later NS Y2/Z2
#define OFF_H     656448    // 256*256
#define OFF_XSQ   723008    // 50000
#define OFF_RUNI  781200    // 256*32 (int)
#define OFF_PW    789392    // 256*32 post_w
#define OFF_PRW   797584    // 256*32 pre_w normalized
#define OFF_D2    805776    // V = T@X^T  (256*50000)

#define OFF_UUT   (OFF_G)
#define OFF_TCTC  (OFF_G + 65536)
#define OFF_W     (OFF_G + 131072)
#define OFF_M     (OFF_G + 131328)
#define OFF_MUT   (OFF_G + 200000)   // 512 raw col sums of T (zeroed region; free after m)

typedef __attribute__((ext_vector_type(8))) short bf16x8;
typedef __attribute__((ext_vector_type(4))) float f32x4;

__device__ __forceinline__ float waveSum(float v) {
#pragma unroll
  for (int off = 32; off > 0; off >>= 1) v += __shfl_xor(v, off);
  return v;
}

// split fp32x4 -> bf16 hi/lo, write packed pairs to LDS at short-offset sa (16B-aligned rows)
__device__ __forceinline__ void cvt_write(float4 v, unsigned short* hi, unsigned short* lo, int sa) {
  unsigned int b0 = __float_as_uint(v.x), b1 = __float_as_uint(v.y);
  unsigned int b2 = __float_as_uint(v.z), b3 = __float_as_uint(v.w);
  unsigned int h0 = b0 & 0xffff0000u, h1 = b1 & 0xffff0000u;
  unsigned int h2 = b2 & 0xffff0000u, h3 = b3 & 0xffff0000u;
  float l0 = v.x - __uint_as_float(h0), l1 = v.y - __uint_as_float(h1);
  float l2 = v.z - __uint_as_float(h2), l3 = v.w - __uint_as_float(h3);
  *(unsigned int*)&hi[sa]     = (h0 >> 16) | h1;
  *(unsigned int*)&hi[sa + 2] = (h2 >> 16) | h3;
  *(unsigned int*)&lo[sa]     = (__float_as_uint(l0) >> 16) | (__float_as_uint(l1) & 0xffff0000u);
  *(unsigned int*)&lo[sa + 2] = (__float_as_uint(l2) >> 16) | (__float_as_uint(l3) & 0xffff0000u);
}

// scalar fp32 -> bf16 hi/lo split
__device__ __forceinline__ void cvt1(float x, unsigned short* hp, unsigned short* lp) {
  unsigned int bb = __float_as_uint(x);
  unsigned int hb = bb & 0xffff0000u;
  float lo = x - __uint_as_float(hb);
  *hp = (unsigned short)(hb >> 16);
  *lp = (unsigned short)(__float_as_uint(lo) >> 16);
}

// ---------------- generic 64x64-tile GEMM, C = scale * A @ B (nn) ----------------
__global__ void __launch_bounds__(256) k_g64_nn(const float* __restrict__ A,
                                                const float* __restrict__ B,
                                                float* __restrict__ C,
                                                int K, int lda, int ldb, int ldc, float scale) {
  __shared__ float As[64][65], Bs[64][65];
  int m0 = blockIdx.y * 64, n0 = blockIdx.x * 64;
  int t = threadIdx.x, tr = t >> 4, tc = t & 15;
  float acc[4][4] = {{0.f}};
  for (int k0 = 0; k0 < K; k0 += 64) {
#pragma unroll
    for (int p = 0; p < 16; ++p) {
      int l = t + 256 * p;
      int r = l >> 6, c = l & 63;
      As[r][c] = A[(m0 + r) * lda + k0 + c];
      Bs[r][c] = B[(k0 + r) * ldb + n0 + c];
    }
    __syncthreads();
#pragma unroll 16
    for (int kk = 0; kk < 64; ++kk) {
      float a[4], b[4];
#pragma unroll
      for (int u = 0; u < 4; ++u) a[u] = As[tr + 16 * u][kk];
#pragma unroll
      for (int v = 0; v < 4; ++v) b[v] = Bs[kk][tc + 16 * v];
#pragma unroll
      for (int u = 0; u < 4; ++u)
#pragma unroll
        for (int v = 0; v < 4; ++v) acc[u][v] += a[u] * b[v];
    }
    __syncthreads();
  }
#pragma unroll
  for (int u = 0; u < 4; ++u)
#pragma unroll
    for (int v = 0; v < 4; ++v)
      C[(m0 + tr + 16 * u) * ldc + n0 + tc + 16 * v] = acc[u][v] * scale;
}

// ---------------- generic 64x64-tile GEMM, C = scale * A @ B^T (nt) ----------------
__global__ void __launch_bounds__(256) k_g64_nt(const float* __restrict__ A,
                                                const float* __restrict__ B,
                                                float* __restrict__ C,
                                                int K, int lda, int ldb, int ldc, float scale) {
  __shared__ float As[64][65], Bs[64][65];
  int m0 = blockIdx.y * 64, n0 = blockIdx.x * 64;
  int t = threadIdx.x, tr = t >> 4, tc = t & 15;
  float acc[4][4] = {{0.f}};
  for (int k0 = 0; k0 < K; k0 += 64) {
#pragma unroll
    for (int p = 0; p < 16; ++p) {
      int l = t + 256 * p;
      int r = l >> 6, c = l & 63;
      As[r][c] = A[(m0 + r) * lda + k0 + c];
      Bs[r][c] = B[(n0 + r) * ldb + k0 + c];
    }
    __syncthreads();
#pragma unroll 16
    for (int kk = 0; kk < 64; ++kk) {
      float a[4], b[4];
#pragma unroll
      for (int u = 0; u < 4; ++u) a[u] = As[tr + 16 * u][kk];
#pragma unroll
      for (int v = 0; v < 4; ++v) b[v] = Bs[tc + 16 * v][kk];
#pragma unroll
      for (int u = 0; u < 4; ++u)
#pragma unroll
        for (int v = 0; v < 4; ++v) acc[u][v] += a[u] * b[v];
    }
    __syncthreads();
  }
#pragma unroll
  for (int u = 0; u < 4; ++u)
#pragma unroll
    for (int v = 0; v < 4; ++v)
      C[(m0 + tr + 16 * u) * ldc + n0 + tc + 16 * v] = acc[u][v] * scale;
}

// ---------------- V = T @ X^T  (MFMA bf16-split, on-the-fly conversion) ----------------
__global__ void __launch_bounds__(256) k_vgemm(const float* __restrict__ T,
                                               const float* __restrict__ X,
                                               float* __restrict__ V) {
  __shared__ unsigned short Ah[128 * 72], Al[128 * 72], Bh[128 * 72], Bl[128 * 72];
  int bj = blockIdx.x, bi = blockIdx.y;
  int t = threadIdx.x;
  int wave = t >> 6, lane = t & 63;
  int m0 = (wave >> 1) * 64, n0 = (wave & 1) * 64;
  int lrow = lane & 15, lq = lane >> 4;
  f32x4 acc[4][4] = {};
  for (int kc = 0; kc < 512; kc += 64) {
#pragma unroll
    for (int f = 0; f < 8; ++f) {
      int lin = f * 256 + t;
      int r = lin >> 4, c4 = lin & 15;
      int sa = r * 72 + c4 * 4;
      float4 va = *(const float4*)&T[(bi * 128 + r) * 512 + kc + c4 * 4];
      cvt_write(va, Ah, Al, sa);
      int jg = bj * 128 + r;
      float4 vb = {0.f, 0.f, 0.f, 0.f};
      if (jg < NN) vb = *(const float4*)&X[(size_t)jg * 512 + kc + c4 * 4];
      cvt_write(vb, Bh, Bl, sa);
    }
    __syncthreads();
#pragma unroll
    for (int ks = 0; ks < 2; ++ks) {
      int kb = ks * 32 + lq * 8;
      bf16x8 ah[4], al[4], bh[4], bl[4];
#pragma unroll
      for (int mi = 0; mi < 4; ++mi) {
        int ro = (m0 + mi * 16 + lrow) * 72 + kb;
        ah[mi] = *(const bf16x8*)&Ah[ro];
        al[mi] = *(const bf16x8*)&Al[ro];
      }
#pragma unroll
      for (int nj = 0; nj < 4; ++nj) {
        int ro = (n0 + nj * 16 + lrow) * 72 + kb;
        bh[nj] = *(const bf16x8*)&Bh[ro];
        bl[nj] = *(const bf16x8*)&Bl[ro];
      }
#pragma unroll
      for (int mi = 0; mi < 4; ++mi)
#pragma unroll
        for (int nj = 0; nj < 4; ++nj) {
          acc[mi][nj] = __builtin_amdgcn_mfma_f32_16x16x32_bf16(ah[mi], bh[nj], acc[mi][nj], 0, 0, 0);
          acc[mi][nj] = __builtin_amdgcn_mfma_f32_16x16x32_bf16(ah[mi], bl[nj], acc[mi][nj], 0, 0, 0);
          acc[mi][nj] = __builtin_amdgcn_mfma_f32_16x16x32_bf16(al[mi], bh[nj], acc[mi][nj], 0, 0, 0);
        }
    }
    __syncthreads();
  }
#pragma unroll
  for (int mi = 0; mi < 4; ++mi)
#pragma unroll
    for (int nj = 0; nj < 4; ++nj)
#pragma unroll
      for (int r = 0; r < 4; ++r) {
        int row = bi * 128 + m0 + mi * 16 + lq * 4 + r;
        int col = bj * 128 + n0 + nj * 16 + lrow;
        if (col < NN) V[(size_t)row * NN + col] = acc[mi][nj][r];
      }
}

// ---------------- UUT += U @ U^T, U = V - m (MFMA bf16-split, split-K atomic) ----------------
__global__ void __launch_bounds__(256) k_uut(const float* __restrict__ V,
                                             const float* __restrict__ m,
                                             float* __restrict__ UUT) {
  __shared__ unsigned short Ah[128 * 72], Al[128 * 72], Bh[128 * 72], Bl[128 * 72];
  const int pi_[3] = {0, 0, 1}, pj_[3] = {0, 1, 1};
  int bi = pi_[blockIdx.x], bj = pj_[blockIdx.x];
  int j0 = blockIdx.y * 1000, jlim = j0 + 1000;
  int t = threadIdx.x;
  int wave = t >> 6, lane = t & 63;
  int m0 = (wave >> 1) * 64, n0 = (wave & 1) * 64;
  int lrow = lane & 15, lq = lane >> 4;
  f32x4 acc[4][4] = {};
  for (int ch = 0; ch < 16; ++ch) {
    int jc = j0 + ch * 64;
#pragma unroll
    for (int f = 0; f < 8; ++f) {
      int lin = f * 256 + t;
      int r = lin >> 4, c4 = lin & 15;
      int sa = r * 72 + c4 * 4;
      int jb = jc + c4 * 4;
      float4 va = {0.f, 0.f, 0.f, 0.f}, vb = {0.f, 0.f, 0.f, 0.f};
      if (jb < jlim) {
        float4 mm = *(const float4*)&m[jb];
        va = *(const float4*)&V[(size_t)(bi * 128 + r) * NN + jb];
        vb = *(const float4*)&V[(size_t)(bj * 128 + r) * NN + jb];
        va.x -= mm.x; va.y -= mm.y; va.z -= mm.z; va.w -= mm.w;
        vb.x -= mm.x; vb.y -= mm.y; vb.z -= mm.z; vb.w -= mm.w;
      }
      cvt_write(va, Ah, Al, sa);
      cvt_write(vb, Bh, Bl, sa);
    }
    __syncthreads();
#pragma unroll
    for (int ks = 0; ks < 2; ++ks) {
      int kb = ks * 32 + lq * 8;
      bf16x8 ah[4], al[4], bh[4], bl[4];
#pragma unroll
      for (int mi = 0; mi < 4; ++mi) {
        int ro = (m0 + mi * 16 + lrow) * 72 + kb;
        ah[mi] = *(const bf16x8*)&Ah[ro];
        al[mi] = *(const bf16x8*)&Al[ro];
      }
#pragma unroll
      for (int nj = 0; nj < 4; ++nj) {
        int ro = (n0 + nj * 16 + lrow) * 72 + kb;
        bh[nj] = *(const bf16x8*)&Bh[ro];
        bl[nj] = *(const bf16x8*)&Bl[ro];
      }
#pragma unroll
      for (int mi = 0; mi < 4; ++mi)
#pragma unroll
        for (int nj = 0; nj < 4; ++nj) {
          acc[mi][nj] = __builtin_amdgcn_mfma_f32_16x16x32_bf16(ah[mi], bh[nj], acc[mi][nj], 0, 0, 0);
          acc[mi][nj] = __builtin_amdgcn_mfma_f32_16x16x32_bf16(ah[mi], bl[nj], acc[mi][nj], 0, 0, 0);
          acc[mi][nj] = __builtin_amdgcn_mfma_f32_16x16x32_bf16(al[mi], bh[nj], acc[mi][nj], 0, 0, 0);
        }
    }
    __syncthreads();
  }
#pragma unroll
  for (int mi = 0; mi < 4; ++mi)
#pragma unroll
    for (int nj = 0; nj < 4; ++nj)
#pragma unroll
      for (int r = 0; r < 4; ++r) {
        int row = bi * 128 + m0 + mi * 16 + lq * 4 + r;
        int col = bj * 128 + n0 + nj * 16 + lrow;
        atomicAdd(&UUT[row * 256 + col], acc[mi][nj][r]);
      }
}

// ---------------- column sums & sumsq of X (float4, high-MLP, atomic) ----------------
// 250 blocks x 200 rows; thread (g = t>>7, c4 = (t&127)*4) strides 2 rows, unrolled.
__global__ void __launch_bounds__(256) k_colstatX(const float* __restrict__ X, float* __restrict__ colsum,
                                                  float* __restrict__ colss) {
  __shared__ float shs[512], shss[512];
  int b = blockIdx.x, t = threadIdx.x;
  int c4 = (t & 127) * 4, g = t >> 7;
  int r0 = b * 200 + g;
  float sx = 0, sy = 0, sz = 0, sw = 0;
  float qx = 0, qy = 0, qz = 0, qw = 0;
#pragma unroll 4
  for (int it = 0; it < 100; ++it) {
    float4 v = *(const float4*)&X[(size_t)(r0 + 2 * it) * 512 + c4];
    sx += v.x; sy += v.y; sz += v.z; sw += v.w;
    qx += v.x * v.x; qy += v.y * v.y; qz += v.z * v.z; qw += v.w * v.w;
  }
  if (g == 1) {
    int o = (t - 128) * 4;
    shs[o] = sx; shs[o + 1] = sy; shs[o + 2] = sz; shs[o + 3] = sw;
    shss[o] = qx; shss[o + 1] = qy; shss[o + 2] = qz; shss[o + 3] = qw;
  }
  __syncthreads();
  if (g == 0) {
    int o = t * 4;
    atomicAdd(&colsum[c4],     sx + shs[o]);
    atomicAdd(&colsum[c4 + 1], sy + shs[o + 1]);
    atomicAdd(&colsum[c4 + 2], sz + shs[o + 2]);
    atomicAdd(&colsum[c4 + 3], sw + shs[o + 3]);
    atomicAdd(&colss[c4],     qx + shss[o]);
    atomicAdd(&colss[c4 + 1], qy + shss[o + 1]);
    atomicAdd(&colss[c4 + 2], qz + shss[o + 2]);
    atomicAdd(&colss[c4 + 3], qw + shss[o + 3]);
  }
}

// ---------------- per-row squared norm of X ----------------
__global__ void k_xsq(const float* __restrict__ X, float* __restrict__ xsq) {
  int row = blockIdx.x * 4 + (threadIdx.x >> 6);
  int lane = threadIdx.x & 63;
  const float* Xr = X + (size_t)row * 512;
  float s = 0.f;
#pragma unroll
  for (int d = 0; d < 8; ++d) { float v = Xr[lane + 64 * d]; s += v * v; }
  s = waveSum(s);
  if (lane == 0) xsq[row] = s;
}

// ---------------- raw column sums of T (atomic partials; consumers divide by 256) ----------------
__global__ void k_colmeanT(const float* __restrict__ T, float* __restrict__ mu) {
  int c = threadIdx.x;  // 512
  int r0 = blockIdx.x * 16;
  float s = 0.f;
#pragma unroll
  for (int r = 0; r < 16; ++r) s += T[(r0 + r) * 512 + c];
  atomicAdd(&mu[c], s);
}

// ---------------- Tc = T - mu, accumulate sum(Tc^2) ----------------
__global__ void k_centerT(const float* __restrict__ T, const float* __restrict__ mu,
                          float* __restrict__ Tc, float* __restrict__ scal) {
  __shared__ float red[4];
  int t = threadIdx.x;
  int base = blockIdx.x * 1024;
  float ss = 0.f;
#pragma unroll
  for (int p = 0; p < 4; ++p) {
    int l = base + p * 256 + t;
    float v = T[l] - mu[l & 511] * (1.0f / 256.0f);
    Tc[l] = v;
    ss += v * v;
  }
  ss = waveSum(ss);
  if ((t & 63) == 0) red[t >> 6] = ss;
  __syncthreads();
  if (t == 0) atomicAdd(&scal[0], red[0] + red[1] + red[2] + red[3]);
}

// ---------------- trace of cov(X) ----------------
__global__ void k_trCX(const float* __restrict__ colsum, const float* __restrict__ colss,
                       float* __restrict__ scal) {
  __shared__ float red[8];
  int t = threadIdx.x;  // 512
  float mu = colsum[t] * (1.0f / 50000.0f);
  float v = (colss[t] - 50000.0f * mu * mu) * (1.0f / 49999.0f);
  v = waveSum(v);
  if ((t & 63) == 0) red[t >> 6] = v;
  __syncthreads();
  if (t == 0) {
    float s = 0;
    for (int i = 0; i < 8; ++i) s += red[i];
    scal[1] = s;
  }
}

// ---------------- colmeans of V -> m (row-split atomic partials) ----------------
__global__ void k_vstats(const float* __restrict__ V, float* __restrict__ m) {
  int j = blockIdx.x * 256 + threadIdx.x;
  if (j >= NN) return;
  int i0 = blockIdx.y * 32;
  float s = 0.f;
#pragma unroll 8
  for (int i = 0; i < 32; ++i) s += V[(size_t)(i0 + i) * NN + j];
  atomicAdd(&m[j], s * (1.0f / 256.0f));
}

// ---------------- w_i = T_i . muX (raw), wsum -> scal[6]; mean folded into k_hfix ----------------
__global__ void __launch_bounds__(256) k_wvec(const float* __restrict__ T,
                                              const float* __restrict__ colsum,
                                              float* __restrict__ w, float* __restrict__ scal) {
  __shared__ float cs[512];
  int t = threadIdx.x, lane = t & 63, wv_ = t >> 6;
  cs[t] = colsum[t] * (1.0f / 50000.0f);
  cs[t + 256] = colsum[t + 256] * (1.0f / 50000.0f);
  __syncthreads();
  int rbase = blockIdx.x * 32 + wv_ * 8;
  float tot = 0.f;
  for (int rr = 0; rr < 8; ++rr) {
    int row = rbase + rr;
    float a = 0.f;
#pragma unroll
    for (int d = 0; d < 8; ++d) a += T[row * 512 + lane + 64 * d] * cs[lane + 64 * d];
    a = waveSum(a);
    if (lane == 0) { w[row] = a; tot += a; }
  }
  if (lane == 0) atomicAdd(&scal[6], tot);
}

// ---------------- H = (UUT - N (w-wm)(w-wm)^T)/(49999*255) + rhoX * TcTc/255 ----------------
__global__ void k_hfix(const float* __restrict__ UUT, const float* __restrict__ TcTc,
                       const float* __restrict__ w, const float* __restrict__ scal,
                       float* __restrict__ H) {
  int l = blockIdx.x * 256 + threadIdx.x;
  int i = l >> 8, j = l & 255;
  float u = (i >= 128 && j < 128) ? UUT[j * 256 + i] : UUT[i * 256 + j];
  float rho = scal[1] * (1e-3f / 512.0f);
  float wm = scal[6] * (1.0f / 256.0f);
  float wi = w[i] - wm, wj = w[j] - wm;
  H[l] = (u - 50000.0f * wi * wj) * (1.0f / (49999.0f * 255.0f))
       + rho * TcTc[i * 256 + j] * (1.0f / 255.0f);
}

// ---------------- power iteration: scal[5] = safe lambda_max bound of H' ----------------
__global__ void __launch_bounds__(256) k_power(const float* __restrict__ H,
                                               float* __restrict__ scal) {
  __shared__ float v[256], nv[256], red[4];
  int t = threadIdx.x;
  float rt = scal[0] * (1.0f / 255.0f) * (1e-3f / 512.0f);
  v[t] = 1.0f;
  __syncthreads();
  float n2 = 256.0f, n3 = 256.0f;
  for (int it = 0; it < 3; ++it) {
    float s = rt * v[t];
    for (int j = 0; j < 256; ++j) s += H[t * 256 + j] * v[j];
    nv[t] = s;
    float ss = waveSum(s * s);
    if ((t & 63) == 0) red[t >> 6] = ss;
    __syncthreads();
    float norm2 = red[0] + red[1] + red[2] + red[3];
    if (it == 1) n2 = norm2;
    if (it == 2) n3 = norm2;
    v[t] = nv[t];
    __syncthreads();
  }
  float d = H[t * 256 + t] + rt;
#pragma unroll
  for (int off = 32; off > 0; off >>= 1) d = fmaxf(d, __shfl_xor(d, off));
  if ((t & 63) == 0) red[t >> 6] = d;
  __syncthreads();
  if (t == 0) {
    float lam = sqrtf(n3 / n2);
    float md = fmaxf(fmaxf(red[0], red[1]), fmaxf(red[2], red[3]));
    scal[5] = fmaxf(1.3f * lam, md);
  }
}

// ---------------- Y0 = (H + rt I)/s, Z0 = I ----------------
__global__ void k_nsinit(const float* __restrict__ H, const float* __restrict__ scal,
                         float* __restrict__ Y, float* __restrict__ Z) {
  int l = blockIdx.x * 256 + threadIdx.x;
  int i = l >> 8, j = l & 255;
  float rt = scal[0] * (1.0f / 255.0f) * (1e-3f / 512.0f);
  float inv = 1.0f / scal[5];
  Y[l] = (H[l] + ((i == j) ? rt : 0.f)) * inv;
  Z[l] = (i == j) ? 1.0f : 0.f;
}

// ---------------- NS: P = Z @ Y (MFMA bf16-split, nn, 64x64 tiles) ----------------
__global__ void __launch_bounds__(256) k_nsp(const float* __restrict__ Z,
                                             const float* __restrict__ Y,
                                             float* __restrict__ P) {
  __shared__ unsigned short Ah[64 * 72], Al[64 * 72], Bh[64 * 72], Bl[64 * 72];
  int n0b = blockIdx.x * 64, m0b = blockIdx.y * 64;
  int t = threadIdx.x, wave = t >> 6, lane = t & 63;
  int m0 = (wave >> 1) * 32, n0 = (wave & 1) * 32;
  int lrow = lane & 15, lq = lane >> 4;
  f32x4 acc[2][2] = {};
  for (int k0 = 0; k0 < 256; k0 += 64) {
#pragma unroll
    for (int f = 0; f < 4; ++f) {
      int lin = f * 256 + t;
      int r = lin >> 4, c4 = (lin & 15) * 4;
      float4 va = *(const float4*)&Z[(m0b + r) * 256 + k0 + c4];
      cvt_write(va, Ah, Al, r * 72 + c4);
      float4 vb = *(const float4*)&Y[(k0 + r) * 256 + n0b + c4];
      cvt1(vb.x, &Bh[(c4 + 0) * 72 + r], &Bl[(c4 + 0) * 72 + r]);
      cvt1(vb.y, &Bh[(c4 + 1) * 72 + r], &Bl[(c4 + 1) * 72 + r]);
      cvt1(vb.z, &Bh[(c4 + 2) * 72 + r], &Bl[(c4 + 2) * 72 + r]);
      cvt1(vb.w, &Bh[(c4 + 3) * 72 + r], &Bl[(c4 + 3) * 72 + r]);
    }
    __syncthreads();
#pragma unroll
    for (int ks = 0; ks < 2; ++ks) {
      int kb = ks * 32 + lq * 8;
      bf16x8 ah[2], al2[2], bh[2], bl2[2];
#pragma unroll
      for (int mi = 0; mi < 2; ++mi) {
        int ro = (m0 + mi * 16 + lrow) * 72 + kb;
        ah[mi] = *(const bf16x8*)&Ah[ro];
        al2[mi] = *(const bf16x8*)&Al[ro];
      }
#pragma unroll
      for (int nj = 0; nj < 2; ++nj) {
        int ro = (n0 + nj * 16 + lrow) * 72 + kb;
        bh[nj] = *(const bf16x8*)&Bh[ro];
        bl2[nj] = *(const bf16x8*)&Bl[ro];
      }
#pragma unroll
      for (int mi = 0; mi < 2; ++mi)
#pragma unroll
        for (int nj = 0; nj < 2; ++nj) {
          acc[mi][nj] = __builtin_amdgcn_mfma_f32_16x16x32_bf16(ah[mi], bh[nj], acc[mi][nj], 0, 0, 0);
          acc[mi][nj] = __builtin_amdgcn_mfma_f32_16x16x32_bf16(ah[mi], bl2[nj], acc[mi][nj], 0, 0, 0);
          acc[mi][nj] = __builtin_amdgcn_mfma_f32_16x16x32_bf16(al2[mi], bh[nj], acc[mi][nj], 0, 0, 0);
        }
    }
    __syncthreads();
  }
#pragma unroll
  for (int mi = 0; mi < 2; ++mi)
#pragma unroll
    for (int nj = 0; nj < 2; ++nj)
#pragma unroll
      for (int r = 0; r < 4; ++r) {
        int row = m0b + m0 + mi * 16 + lq * 4 + r;
        int col = n0b + n0 + nj * 16 + lrow;
        P[row * 256 + col] = acc[mi][nj][r];
      }
}

// ---------------- NS update: O = 1.5 D - 0.5 A@B (MFMA bf16-split, nn) ----------------
__global__ void __launch_bounds__(256) k_nsu(const float* __restrict__ Y, const float* __restrict__ Z,
                                             const float* __restrict__ Pm,
                                             float* __restrict__ Yn, float* __restrict__ Zn) {
  __shared__ unsigned short Ah[64 * 72], Al[64 * 72], Bh[64 * 72], Bl[64 * 72];
  int zz = blockIdx.z;
  const float* A = zz ? Pm : Y;
  const float* B = zz ? Z : Pm;
  const float* D = zz ? Z : Y;
  float* O = zz ? Zn : Yn;
  int n0b = blockIdx.x * 64, m0b = blockIdx.y * 64;
  int t = threadIdx.x, wave = t >> 6, lane = t & 63;
  int m0 = (wave >> 1) * 32, n0 = (wave & 1) * 32;
  int lrow = lane & 15, lq = lane >> 4;
  f32x4 acc[2][2] = {};
  for (int k0 = 0; k0 < 256; k0 += 64) {
#pragma unroll
    for (int f = 0; f < 4; ++f) {
      int lin = f * 256 + t;
      int r = lin >> 4, c4 = (lin & 15) * 4;
      float4 va = *(const float4*)&A[(m0b + r) * 256 + k0 + c4];
      cvt_write(va, Ah, Al, r * 72 + c4);
      float4 vb = *(const float4*)&B[(k0 + r) * 256 + n0b + c4];
      cvt1(vb.x, &Bh[(c4 + 0) * 72 + r], &Bl[(c4 + 0) * 72 + r]);
      cvt1(vb.y, &Bh[(c4 + 1) * 72 + r], &Bl[(c4 + 1) * 72 + r]);
      cvt1(vb.z, &Bh[(c4 + 2) * 72 + r], &Bl[(c4 + 2) * 72 + r]);
      cvt1(vb.w, &Bh[(c4 + 3) * 72 + r], &Bl[(c4 + 3) * 72 + r]);
    }
    __syncthreads();
#pragma unroll
    for (int ks = 0; ks < 2; ++ks) {
      int kb = ks * 32 + lq * 8;
      bf16x8 ah[2], al2[2], bh[2], bl2[2];
#pragma unroll
      for (int mi = 0; mi < 2; ++mi) {
        int ro = (m0 + mi * 16 + lrow) * 72 + kb;
        ah[mi] = *(const bf16x8*)&Ah[ro];
        al2[mi] = *(const bf16x8*)&Al[ro];
      }
#pragma unroll
      for (int nj = 0; nj < 2; ++nj) {
        int ro = (n0 + nj * 16 + lrow) * 72 + kb;
        bh[nj] = *(const bf16x8*)&Bh[ro];
        bl2[nj] = *(const bf16x8*)&Bl[ro];
      }
#pragma unroll
      for (int mi = 0; mi < 2; ++mi)
#pragma unroll
        for (int nj = 0; nj < 2; ++nj) {
          acc[mi][nj] = __builtin_amdgcn_mfma_f32_16x16x32_bf16(ah[mi], bh[nj], acc[mi][nj], 0, 0, 0);
          acc[mi][nj] = __builtin_amdgcn_mfma_f32_16x16x32_bf16(ah[mi], bl2[nj], acc[mi][nj], 0, 0, 0);
          acc[mi][nj] = __builtin_amdgcn_mfma_f32_16x16x32_bf16(al2[mi], bh[nj], acc[mi][nj], 0, 0, 0);
        }
    }
    __syncthreads();
  }
#pragma unroll
  for (int mi = 0; mi < 2; ++mi)
#pragma unroll
    for (int nj = 0; nj < 2; ++nj)
#pragma unroll
      for (int r = 0; r < 4; ++r) {
        int row = m0b + m0 + mi * 16 + lq * 4 + r;
        int col = n0b + n0 + nj * 16 + lrow;
        int idx = row * 256 + col;
        O[idx] = 1.5f * D[idx] - 0.5f * acc[mi][nj][r];
      }
}

// ---------------- S_total = sqrt(s)*tr(Y) + 256*sqrt(rt) ----------------
__global__ void k_ns_trace(const float* __restrict__ Y, float* __restrict__ scal) {
  __shared__ float red[4];
  int t = threadIdx.x;  // 256
  float v = Y[t * 256 + t];
  v = waveSum(v);
  if ((t & 63) == 0) red[t >> 6] = v;
  __syncthreads();
  if (t == 0) {
    float tr = red[0] + red[1] + red[2] + red[3];
    float rt = scal[0] * (1.0f / 255.0f) * (1e-3f / 512.0f);
    scal[2] = sqrtf(scal[5]) * tr + 256.0f * sqrtf(rt);
  }
}

// ---------------- stage 1: threshold-filter exact top-32 per (query, 1/8-slice) ----------------
__global__ void __launch_bounds__(256) k_topk_part(const float* __restrict__ V,
                                                   const float* __restrict__ xsq,
                                                   float* __restrict__ candv,
                                                   int* __restrict__ candi) {
  __shared__ float bufv[512];
  __shared__ int bufi[512];
  __shared__ int lcount;
  __shared__ float tvs;
  __shared__ int tis;
  int part = blockIdx.x, q = blockIdx.y, t = threadIdx.x;
  int base = part * PCH;
  int lane = t & 63;
  if (t == 0) { lcount = 0; tvs = FLT_MAX; tis = 0x7fffffff; }
  __syncthreads();
  const float* rowV = V + (size_t)q * NN + base;
  const float* xs = xsq + base;

  auto flush = [&]() {
    __syncthreads();
    int c = lcount;
    for (int s = c + t; s < 512; s += 256) { bufv[s] = FLT_MAX; bufi[s] = 0x7fffffff; }
    __syncthreads();
    for (int ssz = 2; ssz <= 512; ssz <<= 1) {
      for (int st = ssz >> 1; st > 0; st >>= 1) {
        int i = 2 * t - (t & (st - 1));
        int j = i + st;
        bool up = ((i & ssz) == 0);
        float a = bufv[i], b = bufv[j];
        int ai = bufi[i], bi2 = bufi[j];
        bool agtb = (a > b) || (a == b && ai > bi2);
        if (agtb == up) { bufv[i] = b; bufv[j] = a; bufi[i] = bi2; bufi[j] = ai; }
        __syncthreads();
      }
    }
    if (t == 0) { lcount = 32; tvs = bufv[31]; tis = bufi[31]; }
    __syncthreads();
  };

  int ntile = (PCH + 255) >> 8;
  for (int tile = 0; tile < ntile; ++tile) {
    int j = tile * 256 + t;
    float val = 0.f; int idx = 0;
    bool pred = false;
    if (j < PCH) {
      val = xs[j] - 2.0f * rowV[j];
      idx = base + j;
      float tv = tvs; int ti = tis;
      pred = (val < tv) || (val == tv && idx < ti);
    }
    unsigned long long mask = __ballot(pred);
    if (mask) {
      int lead = __ffsll((unsigned long long)mask) - 1;
      int cnt = __popcll(mask);
      int basep = 0;
      if (lane == lead) basep = atomicAdd(&lcount, cnt);
      basep = __shfl(basep, lead);
      if (pred) {
        int off = __popcll(mask & ((1ull << lane) - 1ull));
        int slot = basep + off;
        bufv[slot] = val; bufi[slot] = idx;
      }
    }
    __syncthreads();
    if (lcount >= 256) flush();
  }
  flush();
  if (t < 32) {
    candv[(q * PARTS + part) * 32 + t] = bufv[t];
    candi[(q * PARTS + part) * 32 + t] = bufi[t];
  }
}

// ---------------- stage 2: bitonic-sort 256 candidates, emit top-32 indices ----------------
__global__ void __launch_bounds__(128) k_topk_final(const float* __restrict__ candv,
                                                    const int* __restrict__ candi,
                                                    int* __restrict__ runi) {
  __shared__ float v[256];
  __shared__ int ix[256];
  int q = blockIdx.x, t = threadIdx.x;
  v[t] = candv[q * 256 + t];
  v[t + 128] = candv[q * 256 + t + 128];
  ix[t] = candi[q * 256 + t];
  ix[t + 128] = candi[q * 256 + t + 128];
  __syncthreads();
  for (int ssz = 2; ssz <= 256; ssz <<= 1) {
    for (int st = ssz >> 1; st > 0; st >>= 1) {
      int i = 2 * t - (t & (st - 1));
      int j = i + st;
      bool up = ((i & ssz) == 0);
      float a = v[i], b = v[j];
      int ai = ix[i], bi = ix[j];
      bool agtb = (a > b) || (a == b && ai > bi);
      if (agtb == up) { v[i] = b; v[j] = a; ix[i] = bi; ix[j] = ai; }
      __syncthreads();
    }
  }
  if (t < 32) runi[q * 32 + t] = ix[t];
}

// ---------------- l2 to neighbors, softmax post_w, normalized pre_w ----------------
__global__ void __launch_bounds__(64) k_l2soft(const float* __restrict__ T, const float* __restrict__ X,
                                               const int* __restrict__ runi, const int* __restrict__ qidx,
                                               const float* __restrict__ prew, float* __restrict__ postw,
                                               float* __restrict__ prewn) {
  __shared__ float l2s[32];
  int b = blockIdx.x, lane = threadIdx.x;
  int qi = qidx[b];
  float pwv = (lane < 32) ? fmaxf(prew[qi * 32 + lane], 1e-8f) : 0.f;
  float psum = waveSum(pwv);
  if (lane < 32) prewn[b * 32 + lane] = pwv / psum;
  const float* Tb = T + b * 512;
  for (int n = 0; n < 32; ++n) {
    int nb = runi[b * 32 + n];
    const float* Xr = X + (size_t)nb * 512;
    float acc = 0.f;
#pragma unroll
    for (int d = 0; d < 8; ++d) {
      float df = Tb[lane + 64 * d] - Xr[lane + 64 * d];
      acc += df * df;
    }
    acc = waveSum(acc);
    if (lane == 0) l2s[n] = acc;
  }
  __syncthreads();
  float lg = (lane < 32) ? (-l2s[lane] * 10.0f) : -FLT_MAX;
  float mx = lg;
#pragma unroll
  for (int off = 32; off > 0; off >>= 1) mx = fmaxf(mx, __shfl_xor(mx, off));
  float e = (lane < 32) ? expf(lg - mx) : 0.f;
  float es = waveSum(e);
  float wv = e / es;
  wv = fmaxf(wv, 1e-8f);
  float ws2 = (lane < 32) ? wv : 0.f;
  ws2 = waveSum(ws2);
  if (lane < 32) postw[b * 32 + lane] = wv / ws2;
}

// ---------------- fused per-batch: Gram(MFMA) -> C -> median(radix-select) -> Sinkhorn -> loss ----
__global__ void __launch_bounds__(256) k_batch(const float* __restrict__ X, const int* __restrict__ qidx,
                                               const int* __restrict__ pre_idx, const int* __restrict__ runi,
                                               const float* __restrict__ prewn, const float* __restrict__ postw,
                                               float* __restrict__ scal) {
  __shared__ float G[64][65];
  __shared__ float Cm[64][65];
  __shared__ unsigned short Ah[64 * 72], Al[64 * 72];
  __shared__ int supp[64];
  __shared__ float uuS[32], vvS[32];
  __shared__ float red[4];
  __shared__ float medsh;
  __shared__ unsigned int hist[256];
  __shared__ unsigned int wtot[4];
  __shared__ unsigned int selp;
  __shared__ int selk;
  __shared__ unsigned int cw[4], mw[4];
  int b = blockIdx.x, t = threadIdx.x;
  int wave = t >> 6, lane = t & 63;
  if (t < 32) supp[t] = pre_idx[qidx[b] * 32 + t];
  else if (t < 64) supp[t] = runi[b * 32 + t - 32];
  if (t == 0) { selp = 0u; selk = 992; }
  __syncthreads();
  // ---- Gram G = S @ S^T via MFMA bf16-split (A = B) ----
  {
    int m0 = (wave >> 1) * 32, n0 = (wave & 1) * 32;
    int lrow = lane & 15, lq = lane >> 4;
    f32x4 acc[2][2] = {};
    for (int kc = 0; kc < 512; kc += 64) {
#pragma unroll
      for (int f = 0; f < 4; ++f) {
        int lin = f * 256 + t;
        int r = lin >> 4, c4 = lin & 15;
        float4 va = *(const float4*)&X[(size_t)supp[r] * 512 + kc + c4 * 4];
        cvt_write(va, Ah, Al, r * 72 + c4 * 4);
      }
      __syncthreads();
#pragma unroll
      for (int ks = 0; ks < 2; ++ks) {
        int kb = ks * 32 + lq * 8;
        bf16x8 ah[2], al[2], bh[2], bl[2];
#pragma unroll
        for (int mi = 0; mi < 2; ++mi) {
          int ro = (m0 + mi * 16 + lrow) * 72 + kb;
          ah[mi] = *(const bf16x8*)&Ah[ro];
          al[mi] = *(const bf16x8*)&Al[ro];
        }
#pragma unroll
        for (int nj = 0; nj < 2; ++nj) {
          int ro = (n0 + nj * 16 + lrow) * 72 + kb;
          bh[nj] = *(const bf16x8*)&Ah[ro];
          bl[nj] = *(const bf16x8*)&Al[ro];
        }
#pragma unroll
        for (int mi = 0; mi < 2; ++mi)
#pragma unroll
          for (int nj = 0; nj < 2; ++nj) {
            acc[mi][nj] = __builtin_amdgcn_mfma_f32_16x16x32_bf16(ah[mi], bh[nj], acc[mi][nj], 0, 0, 0);
            acc[mi][nj] = __builtin_amdgcn_mfma_f32_16x16x32_bf16(ah[mi], bl[nj], acc[mi][nj], 0, 0, 0);
            acc[mi][nj] = __builtin_amdgcn_mfma_f32_16x16x32_bf16(al[mi], bh[nj], acc[mi][nj], 0, 0, 0);
          }
      }
      __syncthreads();
    }
#pragma unroll
    for (int mi = 0; mi < 2; ++mi)
#pragma unroll
      for (int nj = 0; nj < 2; ++nj)
#pragma unroll
        for (int r = 0; r < 4; ++r)
          G[m0 + mi * 16 + lq * 4 + r][n0 + nj * 16 + lrow] = acc[mi][nj][r];
  }
  __syncthreads();
  // ---- C build (raw, unnormalized) ----
  for (int l = t; l < 4096; l += 256) {
    int i = l >> 6, j = l & 63;
    Cm[i][j] = fmaxf(G[i][i] + G[j][j] - 2.0f * G[i][j], 0.f);
  }
  __syncthreads();
  // ---- radix-select ranks 992 & 993 over upper triangle (2016 values) ----
  for (int pass = 0; pass < 4; ++pass) {
    int shift = 24 - 8 * pass;
    hist[t] = 0u;
    __syncthreads();
    for (int l = t; l < 4096; l += 256) {
      int i = l >> 6, j = l & 63;
      if (i < j) {
        unsigned int u = __float_as_uint(Cm[i][j]) & 0x7fffffffu;
        bool match = (pass == 0) || (((u ^ selp) >> (shift + 8)) == 0u);
        if (match) atomicAdd(&hist[(u >> shift) & 255], 1u);
      }
    }
    __syncthreads();
    unsigned int h = hist[t];
    unsigned int c = h;
#pragma unroll
    for (int off = 1; off < 64; off <<= 1) {
      unsigned int n = __shfl_up(c, off);
      if ((t & 63) >= off) c += n;
    }
    if ((t & 63) == 63) wtot[t >> 6] = c;
    __syncthreads();
    unsigned int offw = 0;
    for (int w2 = 0; w2 < (t >> 6); ++w2) offw += wtot[w2];
    c += offw;
    int k = selk;
    if ((int)c >= k && (int)(c - h) < k) {
      selk = k - (int)(c - h);
      selp = selp | ((unsigned int)t << shift);
    }
    __syncthreads();
  }
  {
    unsigned int target = selp;
    unsigned int cnt = 0, mn = 0xffffffffu;
    for (int l = t; l < 4096; l += 256) {
      int i = l >> 6, j = l & 63;
      if (i < j) {
        unsigned int u = __float_as_uint(Cm[i][j]) & 0x7fffffffu;
        if (u <= target) cnt++;
        else mn = (u < mn) ? u : mn;
      }
    }
#pragma unroll
    for (int off = 32; off > 0; off >>= 1) {
      cnt += __shfl_xor(cnt, off);
      unsigned int m2 = __shfl_xor(mn, off);
      mn = (m2 < mn) ? m2 : mn;
    }
    if (lane == 0) { cw[wave] = cnt; mw[wave] = mn; }
    __syncthreads();
    if (t == 0) {
      unsigned int ct = cw[0] + cw[1] + cw[2] + cw[3];
      unsigned int mt = mw[0];
      mt = (mw[1] < mt) ? mw[1] : mt;
      mt = (mw[2] < mt) ? mw[2] : mt;
      mt = (mw[3] < mt) ? mw[3] : mt;
      float v992 = __uint_as_float(target);
      float v993 = (ct >= 993u) ? v992 : __uint_as_float(mt);
      medsh = 0.5f * (v992 + v993) + 1e-8f;
    }
    __syncthreads();
  }
  // ---- normalize C, build K = exp(-10*C) ----
  float inv = 1.0f / medsh;
  for (int l = t; l < 4096; l += 256) {
    int i = l >> 6, j = l & 63;
    float cn = Cm[i][j] * inv;
    Cm[i][j] = cn;
    G[i][j] = expf(-cn * 10.0f);
  }
  __syncthreads();
  // ---- Sinkhorn, wave 0, half-wave split, early exit on bitwise fixed point ----
  if (wave == 0) {
    int half = lane >> 5;
    int l = lane & 31;
    int cb = half * 16;
    float p_l = prewn[b * 32 + l];
    float q_l = postw[b * 32 + l];
    float Kr16[16], Kt16[16];
#pragma unroll
    for (int c2 = 0; c2 < 16; ++c2) Kr16[c2] = G[l][32 + cb + c2];
#pragma unroll
    for (int r2 = 0; r2 < 16; ++r2) Kt16[r2] = G[cb + r2][32 + l];
    float r0 = 0.f;
#pragma unroll
    for (int c2 = 0; c2 < 32; ++c2) r0 += G[l][half * 32 + c2];
    r0 += __shfl_xor(r0, 32);
    float u = p_l / (r0 + 1e-16f);
    float s0 = 0.f, s1 = 0.f, s2 = 0.f, s3 = 0.f;
#pragma unroll
    for (int r2 = 0; r2 < 16; r2 += 4) {
      s0 += Kt16[r2]     * __shfl(u, cb + r2);
      s1 += Kt16[r2 + 1] * __shfl(u, cb + r2 + 1);
      s2 += Kt16[r2 + 2] * __shfl(u, cb + r2 + 2);
      s3 += Kt16[r2 + 3] * __shfl(u, cb + r2 + 3);
    }
    float sv = (s0 + s1) + (s2 + s3);
    sv += __shfl_xor(sv, 32);
    float v = q_l / (sv + 1e-16f);
    for (int it = 1; it < 200; ++it) {
      float uprev = u, vprev = v;
      float a0 = 0.f, a1 = 0.f, a2 = 0.f, a3 = 0.f;
#pragma unroll
      for (int c2 = 0; c2 < 16; c2 += 4) {
        a0 += Kr16[c2]     * __shfl(v, cb + c2);
        a1 += Kr16[c2 + 1] * __shfl(v, cb + c2 + 1);
        a2 += Kr16[c2 + 2] * __shfl(v, cb + c2 + 2);
        a3 += Kr16[c2 + 3] * __shfl(v, cb + c2 + 3);
      }
      float au = (a0 + a1) + (a2 + a3);
      au += __shfl_xor(au, 32);
      u = p_l / (au + 1e-16f);
      a0 = 0.f; a1 = 0.f; a2 = 0.f; a3 = 0.f;
#pragma unroll
      for (int r2 = 0; r2 < 16; r2 += 4) {
        a0 += Kt16[r2]     * __shfl(u, cb + r2);
        a1 += Kt16[r2 + 1] * __shfl(u, cb + r2 + 1);
        a2 += Kt16[r2 + 2] * __shfl(u, cb + r2 + 2);
        a3 += Kt16[r2 + 3] * __shfl(u, cb + r2 + 3);
      }
      float bv = (a0 + a1) + (a2 + a3);
      bv += __shfl_xor(bv, 32);
      v = q_l / (bv + 1e-16f);
      if (__all(u == uprev && v == vprev)) break;
    }
    if (t < 32) { uuS[t] = u; vvS[t] = v; }
  }
  __syncthreads();
  // ---- loss over the nonzero 32x32 block ----
  float lacc = 0.f;
#pragma unroll
  for (int q8 = 0; q8 < 4; ++q8) {
    int l = q8 * 256 + t;
    int i = l >> 5, j = l & 31;
    lacc += uuS[i] * G[i][32 + j] * vvS[j] * Cm[i][32 + j];
  }
  lacc = waveSum(lacc);
  if ((t & 63) == 0) red[t >> 6] = lacc;
  __syncthreads();
  if (t == 0)
    atomicAdd(&scal[3], (red[0] + red[1] + red[2] + red[3]) * (1.0f / 256.0f));
}

// ---------------- sum(W^2) ----------------
__global__ void k_wreg(const float* __restrict__ W, float* __restrict__ scal) {
  __shared__ float red[4];
  int t = threadIdx.x;
  int base = blockIdx.x * 2048;
  float ss = 0.f;
#pragma unroll
  for (int p = 0; p < 8; ++p) {
    float v = W[base + p * 256 + t];
    ss += v * v;
  }
  ss = waveSum(ss);
  if ((t & 63) == 0) red[t >> 6] = ss;
  __syncthreads();
  if (t == 0) atomicAdd(&scal[4], red[0] + red[1] + red[2] + red[3]);
}

// ---------------- final combine ----------------
__global__ void k_combine(const float* __restrict__ mu_t, const float* __restrict__ colsum,
                          const float* __restrict__ scal, float* __restrict__ out) {
  __shared__ float red[8];
  int t = threadIdx.x;  // 512
  float dm = mu_t[t] * (1.0f / 256.0f) - colsum[t] * (1.0f / 50000.0f);
  float v = dm * dm;
  v = waveSum(v);
  if ((t & 63) == 0) red[t >> 6] = v;
  __syncthreads();
  if (t == 0) {
    float term_mean = 0.f;
    for (int i = 0; i < 8; ++i) term_mean += red[i];
    float trCT = scal[0] * (1.0f / 255.0f);
    float trCX = scal[1];
    float S = scal[2];
    float term_cov = trCX * 1.001f + trCT * 1.001f - 2.0f * S;
    term_cov = fmaxf(term_cov, 0.f);
    float loss_dist = term_mean + term_cov;
    float loss_knn = scal[3];
    float loss_reg = 0.5f * scal[4];
    out[0] = loss_dist + loss_knn + 1e-4f * loss_reg;
    out[1] = loss_dist;
    out[2] = loss_knn;
  }
}

extern "C" void kernel_launch(void* const* d_in, const int* in_sizes, int n_in,
                              void* d_out, int out_size, void* d_ws, size_t ws_size,
                              hipStream_t stream) {
  const float* q = (const float*)d_in[0];
  const int* qidx = (const int*)d_in[1];
  const float* W = (const float*)d_in[2];
  const float* X = (const float*)d_in[3];
  const int* pre_idx = (const int*)d_in[4];
  const float* prew = (const float*)d_in[5];
  float* out = (float*)d_out;
  float* ws = (float*)d_ws;

  float* scal = ws + OFF_SC;
  float* colsum = ws + OFF_CS;
  float* colss = ws + OFF_CSS;
  float* T = ws + OFF_T;
  float* Tc = ws + OFF_TC;
  float* H = ws + OFF_H;
  float* mu_t = ws + OFF_MUT;
  float* xsq = ws + OFF_XSQ;
  int* runi = (int*)(ws + OFF_RUNI);
  float* postw = ws + OFF_PW;
  float* prewn = ws + OFF_PRW;
  float* V = ws + OFF_D2;
  float* UUT = ws + OFF_UUT;
  float* TcTc = ws + OFF_TCTC;
  float* wv = ws + OFF_W;
  float* m = ws + OFF_M;
  float* candv = ws + OFF_P;              // 256*256 floats; dead before NS Y2/Z2
  int* candi = (int*)(ws + OFF_P + 65536);

  hipMemsetAsync(d_ws, 0, (size_t)ZERO_F * 4, stream);

  // T = q @ W
  k_g64_nn<<<dim3(8, 4), 256, 0, stream>>>(q, W, T, 512, 512, 512, 512, 1.0f);
  // X stats
  k_colstatX<<<250, 256, 0, stream>>>(X, colsum, colss);
  k_xsq<<<12500, 256, 0, stream>>>(X, xsq);
  // T stats
  k_colmeanT<<<16, 512, 0, stream>>>(T, mu_t);
  k_centerT<<<128, 256, 0, stream>>>(T, mu_t, Tc, scal);
  k_trCX<<<1, 512, 0, stream>>>(colsum, colss, scal);
  // V = T @ X^T (MFMA)
  k_vgemm<<<dim3(391, 2), 256, 0, stream>>>(T, X, V);
  k_vstats<<<dim3(196, 8), 256, 0, stream>>>(V, m);
  // kNN top-32 from d2 = xsq - 2V (threshold-filter)
  k_topk_part<<<dim3(PARTS, 256), 256, 0, stream>>>(V, xsq, candv, candi);
  k_topk_final<<<256, 128, 0, stream>>>(candv, candi, runi);
  // H assembly
  k_g64_nt<<<dim3(4, 4), 256, 0, stream>>>(Tc, Tc, TcTc, 512, 512, 512, 256, 1.0f);
  k_wvec<<<8, 256, 0, stream>>>(T, colsum, wv, scal);
  k_uut<<<dim3(3, 50), 256, 0, stream>>>(V, m, UUT);
  k_hfix<<<256, 256, 0, stream>>>(UUT, TcTc, wv, scal, H);
  // spectral sum via coupled Newton-Schulz, power-iter scaling
  {
    float* Y = ws + OFF_TC;
    float* Z = ws + OFF_TC + 65536;
    float* Y2 = ws + OFF_P;
    float* Z2 = ws + OFF_P + 65536;
    float* Pm = ws + OFF_G;
    k_power<<<1, 256, 0, stream>>>(H, scal);
    k_nsinit<<<256, 256, 0, stream>>>(H, scal, Y, Z);
    for (int it = 0; it < NS_ITERS; ++it) {
      k_nsp<<<dim3(4, 4), 256, 0, stream>>>(Z, Y, Pm);
      k_nsu<<<dim3(4, 4, 2), 256, 0, stream>>>(Y, Z, Pm, Y2, Z2);
      float* tmp = Y; Y = Y2; Y2 = tmp;
      tmp = Z; Z = Z2; Z2 = tmp;
    }
    k_ns_trace<<<1, 256, 0, stream>>>(Y, scal);
  }
  // kNN OT loss
  k_l2soft<<<256, 64, 0, stream>>>(T, X, runi, qidx, prew, postw, prewn);
  k_batch<<<256, 256, 0, stream>>>(X, qidx, pre_idx, runi, prewn, postw, scal);
  k_wreg<<<128, 256, 0, stream>>>(W, scal);
  k_combine<<<1, 512, 0, stream>>>(mu_t, colsum, scal, out);
}

// Round 4
// 925.062 us; speedup vs baseline: 1.4549x; 1.0982x over previous
//
#include <hip/hip_runtime.h>
#include <float.h>
#include <math.h>

// Problem constants
#define BB 256
#define DD 512
#define NN 50000
#define KK 32
#define NS_ITERS 11
#define PARTS 8
#define PCH 6250

// Workspace layout (float offsets)
#define OFF_G     0         // 1M-float region: UUT(65536) + TcTc(65536) + w(256) + m(50000); NS Pm reuses +0
#define OFF_SC    262144    // 64 scalars: 0=sumTc2 1=trCX 2=S_total 3=knn 4=wreg 5=s_ns 6=wsum
#define OFF_CS    262208    // 512 colsum X
#define OFF_CSS   262720    // 512 colsumsq X
#define ZERO_F    263232    // floats to memset
#define OFF_T     263232    // 256*512
#define OFF_TC    394304    // 256*512 Tc; later NS Y/Z
#define OFF_P     525376    // 256*512: top-k cand buffers; later NS Y2/Z2
#define OFF_H     656448    // 256*256
#define OFF_XSQ   723008    // 50000
#define OFF_RUNI  781200    // 256*32 (int)
#define OFF_PW    789392    // 256*32 post_w
#define OFF_PRW   797584    // 256*32 pre_w normalized
#define OFF_D2    805776    // V = T@X^T  (256*50000)

#define OFF_UUT   (OFF_G)
#define OFF_TCTC  (OFF_G + 65536)
#define OFF_W     (OFF_G + 131072)
#define OFF_M     (OFF_G + 131328)
#define OFF_MUT   (OFF_G + 200000)   // 512 raw col sums of T (zeroed region; free after m)

typedef __attribute__((ext_vector_type(8))) short bf16x8;
typedef __attribute__((ext_vector_type(4))) float f32x4;

__device__ __forceinline__ float waveSum(float v) {
#pragma unroll
  for (int off = 32; off > 0; off >>= 1) v += __shfl_xor(v, off);
  return v;
}

// split fp32x4 -> bf16 hi/lo, write packed pairs to LDS at short-offset sa (16B-aligned rows)
__device__ __forceinline__ void cvt_write(float4 v, unsigned short* hi, unsigned short* lo, int sa) {
  unsigned int b0 = __float_as_uint(v.x), b1 = __float_as_uint(v.y);
  unsigned int b2 = __float_as_uint(v.z), b3 = __float_as_uint(v.w);
  unsigned int h0 = b0 & 0xffff0000u, h1 = b1 & 0xffff0000u;
  unsigned int h2 = b2 & 0xffff0000u, h3 = b3 & 0xffff0000u;
  float l0 = v.x - __uint_as_float(h0), l1 = v.y - __uint_as_float(h1);
  float l2 = v.z - __uint_as_float(h2), l3 = v.w - __uint_as_float(h3);
  *(unsigned int*)&hi[sa]     = (h0 >> 16) | h1;
  *(unsigned int*)&hi[sa + 2] = (h2 >> 16) | h3;
  *(unsigned int*)&lo[sa]     = (__float_as_uint(l0) >> 16) | (__float_as_uint(l1) & 0xffff0000u);
  *(unsigned int*)&lo[sa + 2] = (__float_as_uint(l2) >> 16) | (__float_as_uint(l3) & 0xffff0000u);
}

// scalar fp32 -> bf16 hi/lo split
__device__ __forceinline__ void cvt1(float x, unsigned short* hp, unsigned short* lp) {
  unsigned int bb = __float_as_uint(x);
  unsigned int hb = bb & 0xffff0000u;
  float lo = x - __uint_as_float(hb);
  *hp = (unsigned short)(hb >> 16);
  *lp = (unsigned short)(__float_as_uint(lo) >> 16);
}

// ---------------- generic 64x64-tile GEMM, C = scale * A @ B (nn); optional colsum epilogue ----
__global__ void __launch_bounds__(256) k_g64_nn(const float* __restrict__ A,
                                                const float* __restrict__ B,
                                                float* __restrict__ C,
                                                int K, int lda, int ldb, int ldc, float scale,
                                                float* __restrict__ musum) {
  __shared__ float As[64][65], Bs[64][65];
  __shared__ float cp[64];
  int m0 = blockIdx.y * 64, n0 = blockIdx.x * 64;
  int t = threadIdx.x, tr = t >> 4, tc = t & 15;
  float acc[4][4] = {{0.f}};
  for (int k0 = 0; k0 < K; k0 += 64) {
#pragma unroll
    for (int p = 0; p < 16; ++p) {
      int l = t + 256 * p;
      int r = l >> 6, c = l & 63;
      As[r][c] = A[(m0 + r) * lda + k0 + c];
      Bs[r][c] = B[(k0 + r) * ldb + n0 + c];
    }
    __syncthreads();
#pragma unroll 16
    for (int kk = 0; kk < 64; ++kk) {
      float a[4], b[4];
#pragma unroll
      for (int u = 0; u < 4; ++u) a[u] = As[tr + 16 * u][kk];
#pragma unroll
      for (int v = 0; v < 4; ++v) b[v] = Bs[kk][tc + 16 * v];
#pragma unroll
      for (int u = 0; u < 4; ++u)
#pragma unroll
        for (int v = 0; v < 4; ++v) acc[u][v] += a[u] * b[v];
    }
    __syncthreads();
  }
#pragma unroll
  for (int u = 0; u < 4; ++u)
#pragma unroll
    for (int v = 0; v < 4; ++v)
      C[(m0 + tr + 16 * u) * ldc + n0 + tc + 16 * v] = acc[u][v] * scale;
  if (musum != nullptr) {
    if (t < 64) cp[t] = 0.f;
    __syncthreads();
#pragma unroll
    for (int v = 0; v < 4; ++v) {
      float s = 0.f;
#pragma unroll
      for (int u = 0; u < 4; ++u) s += acc[u][v];
      atomicAdd(&cp[tc + 16 * v], s * scale);
    }
    __syncthreads();
    if (t < 64) atomicAdd(&musum[n0 + t], cp[t]);
  }
}

// ---------------- generic 64x64-tile GEMM, C = scale * A @ B^T (nt) ----------------
__global__ void __launch_bounds__(256) k_g64_nt(const float* __restrict__ A,
                                                const float* __restrict__ B,
                                                float* __restrict__ C,
                                                int K, int lda, int ldb, int ldc, float scale) {
  __shared__ float As[64][65], Bs[64][65];
  int m0 = blockIdx.y * 64, n0 = blockIdx.x * 64;
  int t = threadIdx.x, tr = t >> 4, tc = t & 15;
  float acc[4][4] = {{0.f}};
  for (int k0 = 0; k0 < K; k0 += 64) {
#pragma unroll
    for (int p = 0; p < 16; ++p) {
      int l = t + 256 * p;
      int r = l >> 6, c = l & 63;
      As[r][c] = A[(m0 + r) * lda + k0 + c];
      Bs[r][c] = B[(n0 + r) * ldb + k0 + c];
    }
    __syncthreads();
#pragma unroll 16
    for (int kk = 0; kk < 64; ++kk) {
      float a[4], b[4];
#pragma unroll
      for (int u = 0; u < 4; ++u) a[u] = As[tr + 16 * u][kk];
#pragma unroll
      for (int v = 0; v < 4; ++v) b[v] = Bs[tc + 16 * v][kk];
#pragma unroll
      for (int u = 0; u < 4; ++u)
#pragma unroll
        for (int v = 0; v < 4; ++v) acc[u][v] += a[u] * b[v];
    }
    __syncthreads();
  }
#pragma unroll
  for (int u = 0; u < 4; ++u)
#pragma unroll
    for (int v = 0; v < 4; ++v)
      C[(m0 + tr + 16 * u) * ldc + n0 + tc + 16 * v] = acc[u][v] * scale;
}

// ---------------- V = T @ X^T  (MFMA bf16-split, reg-prefetch dbuf) + fused colmeans(V) ------
__global__ void __launch_bounds__(256) k_vgemm(const float* __restrict__ T,
                                               const float* __restrict__ X,
                                               float* __restrict__ V,
                                               float* __restrict__ m) {
  __shared__ unsigned short Ah[128 * 72], Al[128 * 72], Bh[128 * 72], Bl[128 * 72];
  __shared__ float colpart[128];
  int bj = blockIdx.x, bi = blockIdx.y;
  int t = threadIdx.x;
  int wave = t >> 6, lane = t & 63;
  int m0 = (wave >> 1) * 64, n0 = (wave & 1) * 64;
  int lrow = lane & 15, lq = lane >> 4;
  int r_ = t >> 4, c4_ = (t & 15) * 4;
  f32x4 acc[4][4] = {};
  float4 pa[8], pb[8];
#pragma unroll
  for (int f = 0; f < 8; ++f) {
    int r = f * 16 + r_;
    pa[f] = *(const float4*)&T[(bi * 128 + r) * 512 + c4_];
    int jg = bj * 128 + r;
    float4 vb = {0.f, 0.f, 0.f, 0.f};
    if (jg < NN) vb = *(const float4*)&X[(size_t)jg * 512 + c4_];
    pb[f] = vb;
  }
  for (int kc = 0; kc < 512; kc += 64) {
#pragma unroll
    for (int f = 0; f < 8; ++f) {
      int sa = (f * 16 + r_) * 72 + c4_;
      cvt_write(pa[f], Ah, Al, sa);
      cvt_write(pb[f], Bh, Bl, sa);
    }
    __syncthreads();
    if (kc < 448) {
      int kn = kc + 64;
#pragma unroll
      for (int f = 0; f < 8; ++f) {
        int r = f * 16 + r_;
        pa[f] = *(const float4*)&T[(bi * 128 + r) * 512 + kn + c4_];
        int jg = bj * 128 + r;
        float4 vb = {0.f, 0.f, 0.f, 0.f};
        if (jg < NN) vb = *(const float4*)&X[(size_t)jg * 512 + kn + c4_];
        pb[f] = vb;
      }
    }
#pragma unroll
    for (int ks = 0; ks < 2; ++ks) {
      int kb = ks * 32 + lq * 8;
      bf16x8 ah[4], al[4], bh[4], bl[4];
#pragma unroll
      for (int mi = 0; mi < 4; ++mi) {
        int ro = (m0 + mi * 16 + lrow) * 72 + kb;
        ah[mi] = *(const bf16x8*)&Ah[ro];
        al[mi] = *(const bf16x8*)&Al[ro];
      }
#pragma unroll
      for (int nj = 0; nj < 4; ++nj) {
        int ro = (n0 + nj * 16 + lrow) * 72 + kb;
        bh[nj] = *(const bf16x8*)&Bh[ro];
        bl[nj] = *(const bf16x8*)&Bl[ro];
      }
#pragma unroll
      for (int mi = 0; mi < 4; ++mi)
#pragma unroll
        for (int nj = 0; nj < 4; ++nj) {
          acc[mi][nj] = __builtin_amdgcn_mfma_f32_16x16x32_bf16(ah[mi], bh[nj], acc[mi][nj], 0, 0, 0);
          acc[mi][nj] = __builtin_amdgcn_mfma_f32_16x16x32_bf16(ah[mi], bl[nj], acc[mi][nj], 0, 0, 0);
          acc[mi][nj] = __builtin_amdgcn_mfma_f32_16x16x32_bf16(al[mi], bh[nj], acc[mi][nj], 0, 0, 0);
        }
    }
    __syncthreads();
  }
  if (t < 128) colpart[t] = 0.f;
  __syncthreads();
#pragma unroll
  for (int mi = 0; mi < 4; ++mi)
#pragma unroll
    for (int nj = 0; nj < 4; ++nj)
#pragma unroll
      for (int r = 0; r < 4; ++r) {
        int row = bi * 128 + m0 + mi * 16 + lq * 4 + r;
        int col = bj * 128 + n0 + nj * 16 + lrow;
        if (col < NN) V[(size_t)row * NN + col] = acc[mi][nj][r];
      }
#pragma unroll
  for (int nj = 0; nj < 4; ++nj) {
    float s = 0.f;
#pragma unroll
    for (int mi = 0; mi < 4; ++mi)
#pragma unroll
      for (int r = 0; r < 4; ++r) s += acc[mi][nj][r];
    atomicAdd(&colpart[n0 + nj * 16 + lrow], s);
  }
  __syncthreads();
  if (t < 128) {
    int col = bj * 128 + t;
    if (col < NN) atomicAdd(&m[col], colpart[t] * (1.0f / 256.0f));
  }
}

// ---------------- UUT += U @ U^T, U = V - m (MFMA bf16-split, reg-prefetch, split-K atomic) ---
__global__ void __launch_bounds__(256) k_uut(const float* __restrict__ V,
                                             const float* __restrict__ m,
                                             float* __restrict__ UUT) {
  __shared__ unsigned short Ah[128 * 72], Al[128 * 72], Bh[128 * 72], Bl[128 * 72];
  __shared__ __align__(16) float ms[1000];
  const int pi_[3] = {0, 0, 1}, pj_[3] = {0, 1, 1};
  int bi = pi_[blockIdx.x], bj = pj_[blockIdx.x];
  int j0 = blockIdx.y * 1000, jlim = j0 + 1000;
  int t = threadIdx.x;
  int wave = t >> 6, lane = t & 63;
  int m0 = (wave >> 1) * 64, n0 = (wave & 1) * 64;
  int lrow = lane & 15, lq = lane >> 4;
  int r_ = t >> 4, c4_ = (t & 15) * 4;
  f32x4 acc[4][4] = {};
  if (t < 250) ((float4*)ms)[t] = *(const float4*)&m[j0 + t * 4];
  float4 pa[8], pb[8];
#pragma unroll
  for (int f = 0; f < 8; ++f) {
    int r = f * 16 + r_;
    int jb = j0 + c4_;
    float4 va = {0.f, 0.f, 0.f, 0.f}, vb = {0.f, 0.f, 0.f, 0.f};
    if (jb < jlim) {
      va = *(const float4*)&V[(size_t)(bi * 128 + r) * NN + jb];
      vb = *(const float4*)&V[(size_t)(bj * 128 + r) * NN + jb];
    }
    pa[f] = va; pb[f] = vb;
  }
  __syncthreads();
  for (int ch = 0; ch < 16; ++ch) {
    int jc = j0 + ch * 64;
#pragma unroll
    for (int f = 0; f < 8; ++f) {
      int sa = (f * 16 + r_) * 72 + c4_;
      int jb = jc + c4_;
      float4 va = pa[f], vb = pb[f];
      if (jb < jlim) {
        float4 mm = *(const float4*)&ms[jb - j0];
        va.x -= mm.x; va.y -= mm.y; va.z -= mm.z; va.w -= mm.w;
        vb.x -= mm.x; vb.y -= mm.y; vb.z -= mm.z; vb.w -= mm.w;
      }
      cvt_write(va, Ah, Al, sa);
      cvt_write(vb, Bh, Bl, sa);
    }
    __syncthreads();
    if (ch < 15) {
      int jn = j0 + (ch + 1) * 64;
#pragma unroll
      for (int f = 0; f < 8; ++f) {
        int r = f * 16 + r_;
        int jb = jn + c4_;
        float4 va = {0.f, 0.f, 0.f, 0.f}, vb = {0.f, 0.f, 0.f, 0.f};
        if (jb < jlim) {
          va = *(const float4*)&V[(size_t)(bi * 128 + r) * NN + jb];
          vb = *(const float4*)&V[(size_t)(bj * 128 + r) * NN + jb];
        }
        pa[f] = va; pb[f] = vb;
      }
    }
#pragma unroll
    for (int ks = 0; ks < 2; ++ks) {
      int kb = ks * 32 + lq * 8;
      bf16x8 ah[4], al[4], bh[4], bl[4];
#pragma unroll
      for (int mi = 0; mi < 4; ++mi) {
        int ro = (m0 + mi * 16 + lrow) * 72 + kb;
        ah[mi] = *(const bf16x8*)&Ah[ro];
        al[mi] = *(const bf16x8*)&Al[ro];
      }
#pragma unroll
      for (int nj = 0; nj < 4; ++nj) {
        int ro = (n0 + nj * 16 + lrow) * 72 + kb;
        bh[nj] = *(const bf16x8*)&Bh[ro];
        bl[nj] = *(const bf16x8*)&Bl[ro];
      }
#pragma unroll
      for (int mi = 0; mi < 4; ++mi)
#pragma unroll
        for (int nj = 0; nj < 4; ++nj) {
          acc[mi][nj] = __builtin_amdgcn_mfma_f32_16x16x32_bf16(ah[mi], bh[nj], acc[mi][nj], 0, 0, 0);
          acc[mi][nj] = __builtin_amdgcn_mfma_f32_16x16x32_bf16(ah[mi], bl[nj], acc[mi][nj], 0, 0, 0);
          acc[mi][nj] = __builtin_amdgcn_mfma_f32_16x16x32_bf16(al[mi], bh[nj], acc[mi][nj], 0, 0, 0);
        }
    }
    __syncthreads();
  }
#pragma unroll
  for (int mi = 0; mi < 4; ++mi)
#pragma unroll
    for (int nj = 0; nj < 4; ++nj)
#pragma unroll
      for (int r = 0; r < 4; ++r) {
        int row = bi * 128 + m0 + mi * 16 + lq * 4 + r;
        int col = bj * 128 + n0 + nj * 16 + lrow;
        atomicAdd(&UUT[row * 256 + col], acc[mi][nj][r]);
      }
}

// ---------------- column sums & sumsq of X (float4, high-MLP, atomic) ----------------
__global__ void __launch_bounds__(256) k_colstatX(const float* __restrict__ X, float* __restrict__ colsum,
                                                  float* __restrict__ colss) {
  __shared__ float shs[512], shss[512];
  int b = blockIdx.x, t = threadIdx.x;
  int c4 = (t & 127) * 4, g = t >> 7;
  int r0 = b * 200 + g;
  float sx = 0, sy = 0, sz = 0, sw = 0;
  float qx = 0, qy = 0, qz = 0, qw = 0;
#pragma unroll 4
  for (int it = 0; it < 100; ++it) {
    float4 v = *(const float4*)&X[(size_t)(r0 + 2 * it) * 512 + c4];
    sx += v.x; sy += v.y; sz += v.z; sw += v.w;
    qx += v.x * v.x; qy += v.y * v.y; qz += v.z * v.z; qw += v.w * v.w;
  }
  if (g == 1) {
    int o = (t - 128) * 4;
    shs[o] = sx; shs[o + 1] = sy; shs[o + 2] = sz; shs[o + 3] = sw;
    shss[o] = qx; shss[o + 1] = qy; shss[o + 2] = qz; shss[o + 3] = qw;
  }
  __syncthreads();
  if (g == 0) {
    int o = t * 4;
    atomicAdd(&colsum[c4],     sx + shs[o]);
    atomicAdd(&colsum[c4 + 1], sy + shs[o + 1]);
    atomicAdd(&colsum[c4 + 2], sz + shs[o + 2]);
    atomicAdd(&colsum[c4 + 3], sw + shs[o + 3]);
    atomicAdd(&colss[c4],     qx + shss[o]);
    atomicAdd(&colss[c4 + 1], qy + shss[o + 1]);
    atomicAdd(&colss[c4 + 2], qz + shss[o + 2]);
    atomicAdd(&colss[c4 + 3], qw + shss[o + 3]);
  }
}

// ---------------- per-row squared norm of X ----------------
__global__ void k_xsq(const float* __restrict__ X, float* __restrict__ xsq) {
  int row = blockIdx.x * 4 + (threadIdx.x >> 6);
  int lane = threadIdx.x & 63;
  const float* Xr = X + (size_t)row * 512;
  float s = 0.f;
#pragma unroll
  for (int d = 0; d < 8; ++d) { float v = Xr[lane + 64 * d]; s += v * v; }
  s = waveSum(s);
  if (lane == 0) xsq[row] = s;
}

// ---------------- Tc = T - mu, accumulate sum(Tc^2) ----------------
__global__ void k_centerT(const float* __restrict__ T, const float* __restrict__ mu,
                          float* __restrict__ Tc, float* __restrict__ scal) {
  __shared__ float red[4];
  int t = threadIdx.x;
  int base = blockIdx.x * 1024;
  float ss = 0.f;
#pragma unroll
  for (int p = 0; p < 4; ++p) {
    int l = base + p * 256 + t;
    float v = T[l] - mu[l & 511] * (1.0f / 256.0f);
    Tc[l] = v;
    ss += v * v;
  }
  ss = waveSum(ss);
  if ((t & 63) == 0) red[t >> 6] = ss;
  __syncthreads();
  if (t == 0) atomicAdd(&scal[0], red[0] + red[1] + red[2] + red[3]);
}

// ---------------- trace of cov(X) ----------------
__global__ void k_trCX(const float* __restrict__ colsum, const float* __restrict__ colss,
                       float* __restrict__ scal) {
  __shared__ float red[8];
  int t = threadIdx.x;  // 512
  float mu = colsum[t] * (1.0f / 50000.0f);
  float v = (colss[t] - 50000.0f * mu * mu) * (1.0f / 49999.0f);
  v = waveSum(v);
  if ((t & 63) == 0) red[t >> 6] = v;
  __syncthreads();
  if (t == 0) {
    float s = 0;
    for (int i = 0; i < 8; ++i) s += red[i];
    scal[1] = s;
  }
}

// ---------------- w_i = T_i . muX (raw), wsum -> scal[6]; mean folded into k_hfix ----------------
__global__ void __launch_bounds__(256) k_wvec(const float* __restrict__ T,
                                              const float* __restrict__ colsum,
                                              float* __restrict__ w, float* __restrict__ scal) {
  __shared__ float cs[512];
  int t = threadIdx.x, lane = t & 63, wv_ = t >> 6;
  cs[t] = colsum[t] * (1.0f / 50000.0f);
  cs[t + 256] = colsum[t + 256] * (1.0f / 50000.0f);
  __syncthreads();
  int rbase = blockIdx.x * 32 + wv_ * 8;
  float tot = 0.f;
  for (int rr = 0; rr < 8; ++rr) {
    int row = rbase + rr;
    float a = 0.f;
#pragma unroll
    for (int d = 0; d < 8; ++d) a += T[row * 512 + lane + 64 * d] * cs[lane + 64 * d];
    a = waveSum(a);
    if (lane == 0) { w[row] = a; tot += a; }
  }
  if (lane == 0) atomicAdd(&scal[6], tot);
}

// ---------------- H = (UUT - N (w-wm)(w-wm)^T)/(49999*255) + rhoX * TcTc/255 ----------------
__global__ void k_hfix(const float* __restrict__ UUT, const float* __restrict__ TcTc,
                       const float* __restrict__ w, const float* __restrict__ scal,
                       float* __restrict__ H) {
  int l = blockIdx.x * 256 + threadIdx.x;
  int i = l >> 8, j = l & 255;
  float u = (i >= 128 && j < 128) ? UUT[j * 256 + i] : UUT[i * 256 + j];
  float rho = scal[1] * (1e-3f / 512.0f);
  float wm = scal[6] * (1.0f / 256.0f);
  float wi = w[i] - wm, wj = w[j] - wm;
  H[l] = (u - 50000.0f * wi * wj) * (1.0f / (49999.0f * 255.0f))
       + rho * TcTc[i * 256 + j] * (1.0f / 255.0f);
}

// ---------------- power iteration: scal[5] = safe lambda_max bound of H' (H symmetric) -------
__global__ void __launch_bounds__(256) k_power(const float* __restrict__ H,
                                               float* __restrict__ scal) {
  __shared__ float v[256], nv[256], red[4];
  int t = threadIdx.x;
  float rt = scal[0] * (1.0f / 255.0f) * (1e-3f / 512.0f);
  v[t] = 1.0f;
  __syncthreads();
  float n2 = 256.0f, n3 = 256.0f;
  for (int it = 0; it < 3; ++it) {
    float s = rt * v[t];
    for (int j = 0; j < 256; ++j) s += H[j * 256 + t] * v[j];  // coalesced via symmetry
    nv[t] = s;
    float ss = waveSum(s * s);
    if ((t & 63) == 0) red[t >> 6] = ss;
    __syncthreads();
    float norm2 = red[0] + red[1] + red[2] + red[3];
    if (it == 1) n2 = norm2;
    if (it == 2) n3 = norm2;
    v[t] = nv[t];
    __syncthreads();
  }
  float d = H[t * 256 + t] + rt;
#pragma unroll
  for (int off = 32; off > 0; off >>= 1) d = fmaxf(d, __shfl_xor(d, off));
  if ((t & 63) == 0) red[t >> 6] = d;
  __syncthreads();
  if (t == 0) {
    float lam = sqrtf(n3 / n2);
    float md = fmaxf(fmaxf(red[0], red[1]), fmaxf(red[2], red[3]));
    scal[5] = fmaxf(1.3f * lam, md);
  }
}

// ---------------- Y0 = (H + rt I)/s, Z0 = I ----------------
__global__ void k_nsinit(const float* __restrict__ H, const float* __restrict__ scal,
                         float* __restrict__ Y, float* __restrict__ Z) {
  int l = blockIdx.x * 256 + threadIdx.x;
  int i = l >> 8, j = l & 255;
  float rt = scal[0] * (1.0f / 255.0f) * (1e-3f / 512.0f);
  float inv = 1.0f / scal[5];
  Y[l] = (H[l] + ((i == j) ? rt : 0.f)) * inv;
  Z[l] = (i == j) ? 1.0f : 0.f;
}

// ---------------- NS: P = Z @ Y (MFMA bf16-split, nn, 64x64 tiles) ----------------
__global__ void __launch_bounds__(256) k_nsp(const float* __restrict__ Z,
                                             const float* __restrict__ Y,
                                             float* __restrict__ P) {
  __shared__ unsigned short Ah[64 * 72], Al[64 * 72], Bh[64 * 72], Bl[64 * 72];
  int n0b = blockIdx.x * 64, m0b = blockIdx.y * 64;
  int t = threadIdx.x, wave = t >> 6, lane = t & 63;
  int m0 = (wave >> 1) * 32, n0 = (wave & 1) * 32;
  int lrow = lane & 15, lq = lane >> 4;
  f32x4 acc[2][2] = {};
  for (int k0 = 0; k0 < 256; k0 += 64) {
#pragma unroll
    for (int f = 0; f < 4; ++f) {
      int lin = f * 256 + t;
      int r = lin >> 4, c4 = (lin & 15) * 4;
      float4 va = *(const float4*)&Z[(m0b + r) * 256 + k0 + c4];
      cvt_write(va, Ah, Al, r * 72 + c4);
      float4 vb = *(const float4*)&Y[(k0 + r) * 256 + n0b + c4];
      cvt1(vb.x, &Bh[(c4 + 0) * 72 + r], &Bl[(c4 + 0) * 72 + r]);
      cvt1(vb.y, &Bh[(c4 + 1) * 72 + r], &Bl[(c4 + 1) * 72 + r]);
      cvt1(vb.z, &Bh[(c4 + 2) * 72 + r], &Bl[(c4 + 2) * 72 + r]);
      cvt1(vb.w, &Bh[(c4 + 3) * 72 + r], &Bl[(c4 + 3) * 72 + r]);
    }
    __syncthreads();
#pragma unroll
    for (int ks = 0; ks < 2; ++ks) {
      int kb = ks * 32 + lq * 8;
      bf16x8 ah[2], al2[2], bh[2], bl2[2];
#pragma unroll
      for (int mi = 0; mi < 2; ++mi) {
        int ro = (m0 + mi * 16 + lrow) * 72 + kb;
        ah[mi] = *(const bf16x8*)&Ah[ro];
        al2[mi] = *(const bf16x8*)&Al[ro];
      }
#pragma unroll
      for (int nj = 0; nj < 2; ++nj) {
        int ro = (n0 + nj * 16 + lrow) * 72 + kb;
        bh[nj] = *(const bf16x8*)&Bh[ro];
        bl2[nj] = *(const bf16x8*)&Bl[ro];
      }
#pragma unroll
      for (int mi = 0; mi < 2; ++mi)
#pragma unroll
        for (int nj = 0; nj < 2; ++nj) {
          acc[mi][nj] = __builtin_amdgcn_mfma_f32_16x16x32_bf16(ah[mi], bh[nj], acc[mi][nj], 0, 0, 0);
          acc[mi][nj] = __builtin_amdgcn_mfma_f32_16x16x32_bf16(ah[mi], bl2[nj], acc[mi][nj], 0, 0, 0);
          acc[mi][nj] = __builtin_amdgcn_mfma_f32_16x16x32_bf16(al2[mi], bh[nj], acc[mi][nj], 0, 0, 0);
        }
    }
    __syncthreads();
  }
#pragma unroll
  for (int mi = 0; mi < 2; ++mi)
#pragma unroll
    for (int nj = 0; nj < 2; ++nj)
#pragma unroll
      for (int r = 0; r < 4; ++r) {
        int row = m0b + m0 + mi * 16 + lq * 4 + r;
        int col = n0b + n0 + nj * 16 + lrow;
        P[row * 256 + col] = acc[mi][nj][r];
      }
}

// ---------------- NS update: O = 1.5 D - 0.5 A@B (MFMA bf16-split, nn) ----------------
__global__ void __launch_bounds__(256) k_nsu(const float* __restrict__ Y, const float* __restrict__ Z,
                                             const float* __restrict__ Pm,
                                             float* __restrict__ Yn, float* __restrict__ Zn) {
  __shared__ unsigned short Ah[64 * 72], Al[64 * 72], Bh[64 * 72], Bl[64 * 72];
  int zz = blockIdx.z;
  const float* A = zz ? Pm : Y;
  const float* B = zz ? Z : Pm;
  const float* D = zz ? Z : Y;
  float* O = zz ? Zn : Yn;
  int n0b = blockIdx.x * 64, m0b = blockIdx.y * 64;
  int t = threadIdx.x, wave = t >> 6, lane = t & 63;
  int m0 = (wave >> 1) * 32, n0 = (wave & 1) * 32;
  int lrow = lane & 15, lq = lane >> 4;
  f32x4 acc[2][2] = {};
  for (int k0 = 0; k0 < 256; k0 += 64) {
#pragma unroll
    for (int f = 0; f < 4; ++f) {
      int lin = f * 256 + t;
      int r = lin >> 4, c4 = (lin & 15) * 4;
      float4 va = *(const float4*)&A[(m0b + r) * 256 + k0 + c4];
      cvt_write(va, Ah, Al, r * 72 + c4);
      float4 vb = *(const float4*)&B[(k0 + r) * 256 + n0b + c4];
      cvt1(vb.x, &Bh[(c4 + 0) * 72 + r], &Bl[(c4 + 0) * 72 + r]);
      cvt1(vb.y, &Bh[(c4 + 1) * 72 + r], &Bl[(c4 + 1) * 72 + r]);
      cvt1(vb.z, &Bh[(c4 + 2) * 72 + r], &Bl[(c4 + 2) * 72 + r]);
      cvt1(vb.w, &Bh[(c4 + 3) * 72 + r], &Bl[(c4 + 3) * 72 + r]);
    }
    __syncthreads();
#pragma unroll
    for (int ks = 0; ks < 2; ++ks) {
      int kb = ks * 32 + lq * 8;
      bf16x8 ah[2], al2[2], bh[2], bl2[2];
#pragma unroll
      for (int mi = 0; mi < 2; ++mi) {
        int ro = (m0 + mi * 16 + lrow) * 72 + kb;
        ah[mi] = *(const bf16x8*)&Ah[ro];
        al2[mi] = *(const bf16x8*)&Al[ro];
      }
#pragma unroll
      for (int nj = 0; nj < 2; ++nj) {
        int ro = (n0 + nj * 16 + lrow) * 72 + kb;
        bh[nj] = *(const bf16x8*)&Bh[ro];
        bl2[nj] = *(const bf16x8*)&Bl[ro];
      }
#pragma unroll
      for (int mi = 0; mi < 2; ++mi)
#pragma unroll
        for (int nj = 0; nj < 2; ++nj) {
          acc[mi][nj] = __builtin_amdgcn_mfma_f32_16x16x32_bf16(ah[mi], bh[nj], acc[mi][nj], 0, 0, 0);
          acc[mi][nj] = __builtin_amdgcn_mfma_f32_16x16x32_bf16(ah[mi], bl2[nj], acc[mi][nj], 0, 0, 0);
          acc[mi][nj] = __builtin_amdgcn_mfma_f32_16x16x32_bf16(al2[mi], bh[nj], acc[mi][nj], 0, 0, 0);
        }
    }
    __syncthreads();
  }
#pragma unroll
  for (int mi = 0; mi < 2; ++mi)
#pragma unroll
    for (int nj = 0; nj < 2; ++nj)
#pragma unroll
      for (int r = 0; r < 4; ++r) {
        int row = m0b + m0 + mi * 16 + lq * 4 + r;
        int col = n0b + n0 + nj * 16 + lrow;
        int idx = row * 256 + col;
        O[idx] = 1.5f * D[idx] - 0.5f * acc[mi][nj][r];
      }
}

// ---------------- S_total = sqrt(s)*tr(Y) + 256*sqrt(rt) ----------------
__global__ void k_ns_trace(const float* __restrict__ Y, float* __restrict__ scal) {
  __shared__ float red[4];
  int t = threadIdx.x;  // 256
  float v = Y[t * 256 + t];
  v = waveSum(v);
  if ((t & 63) == 0) red[t >> 6] = v;
  __syncthreads();
  if (t == 0) {
    float tr = red[0] + red[1] + red[2] + red[3];
    float rt = scal[0] * (1.0f / 255.0f) * (1e-3f / 512.0f);
    scal[2] = sqrtf(scal[5]) * tr + 256.0f * sqrtf(rt);
  }
}

// ---------------- stage 1: threshold-filter exact top-32 per (query, 1/8-slice) ----------------
__global__ void __launch_bounds__(256) k_topk_part(const float* __restrict__ V,
                                                   const float* __restrict__ xsq,
                                                   float* __restrict__ candv,
                                                   int* __restrict__ candi) {
  __shared__ float bufv[512];
  __shared__ int bufi[512];
  __shared__ int lcount;
  __shared__ float tvs;
  __shared__ int tis;
  int part = blockIdx.x, q = blockIdx.y, t = threadIdx.x;
  int base = part * PCH;
  int lane = t & 63;
  if (t == 0) { lcount = 0; tvs = FLT_MAX; tis = 0x7fffffff; }
  __syncthreads();
  const float* rowV = V + (size_t)q * NN + base;
  const float* xs = xsq + base;

  auto flush = [&]() {
    __syncthreads();
    int c = lcount;
    for (int s = c + t; s < 512; s += 256) { bufv[s] = FLT_MAX; bufi[s] = 0x7fffffff; }
    __syncthreads();
    for (int ssz = 2; ssz <= 512; ssz <<= 1) {
      for (int st = ssz >> 1; st > 0; st >>= 1) {
        int i = 2 * t - (t & (st - 1));
        int j = i + st;
        bool up = ((i & ssz) == 0);
        float a = bufv[i], b = bufv[j];
        int ai = bufi[i], bi2 = bufi[j];
        bool agtb = (a > b) || (a == b && ai > bi2);
        if (agtb == up) { bufv[i] = b; bufv[j] = a; bufi[i] = bi2; bufi[j] = ai; }
        __syncthreads();
      }
    }
    if (t == 0) { lcount = 32; tvs = bufv[31]; tis = bufi[31]; }
    __syncthreads();
  };

  int ntile = (PCH + 255) >> 8;
  for (int tile = 0; tile < ntile; ++tile) {
    int j = tile * 256 + t;
    float val = 0.f; int idx = 0;
    bool pred = false;
    if (j < PCH) {
      val = xs[j] - 2.0f * rowV[j];
      idx = base + j;
      float tv = tvs; int ti = tis;
      pred = (val < tv) || (val == tv && idx < ti);
    }
    unsigned long long mask = __ballot(pred);
    if (mask) {
      int lead = __ffsll((unsigned long long)mask) - 1;
      int cnt = __popcll(mask);
      int basep = 0;
      if (lane == lead) basep = atomicAdd(&lcount, cnt);
      basep = __shfl(basep, lead);
      if (pred) {
        int off = __popcll(mask & ((1ull << lane) - 1ull));
        int slot = basep + off;
        bufv[slot] = val; bufi[slot] = idx;
      }
    }
    __syncthreads();
    if (lcount >= 256) flush();
  }
  flush();
  if (t < 32) {
    candv[(q * PARTS + part) * 32 + t] = bufv[t];
    candi[(q * PARTS + part) * 32 + t] = bufi[t];
  }
}

// ---------------- stage 2: bitonic-sort 256 candidates, emit top-32 indices ----------------
__global__ void __launch_bounds__(128) k_topk_final(const float* __restrict__ candv,
                                                    const int* __restrict__ candi,
                                                    int* __restrict__ runi) {
  __shared__ float v[256];
  __shared__ int ix[256];
  int q = blockIdx.x, t = threadIdx.x;
  v[t] = candv[q * 256 + t];
  v[t + 128] = candv[q * 256 + t + 128];
  ix[t] = candi[q * 256 + t];
  ix[t + 128] = candi[q * 256 + t + 128];
  __syncthreads();
  for (int ssz = 2; ssz <= 256; ssz <<= 1) {
    for (int st = ssz >> 1; st > 0; st >>= 1) {
      int i = 2 * t - (t & (st - 1));
      int j = i + st;
      bool up = ((i & ssz) == 0);
      float a = v[i], b = v[j];
      int ai = ix[i], bi = ix[j];
      bool agtb = (a > b) || (a == b && ai > bi);
      if (agtb == up) { v[i] = b; v[j] = a; ix[i] = bi; ix[j] = ai; }
      __syncthreads();
    }
  }
  if (t < 32) runi[q * 32 + t] = ix[t];
}

// ---------------- l2 to neighbors, softmax post_w, normalized pre_w ----------------
__global__ void __launch_bounds__(64) k_l2soft(const float* __restrict__ T, const float* __restrict__ X,
                                               const int* __restrict__ runi, const int* __restrict__ qidx,
                                               const float* __restrict__ prew, float* __restrict__ postw,
                                               float* __restrict__ prewn) {
  __shared__ float l2s[32];
  int b = blockIdx.x, lane = threadIdx.x;
  int qi = qidx[b];
  float pwv = (lane < 32) ? fmaxf(prew[qi * 32 + lane], 1e-8f) : 0.f;
  float psum = waveSum(pwv);
  if (lane < 32) prewn[b * 32 + lane] = pwv / psum;
  const float* Tb = T + b * 512;
  for (int n = 0; n < 32; ++n) {
    int nb = runi[b * 32 + n];
    const float* Xr = X + (size_t)nb * 512;
    float acc = 0.f;
#pragma unroll
    for (int d = 0; d < 8; ++d) {
      float df = Tb[lane + 64 * d] - Xr[lane + 64 * d];
      acc += df * df;
    }
    acc = waveSum(acc);
    if (lane == 0) l2s[n] = acc;
  }
  __syncthreads();
  float lg = (lane < 32) ? (-l2s[lane] * 10.0f) : -FLT_MAX;
  float mx = lg;
#pragma unroll
  for (int off = 32; off > 0; off >>= 1) mx = fmaxf(mx, __shfl_xor(mx, off));
  float e = (lane < 32) ? expf(lg - mx) : 0.f;
  float es = waveSum(e);
  float wv = e / es;
  wv = fmaxf(wv, 1e-8f);
  float ws2 = (lane < 32) ? wv : 0.f;
  ws2 = waveSum(ws2);
  if (lane < 32) postw[b * 32 + lane] = wv / ws2;
}

// ---------------- fused per-batch: Gram(MFMA) -> C -> median(radix-select) -> Sinkhorn -> loss ----
__global__ void __launch_bounds__(256) k_batch(const float* __restrict__ X, const int* __restrict__ qidx,
                                               const int* __restrict__ pre_idx, const int* __restrict__ runi,
                                               const float* __restrict__ prewn, const float* __restrict__ postw,
                                               float* __restrict__ scal) {
  __shared__ float G[64][65];
  __shared__ float Cm[64][65];
  __shared__ unsigned short Ah[64 * 72], Al[64 * 72];
  __shared__ int supp[64];
  __shared__ float uuS[32], vvS[32];
  __shared__ float red[4];
  __shared__ float medsh;
  __shared__ unsigned int hist[256];
  __shared__ unsigned int wtot[4];
  __shared__ unsigned int selp;
  __shared__ int selk;
  __shared__ unsigned int cw[4], mw[4];
  int b = blockIdx.x, t = threadIdx.x;
  int wave = t >> 6, lane = t & 63;
  if (t < 32) supp[t] = pre_idx[qidx[b] * 32 + t];
  else if (t < 64) supp[t] = runi[b * 32 + t - 32];
  if (t == 0) { selp = 0u; selk = 992; }
  __syncthreads();
  // ---- Gram G = S @ S^T via MFMA bf16-split (A = B), reg-prefetch ----
  {
    int m0 = (wave >> 1) * 32, n0 = (wave & 1) * 32;
    int lrow = lane & 15, lq = lane >> 4;
    int r_ = t >> 4, c4_ = (t & 15) * 4;
    f32x4 acc[2][2] = {};
    float4 pf[4];
#pragma unroll
    for (int f = 0; f < 4; ++f) {
      int r = f * 16 + r_;
      pf[f] = *(const float4*)&X[(size_t)supp[r] * 512 + c4_];
    }
    for (int kc = 0; kc < 512; kc += 64) {
#pragma unroll
      for (int f = 0; f < 4; ++f)
        cvt_write(pf[f], Ah, Al, (f * 16 + r_) * 72 + c4_);
      __syncthreads();
      if (kc < 448) {
        int kn = kc + 64;
#pragma unroll
        for (int f = 0; f < 4; ++f) {
          int r = f * 16 + r_;
          pf[f] = *(const float4*)&X[(size_t)supp[r] * 512 + kn + c4_];
        }
      }
#pragma unroll
      for (int ks = 0; ks < 2; ++ks) {
        int kb = ks * 32 + lq * 8;
        bf16x8 ah[2], al[2], bh[2], bl[2];
#pragma unroll
        for (int mi = 0; mi < 2; ++mi) {
          int ro = (m0 + mi * 16 + lrow) * 72 + kb;
          ah[mi] = *(const bf16x8*)&Ah[ro];
          al[mi] = *(const bf16x8*)&Al[ro];
        }
#pragma unroll
        for (int nj = 0; nj < 2; ++nj) {
          int ro = (n0 + nj * 16 + lrow) * 72 + kb;
          bh[nj] = *(const bf16x8*)&Ah[ro];
          bl[nj] = *(const bf16x8*)&Al[ro];
        }
#pragma unroll
        for (int mi = 0; mi < 2; ++mi)
#pragma unroll
          for (int nj = 0; nj < 2; ++nj) {
            acc[mi][nj] = __builtin_amdgcn_mfma_f32_16x16x32_bf16(ah[mi], bh[nj], acc[mi][nj], 0, 0, 0);
            acc[mi][nj] = __builtin_amdgcn_mfma_f32_16x16x32_bf16(ah[mi], bl[nj], acc[mi][nj], 0, 0, 0);
            acc[mi][nj] = __builtin_amdgcn_mfma_f32_16x16x32_bf16(al[mi], bh[nj], acc[mi][nj], 0, 0, 0);
          }
      }
      __syncthreads();
    }
#pragma unroll
    for (int mi = 0; mi < 2; ++mi)
#pragma unroll
      for (int nj = 0; nj < 2; ++nj)
#pragma unroll
        for (int r = 0; r < 4; ++r)
          G[m0 + mi * 16 + lq * 4 + r][n0 + nj * 16 + lrow] = acc[mi][nj][r];
  }
  __syncthreads();
  // ---- C build (raw, unnormalized) ----
  for (int l = t; l < 4096; l += 256) {
    int i = l >> 6, j = l & 63;
    Cm[i][j] = fmaxf(G[i][i] + G[j][j] - 2.0f * G[i][j], 0.f);
  }
  __syncthreads();
  // ---- radix-select ranks 992 & 993 over upper triangle (2016 values) ----
  for (int pass = 0; pass < 4; ++pass) {
    int shift = 24 - 8 * pass;
    hist[t] = 0u;
    __syncthreads();
    for (int l = t; l < 4096; l += 256) {
      int i = l >> 6, j = l & 63;
      if (i < j) {
        unsigned int u = __float_as_uint(Cm[i][j]) & 0x7fffffffu;
        bool match = (pass == 0) || (((u ^ selp) >> (shift + 8)) == 0u);
        if (match) atomicAdd(&hist[(u >> shift) & 255], 1u);
      }
    }
    __syncthreads();
    unsigned int h = hist[t];
    unsigned int c = h;
#pragma unroll
    for (int off = 1; off < 64; off <<= 1) {
      unsigned int n = __shfl_up(c, off);
      if ((t & 63) >= off) c += n;
    }
    if ((t & 63) == 63) wtot[t >> 6] = c;
    __syncthreads();
    unsigned int offw = 0;
    for (int w2 = 0; w2 < (t >> 6); ++w2) offw += wtot[w2];
    c += offw;
    int k = selk;
    if ((int)c >= k && (int)(c - h) < k) {
      selk = k - (int)(c - h);
      selp = selp | ((unsigned int)t << shift);
    }
    __syncthreads();
  }
  {
    unsigned int target = selp;
    unsigned int cnt = 0, mn = 0xffffffffu;
    for (int l = t; l < 4096; l += 256) {
      int i = l >> 6, j = l & 63;
      if (i < j) {
        unsigned int u = __float_as_uint(Cm[i][j]) & 0x7fffffffu;
        if (u <= target) cnt++;
        else mn = (u < mn) ? u : mn;
      }
    }
#pragma unroll
    for (int off = 32; off > 0; off >>= 1) {
      cnt += __shfl_xor(cnt, off);
      unsigned int m2 = __shfl_xor(mn, off);
      mn = (m2 < mn) ? m2 : mn;
    }
    if (lane == 0) { cw[wave] = cnt; mw[wave] = mn; }
    __syncthreads();
    if (t == 0) {
      unsigned int ct = cw[0] + cw[1] + cw[2] + cw[3];
      unsigned int mt = mw[0];
      mt = (mw[1] < mt) ? mw[1] : mt;
      mt = (mw[2] < mt) ? mw[2] : mt;
      mt = (mw[3] < mt) ? mw[3] : mt;
      float v992 = __uint_as_float(target);
      float v993 = (ct >= 993u) ? v992 : __uint_as_float(mt);
      medsh = 0.5f * (v992 + v993) + 1e-8f;
    }
    __syncthreads();
  }
  // ---- normalize C, build K = exp(-10*C) ----
  float inv = 1.0f / medsh;
  for (int l = t; l < 4096; l += 256) {
    int i = l >> 6, j = l & 63;
    float cn = Cm[i][j] * inv;
    Cm[i][j] = cn;
    G[i][j] = expf(-cn * 10.0f);
  }
  __syncthreads();
  // ---- Sinkhorn, wave 0, half-wave split, early exit on bitwise fixed point ----
  if (wave == 0) {
    int half = lane >> 5;
    int l = lane & 31;
    int cb = half * 16;
    float p_l = prewn[b * 32 + l];
    float q_l = postw[b * 32 + l];
    float Kr16[16], Kt16[16];
#pragma unroll
    for (int c2 = 0; c2 < 16; ++c2) Kr16[c2] = G[l][32 + cb + c2];
#pragma unroll
    for (int r2 = 0; r2 < 16; ++r2) Kt16[r2] = G[cb + r2][32 + l];
    float r0 = 0.f;
#pragma unroll
    for (int c2 = 0; c2 < 32; ++c2) r0 += G[l][half * 32 + c2];
    r0 += __shfl_xor(r0, 32);
    float u = p_l / (r0 + 1e-16f);
    float s0 = 0.f, s1 = 0.f, s2 = 0.f, s3 = 0.f;
#pragma unroll
    for (int r2 = 0; r2 < 16; r2 += 4) {
      s0 += Kt16[r2]     * __shfl(u, cb + r2);
      s1 += Kt16[r2 + 1] * __shfl(u, cb + r2 + 1);
      s2 += Kt16[r2 + 2] * __shfl(u, cb + r2 + 2);
      s3 += Kt16[r2 + 3] * __shfl(u, cb + r2 + 3);
    }
    float sv = (s0 + s1) + (s2 + s3);
    sv += __shfl_xor(sv, 32);
    float v = q_l / (sv + 1e-16f);
    for (int it = 1; it < 200; ++it) {
      float uprev = u, vprev = v;
      float a0 = 0.f, a1 = 0.f, a2 = 0.f, a3 = 0.f;
#pragma unroll
      for (int c2 = 0; c2 < 16; c2 += 4) {
        a0 += Kr16[c2]     * __shfl(v, cb + c2);
        a1 += Kr16[c2 + 1] * __shfl(v, cb + c2 + 1);
        a2 += Kr16[c2 + 2] * __shfl(v, cb + c2 + 2);
        a3 += Kr16[c2 + 3] * __shfl(v, cb + c2 + 3);
      }
      float au = (a0 + a1) + (a2 + a3);
      au += __shfl_xor(au, 32);
      u = p_l / (au + 1e-16f);
      a0 = 0.f; a1 = 0.f; a2 = 0.f; a3 = 0.f;
#pragma unroll
      for (int r2 = 0; r2 < 16; r2 += 4) {
        a0 += Kt16[r2]     * __shfl(u, cb + r2);
        a1 += Kt16[r2 + 1] * __shfl(u, cb + r2 + 1);
        a2 += Kt16[r2 + 2] * __shfl(u, cb + r2 + 2);
        a3 += Kt16[r2 + 3] * __shfl(u, cb + r2 + 3);
      }
      float bv = (a0 + a1) + (a2 + a3);
      bv += __shfl_xor(bv, 32);
      v = q_l / (bv + 1e-16f);
      if (__all(u == uprev && v == vprev)) break;
    }
    if (t < 32) { uuS[t] = u; vvS[t] = v; }
  }
  __syncthreads();
  // ---- loss over the nonzero 32x32 block ----
  float lacc = 0.f;
#pragma unroll
  for (int q8 = 0; q8 < 4; ++q8) {
    int l = q8 * 256 + t;
    int i = l >> 5, j = l & 31;
    lacc += uuS[i] * G[i][32 + j] * vvS[j] * Cm[i][32 + j];
  }
  lacc = waveSum(lacc);
  if ((t & 63) == 0) red[t >> 6] = lacc;
  __syncthreads();
  if (t == 0)
    atomicAdd(&scal[3], (red[0] + red[1] + red[2] + red[3]) * (1.0f / 256.0f));
}

// ---------------- sum(W^2) ----------------
__global__ void k_wreg(const float* __restrict__ W, float* __restrict__ scal) {
  __shared__ float red[4];
  int t = threadIdx.x;
  int base = blockIdx.x * 2048;
  float ss = 0.f;
#pragma unroll
  for (int p = 0; p < 8; ++p) {
    float v = W[base + p * 256 + t];
    ss += v * v;
  }
  ss = waveSum(ss);
  if ((t & 63) == 0) red[t >> 6] = ss;
  __syncthreads();
  if (t == 0) atomicAdd(&scal[4], red[0] + red[1] + red[2] + red[3]);
}

// ---------------- final combine ----------------
__global__ void k_combine(const float* __restrict__ mu_t, const float* __restrict__ colsum,
                          const float* __restrict__ scal, float* __restrict__ out) {
  __shared__ float red[8];
  int t = threadIdx.x;  // 512
  float dm = mu_t[t] * (1.0f / 256.0f) - colsum[t] * (1.0f / 50000.0f);
  float v = dm * dm;
  v = waveSum(v);
  if ((t & 63) == 0) red[t >> 6] = v;
  __syncthreads();
  if (t == 0) {
    float term_mean = 0.f;
    for (int i = 0; i < 8; ++i) term_mean += red[i];
    float trCT = scal[0] * (1.0f / 255.0f);
    float trCX = scal[1];
    float S = scal[2];
    float term_cov = trCX * 1.001f + trCT * 1.001f - 2.0f * S;
    term_cov = fmaxf(term_cov, 0.f);
    float loss_dist = term_mean + term_cov;
    float loss_knn = scal[3];
    float loss_reg = 0.5f * scal[4];
    out[0] = loss_dist + loss_knn + 1e-4f * loss_reg;
    out[1] = loss_dist;
    out[2] = loss_knn;
  }
}

extern "C" void kernel_launch(void* const* d_in, const int* in_sizes, int n_in,
                              void* d_out, int out_size, void* d_ws, size_t ws_size,
                              hipStream_t stream) {
  const float* q = (const float*)d_in[0];
  const int* qidx = (const int*)d_in[1];
  const float* W = (const float*)d_in[2];
  const float* X = (const float*)d_in[3];
  const int* pre_idx = (const int*)d_in[4];
  const float* prew = (const float*)d_in[5];
  float* out = (float*)d_out;
  float* ws = (float*)d_ws;

  float* scal = ws + OFF_SC;
  float* colsum = ws + OFF_CS;
  float* colss = ws + OFF_CSS;
  float* T = ws + OFF_T;
  float* Tc = ws + OFF_TC;
  float* H = ws + OFF_H;
  float* mu_t = ws + OFF_MUT;
  float* xsq = ws + OFF_XSQ;
  int* runi = (int*)(ws + OFF_RUNI);
  float* postw = ws + OFF_PW;
  float* prewn = ws + OFF_PRW;
  float* V = ws + OFF_D2;
  float* UUT = ws + OFF_UUT;
  float* TcTc = ws + OFF_TCTC;
  float* wv = ws + OFF_W;
  float* m = ws + OFF_M;
  float* candv = ws + OFF_P;              // 256*256 floats; dead before NS Y2/Z2
  int* candi = (int*)(ws + OFF_P + 65536);

  hipMemsetAsync(d_ws, 0, (size_t)ZERO_F * 4, stream);

  // T = q @ W (+ fused raw column sums of T into mu_t)
  k_g64_nn<<<dim3(8, 4), 256, 0, stream>>>(q, W, T, 512, 512, 512, 512, 1.0f, mu_t);
  // X stats
  k_colstatX<<<250, 256, 0, stream>>>(X, colsum, colss);
  k_xsq<<<12500, 256, 0, stream>>>(X, xsq);
  // T stats
  k_centerT<<<128, 256, 0, stream>>>(T, mu_t, Tc, scal);
  k_trCX<<<1, 512, 0, stream>>>(colsum, colss, scal);
  // V = T @ X^T (MFMA, prefetch, + fused colmeans -> m)
  k_vgemm<<<dim3(391, 2), 256, 0, stream>>>(T, X, V, m);
  // kNN top-32 from d2 = xsq - 2V (threshold-filter)
  k_topk_part<<<dim3(PARTS, 256), 256, 0, stream>>>(V, xsq, candv, candi);
  k_topk_final<<<256, 128, 0, stream>>>(candv, candi, runi);
  // H assembly
  k_g64_nt<<<dim3(4, 4), 256, 0, stream>>>(Tc, Tc, TcTc, 512, 512, 512, 256, 1.0f);
  k_wvec<<<8, 256, 0, stream>>>(T, colsum, wv, scal);
  k_uut<<<dim3(3, 50), 256, 0, stream>>>(V, m, UUT);
  k_hfix<<<256, 256, 0, stream>>>(UUT, TcTc, wv, scal, H);
  // spectral sum via coupled Newton-Schulz, power-iter scaling
  {
    float* Y = ws + OFF_TC;
    float* Z = ws + OFF_TC + 65536;
    float* Y2 = ws + OFF_P;
    float* Z2 = ws + OFF_P + 65536;
    float* Pm = ws + OFF_G;
    k_power<<<1, 256, 0, stream>>>(H, scal);
    k_nsinit<<<256, 256, 0, stream>>>(H, scal, Y, Z);
    for (int it = 0; it < NS_ITERS; ++it) {
      k_nsp<<<dim3(4, 4), 256, 0, stream>>>(Z, Y, Pm);
      k_nsu<<<dim3(4, 4, 2), 256, 0, stream>>>(Y, Z, Pm, Y2, Z2);
      float* tmp = Y; Y = Y2; Y2 = tmp;
      tmp = Z; Z = Z2; Z2 = tmp;
    }
    k_ns_trace<<<1, 256, 0, stream>>>(Y, scal);
  }
  // kNN OT loss
  k_l2soft<<<256, 64, 0, stream>>>(T, X, runi, qidx, prew, postw, prewn);
  k_batch<<<256, 256, 0, stream>>>(X, qidx, pre_idx, runi, prewn, postw, scal);
  k_wreg<<<128, 256, 0, stream>>>(W, scal);
  k_combine<<<1, 512, 0, stream>>>(mu_t, colsum, scal, out);
}

// Round 5
// 905.264 us; speedup vs baseline: 1.4867x; 1.0219x over previous
//
#include <hip/hip_runtime.h>
#include <float.h>
#include <math.h>

// Problem constants
#define BB 256
#define DD 512
#define NN 50000
#define KK 32
#define NS_ITERS 11
#define PARTS 8
#define PCH 6250

// Workspace layout (float offsets)
#define OFF_G     0         // 1M-float region: UUT(65536) + TcTc(65536) + w(256) + m(50000); NS Pm reuses +0
#define OFF_SC    262144    // 64 scalars: 0=sumTc2 1=trCX 2=S_total 3=knn 4=wreg 5=s_ns 6=wsum
#define OFF_CS    262208    // 512 colsum X
#define OFF_CSS   262720    // 512 colsumsq X
#define ZERO_F    263232    // floats to memset
#define OFF_T     263232    // 256*512
#define OFF_TC    394304    // 256*512 Tc; later NS Y/Z
#define OFF_P     525376    // 256*512: top-k cand buffers; later NS Y2/Z2
#define OFF_H     656448    // 256*256
#define OFF_XSQ   723008    // 50000
#define OFF_RUNI  781200    // 256*32 (int)
#define OFF_PW    789392    // 256*32 post_w
#define OFF_PRW   797584    // 256*32 pre_w normalized
#define OFF_D2    805776    // V = T@X^T  (256*50000)

#define OFF_UUT   (OFF_G)
#define OFF_TCTC  (OFF_G + 65536)
#define OFF_W     (OFF_G + 131072)
#define OFF_M     (OFF_G + 131328)
#define OFF_MUT   (OFF_G + 200000)   // 512 raw col sums of T (zeroed region; free after m)

typedef __attribute__((ext_vector_type(8))) short bf16x8;
typedef __attribute__((ext_vector_type(4))) float f32x4;

__device__ __forceinline__ float waveSum(float v) {
#pragma unroll
  for (int off = 32; off > 0; off >>= 1) v += __shfl_xor(v, off);
  return v;
}

// split fp32x4 -> bf16 hi/lo, write packed pairs to LDS at short-offset sa (16B-aligned rows)
__device__ __forceinline__ void cvt_write(float4 v, unsigned short* hi, unsigned short* lo, int sa) {
  unsigned int b0 = __float_as_uint(v.x), b1 = __float_as_uint(v.y);
  unsigned int b2 = __float_as_uint(v.z), b3 = __float_as_uint(v.w);
  unsigned int h0 = b0 & 0xffff0000u, h1 = b1 & 0xffff0000u;
  unsigned int h2 = b2 & 0xffff0000u, h3 = b3 & 0xffff0000u;
  float l0 = v.x - __uint_as_float(h0), l1 = v.y - __uint_as_float(h1);
  float l2 = v.z - __uint_as_float(h2), l3 = v.w - __uint_as_float(h3);
  *(unsigned int*)&hi[sa]     = (h0 >> 16) | h1;
  *(unsigned int*)&hi[sa + 2] = (h2 >> 16) | h3;
  *(unsigned int*)&lo[sa]     = (__float_as_uint(l0) >> 16) | (__float_as_uint(l1) & 0xffff0000u);
  *(unsigned int*)&lo[sa + 2] = (__float_as_uint(l2) >> 16) | (__float_as_uint(l3) & 0xffff0000u);
}

// scalar fp32 -> bf16 hi/lo split
__device__ __forceinline__ void cvt1(float x, unsigned short* hp, unsigned short* lp) {
  unsigned int bb = __float_as_uint(x);
  unsigned int hb = bb & 0xffff0000u;
  float lo = x - __uint_as_float(hb);
  *hp = (unsigned short)(hb >> 16);
  *lp = (unsigned short)(__float_as_uint(lo) >> 16);
}

// ---------------- generic 64x64-tile GEMM, C = scale * A @ B (nn); optional colsum epilogue ----
__global__ void __launch_bounds__(256) k_g64_nn(const float* __restrict__ A,
                                                const float* __restrict__ B,
                                                float* __restrict__ C,
                                                int K, int lda, int ldb, int ldc, float scale,
                                                float* __restrict__ musum) {
  __shared__ float As[64][65], Bs[64][65];
  __shared__ float cp[64];
  int m0 = blockIdx.y * 64, n0 = blockIdx.x * 64;
  int t = threadIdx.x, tr = t >> 4, tc = t & 15;
  float acc[4][4] = {{0.f}};
  for (int k0 = 0; k0 < K; k0 += 64) {
#pragma unroll
    for (int p = 0; p < 16; ++p) {
      int l = t + 256 * p;
      int r = l >> 6, c = l & 63;
      As[r][c] = A[(m0 + r) * lda + k0 + c];
      Bs[r][c] = B[(k0 + r) * ldb + n0 + c];
    }
    __syncthreads();
#pragma unroll 16
    for (int kk = 0; kk < 64; ++kk) {
      float a[4], b[4];
#pragma unroll
      for (int u = 0; u < 4; ++u) a[u] = As[tr + 16 * u][kk];
#pragma unroll
      for (int v = 0; v < 4; ++v) b[v] = Bs[kk][tc + 16 * v];
#pragma unroll
      for (int u = 0; u < 4; ++u)
#pragma unroll
        for (int v = 0; v < 4; ++v) acc[u][v] += a[u] * b[v];
    }
    __syncthreads();
  }
#pragma unroll
  for (int u = 0; u < 4; ++u)
#pragma unroll
    for (int v = 0; v < 4; ++v)
      C[(m0 + tr + 16 * u) * ldc + n0 + tc + 16 * v] = acc[u][v] * scale;
  if (musum != nullptr) {
    if (t < 64) cp[t] = 0.f;
    __syncthreads();
#pragma unroll
    for (int v = 0; v < 4; ++v) {
      float s = 0.f;
#pragma unroll
      for (int u = 0; u < 4; ++u) s += acc[u][v];
      atomicAdd(&cp[tc + 16 * v], s * scale);
    }
    __syncthreads();
    if (t < 64) atomicAdd(&musum[n0 + t], cp[t]);
  }
}

// ---------------- generic 64x64-tile GEMM, C = scale * A @ B^T (nt) ----------------
__global__ void __launch_bounds__(256) k_g64_nt(const float* __restrict__ A,
                                                const float* __restrict__ B,
                                                float* __restrict__ C,
                                                int K, int lda, int ldb, int ldc, float scale) {
  __shared__ float As[64][65], Bs[64][65];
  int m0 = blockIdx.y * 64, n0 = blockIdx.x * 64;
  int t = threadIdx.x, tr = t >> 4, tc = t & 15;
  float acc[4][4] = {{0.f}};
  for (int k0 = 0; k0 < K; k0 += 64) {
#pragma unroll
    for (int p = 0; p < 16; ++p) {
      int l = t + 256 * p;
      int r = l >> 6, c = l & 63;
      As[r][c] = A[(m0 + r) * lda + k0 + c];
      Bs[r][c] = B[(n0 + r) * ldb + k0 + c];
    }
    __syncthreads();
#pragma unroll 16
    for (int kk = 0; kk < 64; ++kk) {
      float a[4], b[4];
#pragma unroll
      for (int u = 0; u < 4; ++u) a[u] = As[tr + 16 * u][kk];
#pragma unroll
      for (int v = 0; v < 4; ++v) b[v] = Bs[tc + 16 * v][kk];
#pragma unroll
      for (int u = 0; u < 4; ++u)
#pragma unroll
        for (int v = 0; v < 4; ++v) acc[u][v] += a[u] * b[v];
    }
    __syncthreads();
  }
#pragma unroll
  for (int u = 0; u < 4; ++u)
#pragma unroll
    for (int v = 0; v < 4; ++v)
      C[(m0 + tr + 16 * u) * ldc + n0 + tc + 16 * v] = acc[u][v] * scale;
}

// ---------------- V = T @ X^T  (MFMA bf16-split, reg-prefetch dbuf) + fused colmeans(V) ------
__global__ void __launch_bounds__(256) k_vgemm(const float* __restrict__ T,
                                               const float* __restrict__ X,
                                               float* __restrict__ V,
                                               float* __restrict__ m) {
  __shared__ unsigned short Ah[128 * 72], Al[128 * 72], Bh[128 * 72], Bl[128 * 72];
  __shared__ float colpart[128];
  int bj = blockIdx.x, bi = blockIdx.y;
  int t = threadIdx.x;
  int wave = t >> 6, lane = t & 63;
  int m0 = (wave >> 1) * 64, n0 = (wave & 1) * 64;
  int lrow = lane & 15, lq = lane >> 4;
  int r_ = t >> 4, c4_ = (t & 15) * 4;
  f32x4 acc[4][4] = {};
  float4 pa[8], pb[8];
#pragma unroll
  for (int f = 0; f < 8; ++f) {
    int r = f * 16 + r_;
    pa[f] = *(const float4*)&T[(bi * 128 + r) * 512 + c4_];
    int jg = bj * 128 + r;
    float4 vb = {0.f, 0.f, 0.f, 0.f};
    if (jg < NN) vb = *(const float4*)&X[(size_t)jg * 512 + c4_];
    pb[f] = vb;
  }
  for (int kc = 0; kc < 512; kc += 64) {
#pragma unroll
    for (int f = 0; f < 8; ++f) {
      int sa = (f * 16 + r_) * 72 + c4_;
      cvt_write(pa[f], Ah, Al, sa);
      cvt_write(pb[f], Bh, Bl, sa);
    }
    __syncthreads();
    if (kc < 448) {
      int kn = kc + 64;
#pragma unroll
      for (int f = 0; f < 8; ++f) {
        int r = f * 16 + r_;
        pa[f] = *(const float4*)&T[(bi * 128 + r) * 512 + kn + c4_];
        int jg = bj * 128 + r;
        float4 vb = {0.f, 0.f, 0.f, 0.f};
        if (jg < NN) vb = *(const float4*)&X[(size_t)jg * 512 + kn + c4_];
        pb[f] = vb;
      }
    }
#pragma unroll
    for (int ks = 0; ks < 2; ++ks) {
      int kb = ks * 32 + lq * 8;
      bf16x8 ah[4], al[4], bh[4], bl[4];
#pragma unroll
      for (int mi = 0; mi < 4; ++mi) {
        int ro = (m0 + mi * 16 + lrow) * 72 + kb;
        ah[mi] = *(const bf16x8*)&Ah[ro];
        al[mi] = *(const bf16x8*)&Al[ro];
      }
#pragma unroll
      for (int nj = 0; nj < 4; ++nj) {
        int ro = (n0 + nj * 16 + lrow) * 72 + kb;
        bh[nj] = *(const bf16x8*)&Bh[ro];
        bl[nj] = *(const bf16x8*)&Bl[ro];
      }
#pragma unroll
      for (int mi = 0; mi < 4; ++mi)
#pragma unroll
        for (int nj = 0; nj < 4; ++nj) {
          acc[mi][nj] = __builtin_amdgcn_mfma_f32_16x16x32_bf16(ah[mi], bh[nj], acc[mi][nj], 0, 0, 0);
          acc[mi][nj] = __builtin_amdgcn_mfma_f32_16x16x32_bf16(ah[mi], bl[nj], acc[mi][nj], 0, 0, 0);
          acc[mi][nj] = __builtin_amdgcn_mfma_f32_16x16x32_bf16(al[mi], bh[nj], acc[mi][nj], 0, 0, 0);
        }
    }
    __syncthreads();
  }
  if (t < 128) colpart[t] = 0.f;
  __syncthreads();
#pragma unroll
  for (int mi = 0; mi < 4; ++mi)
#pragma unroll
    for (int nj = 0; nj < 4; ++nj)
#pragma unroll
      for (int r = 0; r < 4; ++r) {
        int row = bi * 128 + m0 + mi * 16 + lq * 4 + r;
        int col = bj * 128 + n0 + nj * 16 + lrow;
        if (col < NN) V[(size_t)row * NN + col] = acc[mi][nj][r];
      }
#pragma unroll
  for (int nj = 0; nj < 4; ++nj) {
    float s = 0.f;
#pragma unroll
    for (int mi = 0; mi < 4; ++mi)
#pragma unroll
      for (int r = 0; r < 4; ++r) s += acc[mi][nj][r];
    atomicAdd(&colpart[n0 + nj * 16 + lrow], s);
  }
  __syncthreads();
  if (t < 128) {
    int col = bj * 128 + t;
    if (col < NN) atomicAdd(&m[col], colpart[t] * (1.0f / 256.0f));
  }
}

// ---------------- UUT += U @ U^T, U = V - m (MFMA bf16-split, reg-prefetch, split-K atomic) ---
__global__ void __launch_bounds__(256) k_uut(const float* __restrict__ V,
                                             const float* __restrict__ m,
                                             float* __restrict__ UUT) {
  __shared__ unsigned short Ah[128 * 72], Al[128 * 72], Bh[128 * 72], Bl[128 * 72];
  __shared__ __align__(16) float ms[1000];
  const int pi_[3] = {0, 0, 1}, pj_[3] = {0, 1, 1};
  int bi = pi_[blockIdx.x], bj = pj_[blockIdx.x];
  int j0 = blockIdx.y * 1000, jlim = j0 + 1000;
  int t = threadIdx.x;
  int wave = t >> 6, lane = t & 63;
  int m0 = (wave >> 1) * 64, n0 = (wave & 1) * 64;
  int lrow = lane & 15, lq = lane >> 4;
  int r_ = t >> 4, c4_ = (t & 15) * 4;
  f32x4 acc[4][4] = {};
  if (t < 250) ((float4*)ms)[t] = *(const float4*)&m[j0 + t * 4];
  float4 pa[8], pb[8];
#pragma unroll
  for (int f = 0; f < 8; ++f) {
    int r = f * 16 + r_;
    int jb = j0 + c4_;
    float4 va = {0.f, 0.f, 0.f, 0.f}, vb = {0.f, 0.f, 0.f, 0.f};
    if (jb < jlim) {
      va = *(const float4*)&V[(size_t)(bi * 128 + r) * NN + jb];
      vb = *(const float4*)&V[(size_t)(bj * 128 + r) * NN + jb];
    }
    pa[f] = va; pb[f] = vb;
  }
  __syncthreads();
  for (int ch = 0; ch < 16; ++ch) {
    int jc = j0 + ch * 64;
#pragma unroll
    for (int f = 0; f < 8; ++f) {
      int sa = (f * 16 + r_) * 72 + c4_;
      int jb = jc + c4_;
      float4 va = pa[f], vb = pb[f];
      if (jb < jlim) {
        float4 mm = *(const float4*)&ms[jb - j0];
        va.x -= mm.x; va.y -= mm.y; va.z -= mm.z; va.w -= mm.w;
        vb.x -= mm.x; vb.y -= mm.y; vb.z -= mm.z; vb.w -= mm.w;
      }
      cvt_write(va, Ah, Al, sa);
      cvt_write(vb, Bh, Bl, sa);
    }
    __syncthreads();
    if (ch < 15) {
      int jn = j0 + (ch + 1) * 64;
#pragma unroll
      for (int f = 0; f < 8; ++f) {
        int r = f * 16 + r_;
        int jb = jn + c4_;
        float4 va = {0.f, 0.f, 0.f, 0.f}, vb = {0.f, 0.f, 0.f, 0.f};
        if (jb < jlim) {
          va = *(const float4*)&V[(size_t)(bi * 128 + r) * NN + jb];
          vb = *(const float4*)&V[(size_t)(bj * 128 + r) * NN + jb];
        }
        pa[f] = va; pb[f] = vb;
      }
    }
#pragma unroll
    for (int ks = 0; ks < 2; ++ks) {
      int kb = ks * 32 + lq * 8;
      bf16x8 ah[4], al[4], bh[4], bl[4];
#pragma unroll
      for (int mi = 0; mi < 4; ++mi) {
        int ro = (m0 + mi * 16 + lrow) * 72 + kb;
        ah[mi] = *(const bf16x8*)&Ah[ro];
        al[mi] = *(const bf16x8*)&Al[ro];
      }
#pragma unroll
      for (int nj = 0; nj < 4; ++nj) {
        int ro = (n0 + nj * 16 + lrow) * 72 + kb;
        bh[nj] = *(const bf16x8*)&Bh[ro];
        bl[nj] = *(const bf16x8*)&Bl[ro];
      }
#pragma unroll
      for (int mi = 0; mi < 4; ++mi)
#pragma unroll
        for (int nj = 0; nj < 4; ++nj) {
          acc[mi][nj] = __builtin_amdgcn_mfma_f32_16x16x32_bf16(ah[mi], bh[nj], acc[mi][nj], 0, 0, 0);
          acc[mi][nj] = __builtin_amdgcn_mfma_f32_16x16x32_bf16(ah[mi], bl[nj], acc[mi][nj], 0, 0, 0);
          acc[mi][nj] = __builtin_amdgcn_mfma_f32_16x16x32_bf16(al[mi], bh[nj], acc[mi][nj], 0, 0, 0);
        }
    }
    __syncthreads();
  }
#pragma unroll
  for (int mi = 0; mi < 4; ++mi)
#pragma unroll
    for (int nj = 0; nj < 4; ++nj)
#pragma unroll
      for (int r = 0; r < 4; ++r) {
        int row = bi * 128 + m0 + mi * 16 + lq * 4 + r;
        int col = bj * 128 + n0 + nj * 16 + lrow;
        atomicAdd(&UUT[row * 256 + col], acc[mi][nj][r]);
      }
}

// ---------------- fused X stats: column sums/sumsq + per-row sq-norm (ONE X pass) ------------
// 250 blocks x 4 waves x 50 rows. Lane owns cols lane*4..+3 and 256+lane*4..+3.
__global__ void __launch_bounds__(256) k_colstatX(const float* __restrict__ X, float* __restrict__ colsum,
                                                  float* __restrict__ colss, float* __restrict__ xsq) {
  __shared__ float shs[512], shq[512];
  int b = blockIdx.x, t = threadIdx.x;
  int wave = t >> 6, lane = t & 63;
  shs[t] = 0.f; shq[t] = 0.f; shs[t + 256] = 0.f; shq[t + 256] = 0.f;
  __syncthreads();
  int c0 = lane * 4;
  float s0 = 0, s1 = 0, s2 = 0, s3 = 0, s4 = 0, s5 = 0, s6 = 0, s7 = 0;
  float q0 = 0, q1 = 0, q2 = 0, q3 = 0, q4 = 0, q5 = 0, q6 = 0, q7 = 0;
  int r0 = b * 200 + wave * 50;
  for (int rr = 0; rr < 50; ++rr) {
    const float* Xr = X + (size_t)(r0 + rr) * 512;
    float4 a = *(const float4*)&Xr[c0];
    float4 c = *(const float4*)&Xr[c0 + 256];
    s0 += a.x; s1 += a.y; s2 += a.z; s3 += a.w;
    s4 += c.x; s5 += c.y; s6 += c.z; s7 += c.w;
    float ax = a.x * a.x, ay = a.y * a.y, az = a.z * a.z, aw = a.w * a.w;
    float cx = c.x * c.x, cy = c.y * c.y, cz = c.z * c.z, cw = c.w * c.w;
    q0 += ax; q1 += ay; q2 += az; q3 += aw;
    q4 += cx; q5 += cy; q6 += cz; q7 += cw;
    float rsq = waveSum(((ax + ay) + (az + aw)) + ((cx + cy) + (cz + cw)));
    if (lane == 0) xsq[r0 + rr] = rsq;
  }
  atomicAdd(&shs[c0 + 0], s0); atomicAdd(&shs[c0 + 1], s1);
  atomicAdd(&shs[c0 + 2], s2); atomicAdd(&shs[c0 + 3], s3);
  atomicAdd(&shs[c0 + 256], s4); atomicAdd(&shs[c0 + 257], s5);
  atomicAdd(&shs[c0 + 258], s6); atomicAdd(&shs[c0 + 259], s7);
  atomicAdd(&shq[c0 + 0], q0); atomicAdd(&shq[c0 + 1], q1);
  atomicAdd(&shq[c0 + 2], q2); atomicAdd(&shq[c0 + 3], q3);
  atomicAdd(&shq[c0 + 256], q4); atomicAdd(&shq[c0 + 257], q5);
  atomicAdd(&shq[c0 + 258], q6); atomicAdd(&shq[c0 + 259], q7);
  __syncthreads();
  atomicAdd(&colsum[t], shs[t]);             atomicAdd(&colss[t], shq[t]);
  atomicAdd(&colsum[t + 256], shs[t + 256]); atomicAdd(&colss[t + 256], shq[t + 256]);
}

// ---------------- Tc = T - mu, accumulate sum(Tc^2) ----------------
__global__ void k_centerT(const float* __restrict__ T, const float* __restrict__ mu,
                          float* __restrict__ Tc, float* __restrict__ scal) {
  __shared__ float red[4];
  int t = threadIdx.x;
  int base = blockIdx.x * 1024;
  float ss = 0.f;
#pragma unroll
  for (int p = 0; p < 4; ++p) {
    int l = base + p * 256 + t;
    float v = T[l] - mu[l & 511] * (1.0f / 256.0f);
    Tc[l] = v;
    ss += v * v;
  }
  ss = waveSum(ss);
  if ((t & 63) == 0) red[t >> 6] = ss;
  __syncthreads();
  if (t == 0) atomicAdd(&scal[0], red[0] + red[1] + red[2] + red[3]);
}

// ---------------- trace of cov(X) ----------------
__global__ void k_trCX(const float* __restrict__ colsum, const float* __restrict__ colss,
                       float* __restrict__ scal) {
  __shared__ float red[8];
  int t = threadIdx.x;  // 512
  float mu = colsum[t] * (1.0f / 50000.0f);
  float v = (colss[t] - 50000.0f * mu * mu) * (1.0f / 49999.0f);
  v = waveSum(v);
  if ((t & 63) == 0) red[t >> 6] = v;
  __syncthreads();
  if (t == 0) {
    float s = 0;
    for (int i = 0; i < 8; ++i) s += red[i];
    scal[1] = s;
  }
}

// ---------------- w_i = T_i . muX (raw), wsum -> scal[6]; mean folded into k_hfix ----------------
__global__ void __launch_bounds__(256) k_wvec(const float* __restrict__ T,
                                              const float* __restrict__ colsum,
                                              float* __restrict__ w, float* __restrict__ scal) {
  __shared__ float cs[512];
  int t = threadIdx.x, lane = t & 63, wv_ = t >> 6;
  cs[t] = colsum[t] * (1.0f / 50000.0f);
  cs[t + 256] = colsum[t + 256] * (1.0f / 50000.0f);
  __syncthreads();
  int rbase = blockIdx.x * 32 + wv_ * 8;
  float tot = 0.f;
  for (int rr = 0; rr < 8; ++rr) {
    int row = rbase + rr;
    float a = 0.f;
#pragma unroll
    for (int d = 0; d < 8; ++d) a += T[row * 512 + lane + 64 * d] * cs[lane + 64 * d];
    a = waveSum(a);
    if (lane == 0) { w[row] = a; tot += a; }
  }
  if (lane == 0) atomicAdd(&scal[6], tot);
}

// ---------------- H = (UUT - N (w-wm)(w-wm)^T)/(49999*255) + rhoX * TcTc/255 ----------------
__global__ void k_hfix(const float* __restrict__ UUT, const float* __restrict__ TcTc,
                       const float* __restrict__ w, const float* __restrict__ scal,
                       float* __restrict__ H) {
  int l = blockIdx.x * 256 + threadIdx.x;
  int i = l >> 8, j = l & 255;
  float u = (i >= 128 && j < 128) ? UUT[j * 256 + i] : UUT[i * 256 + j];
  float rho = scal[1] * (1e-3f / 512.0f);
  float wm = scal[6] * (1.0f / 256.0f);
  float wi = w[i] - wm, wj = w[j] - wm;
  H[l] = (u - 50000.0f * wi * wj) * (1.0f / (49999.0f * 255.0f))
       + rho * TcTc[i * 256 + j] * (1.0f / 255.0f);
}

// ---------------- power iteration: scal[5] = safe lambda_max bound of H' (H symmetric) -------
__global__ void __launch_bounds__(256) k_power(const float* __restrict__ H,
                                               float* __restrict__ scal) {
  __shared__ float v[256], nv[256], red[4];
  int t = threadIdx.x;
  float rt = scal[0] * (1.0f / 255.0f) * (1e-3f / 512.0f);
  v[t] = 1.0f;
  __syncthreads();
  float n2 = 256.0f, n3 = 256.0f;
  for (int it = 0; it < 3; ++it) {
    float s = rt * v[t];
    for (int j = 0; j < 256; ++j) s += H[j * 256 + t] * v[j];  // coalesced via symmetry
    nv[t] = s;
    float ss = waveSum(s * s);
    if ((t & 63) == 0) red[t >> 6] = ss;
    __syncthreads();
    float norm2 = red[0] + red[1] + red[2] + red[3];
    if (it == 1) n2 = norm2;
    if (it == 2) n3 = norm2;
    v[t] = nv[t];
    __syncthreads();
  }
  float d = H[t * 256 + t] + rt;
#pragma unroll
  for (int off = 32; off > 0; off >>= 1) d = fmaxf(d, __shfl_xor(d, off));
  if ((t & 63) == 0) red[t >> 6] = d;
  __syncthreads();
  if (t == 0) {
    float lam = sqrtf(n3 / n2);
    float md = fmaxf(fmaxf(red[0], red[1]), fmaxf(red[2], red[3]));
    scal[5] = fmaxf(1.3f * lam, md);
  }
}

// ---------------- Y0 = (H + rt I)/s, Z0 = I ----------------
__global__ void k_nsinit(const float* __restrict__ H, const float* __restrict__ scal,
                         float* __restrict__ Y, float* __restrict__ Z) {
  int l = blockIdx.x * 256 + threadIdx.x;
  int i = l >> 8, j = l & 255;
  float rt = scal[0] * (1.0f / 255.0f) * (1e-3f / 512.0f);
  float inv = 1.0f / scal[5];
  Y[l] = (H[l] + ((i == j) ? rt : 0.f)) * inv;
  Z[l] = (i == j) ? 1.0f : 0.f;
}

// ---------------- NS: P = Z @ Y (MFMA bf16-split, nn, 64x64 tiles) ----------------
__global__ void __launch_bounds__(256) k_nsp(const float* __restrict__ Z,
                                             const float* __restrict__ Y,
                                             float* __restrict__ P) {
  __shared__ unsigned short Ah[64 * 72], Al[64 * 72], Bh[64 * 72], Bl[64 * 72];
  int n0b = blockIdx.x * 64, m0b = blockIdx.y * 64;
  int t = threadIdx.x, wave = t >> 6, lane = t & 63;
  int m0 = (wave >> 1) * 32, n0 = (wave & 1) * 32;
  int lrow = lane & 15, lq = lane >> 4;
  f32x4 acc[2][2] = {};
  for (int k0 = 0; k0 < 256; k0 += 64) {
#pragma unroll
    for (int f = 0; f < 4; ++f) {
      int lin = f * 256 + t;
      int r = lin >> 4, c4 = (lin & 15) * 4;
      float4 va = *(const float4*)&Z[(m0b + r) * 256 + k0 + c4];
      cvt_write(va, Ah, Al, r * 72 + c4);
      float4 vb = *(const float4*)&Y[(k0 + r) * 256 + n0b + c4];
      cvt1(vb.x, &Bh[(c4 + 0) * 72 + r], &Bl[(c4 + 0) * 72 + r]);
      cvt1(vb.y, &Bh[(c4 + 1) * 72 + r], &Bl[(c4 + 1) * 72 + r]);
      cvt1(vb.z, &Bh[(c4 + 2) * 72 + r], &Bl[(c4 + 2) * 72 + r]);
      cvt1(vb.w, &Bh[(c4 + 3) * 72 + r], &Bl[(c4 + 3) * 72 + r]);
    }
    __syncthreads();
#pragma unroll
    for (int ks = 0; ks < 2; ++ks) {
      int kb = ks * 32 + lq * 8;
      bf16x8 ah[2], al2[2], bh[2], bl2[2];
#pragma unroll
      for (int mi = 0; mi < 2; ++mi) {
        int ro = (m0 + mi * 16 + lrow) * 72 + kb;
        ah[mi] = *(const bf16x8*)&Ah[ro];
        al2[mi] = *(const bf16x8*)&Al[ro];
      }
#pragma unroll
      for (int nj = 0; nj < 2; ++nj) {
        int ro = (n0 + nj * 16 + lrow) * 72 + kb;
        bh[nj] = *(const bf16x8*)&Bh[ro];
        bl2[nj] = *(const bf16x8*)&Bl[ro];
      }
#pragma unroll
      for (int mi = 0; mi < 2; ++mi)
#pragma unroll
        for (int nj = 0; nj < 2; ++nj) {
          acc[mi][nj] = __builtin_amdgcn_mfma_f32_16x16x32_bf16(ah[mi], bh[nj], acc[mi][nj], 0, 0, 0);
          acc[mi][nj] = __builtin_amdgcn_mfma_f32_16x16x32_bf16(ah[mi], bl2[nj], acc[mi][nj], 0, 0, 0);
          acc[mi][nj] = __builtin_amdgcn_mfma_f32_16x16x32_bf16(al2[mi], bh[nj], acc[mi][nj], 0, 0, 0);
        }
    }
    __syncthreads();
  }
#pragma unroll
  for (int mi = 0; mi < 2; ++mi)
#pragma unroll
    for (int nj = 0; nj < 2; ++nj)
#pragma unroll
      for (int r = 0; r < 4; ++r) {
        int row = m0b + m0 + mi * 16 + lq * 4 + r;
        int col = n0b + n0 + nj * 16 + lrow;
        P[row * 256 + col] = acc[mi][nj][r];
      }
}

// ---------------- NS update: O = 1.5 D - 0.5 A@B (MFMA bf16-split, nn) ----------------
__global__ void __launch_bounds__(256) k_nsu(const float* __restrict__ Y, const float* __restrict__ Z,
                                             const float* __restrict__ Pm,
                                             float* __restrict__ Yn, float* __restrict__ Zn) {
  __shared__ unsigned short Ah[64 * 72], Al[64 * 72], Bh[64 * 72], Bl[64 * 72];
  int zz = blockIdx.z;
  const float* A = zz ? Pm : Y;
  const float* B = zz ? Z : Pm;
  const float* D = zz ? Z : Y;
  float* O = zz ? Zn : Yn;
  int n0b = blockIdx.x * 64, m0b = blockIdx.y * 64;
  int t = threadIdx.x, wave = t >> 6, lane = t & 63;
  int m0 = (wave >> 1) * 32, n0 = (wave & 1) * 32;
  int lrow = lane & 15, lq = lane >> 4;
  f32x4 acc[2][2] = {};
  for (int k0 = 0; k0 < 256; k0 += 64) {
#pragma unroll
    for (int f = 0; f < 4; ++f) {
      int lin = f * 256 + t;
      int r = lin >> 4, c4 = (lin & 15) * 4;
      float4 va = *(const float4*)&A[(m0b + r) * 256 + k0 + c4];
      cvt_write(va, Ah, Al, r * 72 + c4);
      float4 vb = *(const float4*)&B[(k0 + r) * 256 + n0b + c4];
      cvt1(vb.x, &Bh[(c4 + 0) * 72 + r], &Bl[(c4 + 0) * 72 + r]);
      cvt1(vb.y, &Bh[(c4 + 1) * 72 + r], &Bl[(c4 + 1) * 72 + r]);
      cvt1(vb.z, &Bh[(c4 + 2) * 72 + r], &Bl[(c4 + 2) * 72 + r]);
      cvt1(vb.w, &Bh[(c4 + 3) * 72 + r], &Bl[(c4 + 3) * 72 + r]);
    }
    __syncthreads();
#pragma unroll
    for (int ks = 0; ks < 2; ++ks) {
      int kb = ks * 32 + lq * 8;
      bf16x8 ah[2], al2[2], bh[2], bl2[2];
#pragma unroll
      for (int mi = 0; mi < 2; ++mi) {
        int ro = (m0 + mi * 16 + lrow) * 72 + kb;
        ah[mi] = *(const bf16x8*)&Ah[ro];
        al2[mi] = *(const bf16x8*)&Al[ro];
      }
#pragma unroll
      for (int nj = 0; nj < 2; ++nj) {
        int ro = (n0 + nj * 16 + lrow) * 72 + kb;
        bh[nj] = *(const bf16x8*)&Bh[ro];
        bl2[nj] = *(const bf16x8*)&Bl[ro];
      }
#pragma unroll
      for (int mi = 0; mi < 2; ++mi)
#pragma unroll
        for (int nj = 0; nj < 2; ++nj) {
          acc[mi][nj] = __builtin_amdgcn_mfma_f32_16x16x32_bf16(ah[mi], bh[nj], acc[mi][nj], 0, 0, 0);
          acc[mi][nj] = __builtin_amdgcn_mfma_f32_16x16x32_bf16(ah[mi], bl2[nj], acc[mi][nj], 0, 0, 0);
          acc[mi][nj] = __builtin_amdgcn_mfma_f32_16x16x32_bf16(al2[mi], bh[nj], acc[mi][nj], 0, 0, 0);
        }
    }
    __syncthreads();
  }
#pragma unroll
  for (int mi = 0; mi < 2; ++mi)
#pragma unroll
    for (int nj = 0; nj < 2; ++nj)
#pragma unroll
      for (int r = 0; r < 4; ++r) {
        int row = m0b + m0 + mi * 16 + lq * 4 + r;
        int col = n0b + n0 + nj * 16 + lrow;
        int idx = row * 256 + col;
        O[idx] = 1.5f * D[idx] - 0.5f * acc[mi][nj][r];
      }
}

// ---------------- S_total = sqrt(s)*tr(Y) + 256*sqrt(rt) ----------------
__global__ void k_ns_trace(const float* __restrict__ Y, float* __restrict__ scal) {
  __shared__ float red[4];
  int t = threadIdx.x;  // 256
  float v = Y[t * 256 + t];
  v = waveSum(v);
  if ((t & 63) == 0) red[t >> 6] = v;
  __syncthreads();
  if (t == 0) {
    float tr = red[0] + red[1] + red[2] + red[3];
    float rt = scal[0] * (1.0f / 255.0f) * (1e-3f / 512.0f);
    scal[2] = sqrtf(scal[5]) * tr + 256.0f * sqrtf(rt);
  }
}

// ---------------- stage 1: threshold-filter exact top-32 per (query, 1/8-slice) ----------------
__global__ void __launch_bounds__(256) k_topk_part(const float* __restrict__ V,
                                                   const float* __restrict__ xsq,
                                                   float* __restrict__ candv,
                                                   int* __restrict__ candi) {
  __shared__ float bufv[512];
  __shared__ int bufi[512];
  __shared__ int lcount;
  __shared__ float tvs;
  __shared__ int tis;
  int part = blockIdx.x, q = blockIdx.y, t = threadIdx.x;
  int base = part * PCH;
  int lane = t & 63;
  if (t == 0) { lcount = 0; tvs = FLT_MAX; tis = 0x7fffffff; }
  __syncthreads();
  const float* rowV = V + (size_t)q * NN + base;
  const float* xs = xsq + base;

  auto flush = [&]() {
    __syncthreads();
    int c = lcount;
    for (int s = c + t; s < 512; s += 256) { bufv[s] = FLT_MAX; bufi[s] = 0x7fffffff; }
    __syncthreads();
    for (int ssz = 2; ssz <= 512; ssz <<= 1) {
      for (int st = ssz >> 1; st > 0; st >>= 1) {
        int i = 2 * t - (t & (st - 1));
        int j = i + st;
        bool up = ((i & ssz) == 0);
        float a = bufv[i], b = bufv[j];
        int ai = bufi[i], bi2 = bufi[j];
        bool agtb = (a > b) || (a == b && ai > bi2);
        if (agtb == up) { bufv[i] = b; bufv[j] = a; bufi[i] = bi2; bufi[j] = ai; }
        __syncthreads();
      }
    }
    if (t == 0) { lcount = 32; tvs = bufv[31]; tis = bufi[31]; }
    __syncthreads();
  };

  int ntile = (PCH + 255) >> 8;
  for (int tile = 0; tile < ntile; ++tile) {
    int j = tile * 256 + t;
    float val = 0.f; int idx = 0;
    bool pred = false;
    if (j < PCH) {
      val = xs[j] - 2.0f * rowV[j];
      idx = base + j;
      float tv = tvs; int ti = tis;
      pred = (val < tv) || (val == tv && idx < ti);
    }
    unsigned long long mask = __ballot(pred);
    if (mask) {
      int lead = __ffsll((unsigned long long)mask) - 1;
      int cnt = __popcll(mask);
      int basep = 0;
      if (lane == lead) basep = atomicAdd(&lcount, cnt);
      basep = __shfl(basep, lead);
      if (pred) {
        int off = __popcll(mask & ((1ull << lane) - 1ull));
        int slot = basep + off;
        bufv[slot] = val; bufi[slot] = idx;
      }
    }
    __syncthreads();
    if (lcount >= 256) flush();
  }
  flush();
  if (t < 32) {
    candv[(q * PARTS + part) * 32 + t] = bufv[t];
    candi[(q * PARTS + part) * 32 + t] = bufi[t];
  }
}

// ---------------- stage 2: bitonic-sort 256 candidates, emit top-32 indices ----------------
__global__ void __launch_bounds__(128) k_topk_final(const float* __restrict__ candv,
                                                    const int* __restrict__ candi,
                                                    int* __restrict__ runi) {
  __shared__ float v[256];
  __shared__ int ix[256];
  int q = blockIdx.x, t = threadIdx.x;
  v[t] = candv[q * 256 + t];
  v[t + 128] = candv[q * 256 + t + 128];
  ix[t] = candi[q * 256 + t];
  ix[t + 128] = candi[q * 256 + t + 128];
  __syncthreads();
  for (int ssz = 2; ssz <= 256; ssz <<= 1) {
    for (int st = ssz >> 1; st > 0; st >>= 1) {
      int i = 2 * t - (t & (st - 1));
      int j = i + st;
      bool up = ((i & ssz) == 0);
      float a = v[i], b = v[j];
      int ai = ix[i], bi = ix[j];
      bool agtb = (a > b) || (a == b && ai > bi);
      if (agtb == up) { v[i] = b; v[j] = a; ix[i] = bi; ix[j] = ai; }
      __syncthreads();
    }
  }
  if (t < 32) runi[q * 32 + t] = ix[t];
}

// ---------------- l2 to neighbors (4 waves x 8 neighbors), softmax post_w, pre_w norm --------
__global__ void __launch_bounds__(256) k_l2soft(const float* __restrict__ T, const float* __restrict__ X,
                                                const int* __restrict__ runi, const int* __restrict__ qidx,
                                                const float* __restrict__ prew, float* __restrict__ postw,
                                                float* __restrict__ prewn) {
  __shared__ float l2s[32];
  int b = blockIdx.x, t = threadIdx.x;
  int wave = t >> 6, lane = t & 63;
  int qi = qidx[b];
  if (wave == 0) {
    float pwv = (lane < 32) ? fmaxf(prew[qi * 32 + lane], 1e-8f) : 0.f;
    float psum = waveSum(pwv);
    if (lane < 32) prewn[b * 32 + lane] = pwv / psum;
  }
  const float* Tb = T + b * 512;
#pragma unroll
  for (int n8 = 0; n8 < 8; ++n8) {
    int n = wave * 8 + n8;
    int nb = runi[b * 32 + n];
    const float* Xr = X + (size_t)nb * 512;
    float acc = 0.f;
#pragma unroll
    for (int d = 0; d < 8; ++d) {
      float df = Tb[lane + 64 * d] - Xr[lane + 64 * d];
      acc += df * df;
    }
    acc = waveSum(acc);
    if (lane == 0) l2s[n] = acc;
  }
  __syncthreads();
  if (wave == 0) {
    float lg = (lane < 32) ? (-l2s[lane] * 10.0f) : -FLT_MAX;
    float mx = lg;
#pragma unroll
    for (int off = 32; off > 0; off >>= 1) mx = fmaxf(mx, __shfl_xor(mx, off));
    float e = (lane < 32) ? expf(lg - mx) : 0.f;
    float es = waveSum(e);
    float wv = e / es;
    wv = fmaxf(wv, 1e-8f);
    float ws2 = (lane < 32) ? wv : 0.f;
    ws2 = waveSum(ws2);
    if (lane < 32) postw[b * 32 + lane] = wv / ws2;
  }
}

// ---------------- fused per-batch: Gram(MFMA) -> C -> median(bit-search) -> Sinkhorn -> loss --
// Median: rank-992 of the 2016 upper-tri values via 31-step binary search on the monotone uint
// encoding; counts via ballot+popc (no LDS atomics -- the radix histogram serialized on
// clustered exponents). Sinkhorn: period-1 AND period-2 bitwise-cycle detection; period-2
// break picks state(199) by parity, so the result is EXACTLY the 200-iteration state.
__global__ void __launch_bounds__(256) k_batch(const float* __restrict__ X, const int* __restrict__ qidx,
                                               const int* __restrict__ pre_idx, const int* __restrict__ runi,
                                               const float* __restrict__ prewn, const float* __restrict__ postw,
                                               float* __restrict__ scal) {
  __shared__ float G[64][65];
  __shared__ float Cm[64][65];
  __shared__ unsigned short Ah[64 * 72], Al[64 * 72];
  __shared__ int supp[64];
  __shared__ float uuS[32], vvS[32];
  __shared__ float red[4];
  __shared__ float medsh;
  __shared__ unsigned int cw[4], mw[4];
  int b = blockIdx.x, t = threadIdx.x;
  int wave = t >> 6, lane = t & 63;
  if (t < 32) supp[t] = pre_idx[qidx[b] * 32 + t];
  else if (t < 64) supp[t] = runi[b * 32 + t - 32];
  __syncthreads();
  // ---- Gram G = S @ S^T via MFMA bf16-split (A = B), reg-prefetch ----
  {
    int m0 = (wave >> 1) * 32, n0 = (wave & 1) * 32;
    int lrow = lane & 15, lq = lane >> 4;
    int r_ = t >> 4, c4_ = (t & 15) * 4;
    f32x4 acc[2][2] = {};
    float4 pf[4];
#pragma unroll
    for (int f = 0; f < 4; ++f) {
      int r = f * 16 + r_;
      pf[f] = *(const float4*)&X[(size_t)supp[r] * 512 + c4_];
    }
    for (int kc = 0; kc < 512; kc += 64) {
#pragma unroll
      for (int f = 0; f < 4; ++f)
        cvt_write(pf[f], Ah, Al, (f * 16 + r_) * 72 + c4_);
      __syncthreads();
      if (kc < 448) {
        int kn = kc + 64;
#pragma unroll
        for (int f = 0; f < 4; ++f) {
          int r = f * 16 + r_;
          pf[f] = *(const float4*)&X[(size_t)supp[r] * 512 + kn + c4_];
        }
      }
#pragma unroll
      for (int ks = 0; ks < 2; ++ks) {
        int kb = ks * 32 + lq * 8;
        bf16x8 ah[2], al[2], bh[2], bl[2];
#pragma unroll
        for (int mi = 0; mi < 2; ++mi) {
          int ro = (m0 + mi * 16 + lrow) * 72 + kb;
          ah[mi] = *(const bf16x8*)&Ah[ro];
          al[mi] = *(const bf16x8*)&Al[ro];
        }
#pragma unroll
        for (int nj = 0; nj < 2; ++nj) {
          int ro = (n0 + nj * 16 + lrow) * 72 + kb;
          bh[nj] = *(const bf16x8*)&Ah[ro];
          bl[nj] = *(const bf16x8*)&Al[ro];
        }
#pragma unroll
        for (int mi = 0; mi < 2; ++mi)
#pragma unroll
          for (int nj = 0; nj < 2; ++nj) {
            acc[mi][nj] = __builtin_amdgcn_mfma_f32_16x16x32_bf16(ah[mi], bh[nj], acc[mi][nj], 0, 0, 0);
            acc[mi][nj] = __builtin_amdgcn_mfma_f32_16x16x32_bf16(ah[mi], bl[nj], acc[mi][nj], 0, 0, 0);
            acc[mi][nj] = __builtin_amdgcn_mfma_f32_16x16x32_bf16(al[mi], bh[nj], acc[mi][nj], 0, 0, 0);
          }
      }
      __syncthreads();
    }
#pragma unroll
    for (int mi = 0; mi < 2; ++mi)
#pragma unroll
      for (int nj = 0; nj < 2; ++nj)
#pragma unroll
        for (int r = 0; r < 4; ++r)
          G[m0 + mi * 16 + lq * 4 + r][n0 + nj * 16 + lrow] = acc[mi][nj][r];
  }
  __syncthreads();
  // ---- C build + register snapshot of upper-tri uint encodings (sentinel for i>=j) ----
  unsigned int uval[16];
#pragma unroll
  for (int s = 0; s < 16; ++s) {
    int l = s * 256 + t;
    int i = l >> 6, j = l & 63;
    float cc = fmaxf(G[i][i] + G[j][j] - 2.0f * G[i][j], 0.f);
    Cm[i][j] = cc;
    uval[s] = (i < j) ? (__float_as_uint(cc) & 0x7fffffffu) : 0xffffffffu;
  }
  // ---- rank-992 via 31-step bit-descend (count strictly-less via ballot) ----
  unsigned int ans = 0;
  for (int bb = 30; bb >= 0; --bb) {
    unsigned int test = ans | (1u << bb);
    int cw_ = 0;
#pragma unroll
    for (int s = 0; s < 16; ++s)
      cw_ += __popcll(__ballot(uval[s] < test));
    __syncthreads();
    if (lane == 0) red[wave] = (float)cw_;
    __syncthreads();
    int cnt = (int)(red[0] + red[1] + red[2] + red[3]);
    if (cnt < 992) ans = test;
  }
  // ---- v993 = min value > v992 (or v992 if duplicates cover rank 993) ----
  {
    unsigned int target = ans;
    unsigned int cnt = 0, mn = 0xffffffffu;
#pragma unroll
    for (int s = 0; s < 16; ++s) {
      unsigned int u = uval[s];
      if (u <= target) cnt++;
      else mn = (u < mn) ? u : mn;
    }
#pragma unroll
    for (int off = 32; off > 0; off >>= 1) {
      cnt += __shfl_xor(cnt, off);
      unsigned int m2 = __shfl_xor(mn, off);
      mn = (m2 < mn) ? m2 : mn;
    }
    __syncthreads();
    if (lane == 0) { cw[wave] = cnt; mw[wave] = mn; }
    __syncthreads();
    if (t == 0) {
      unsigned int ct = cw[0] + cw[1] + cw[2] + cw[3];
      unsigned int mt = mw[0];
      mt = (mw[1] < mt) ? mw[1] : mt;
      mt = (mw[2] < mt) ? mw[2] : mt;
      mt = (mw[3] < mt) ? mw[3] : mt;
      float v992 = __uint_as_float(target);
      float v993 = (ct >= 993u) ? v992 : __uint_as_float(mt);
      medsh = 0.5f * (v992 + v993) + 1e-8f;
    }
    __syncthreads();
  }
  // ---- normalize C, build K = exp(-10*C) ----
  float inv = 1.0f / medsh;
  for (int l = t; l < 4096; l += 256) {
    int i = l >> 6, j = l & 63;
    float cn = Cm[i][j] * inv;
    Cm[i][j] = cn;
    G[i][j] = expf(-cn * 10.0f);
  }
  __syncthreads();
  // ---- Sinkhorn, wave 0, half-wave split, period-1/2 exact early exit ----
  if (wave == 0) {
    int half = lane >> 5;
    int l = lane & 31;
    int cb = half * 16;
    float p_l = prewn[b * 32 + l];
    float q_l = postw[b * 32 + l];
    float Kr16[16], Kt16[16];
#pragma unroll
    for (int c2 = 0; c2 < 16; ++c2) Kr16[c2] = G[l][32 + cb + c2];
#pragma unroll
    for (int r2 = 0; r2 < 16; ++r2) Kt16[r2] = G[cb + r2][32 + l];
    float r0 = 0.f;
#pragma unroll
    for (int c2 = 0; c2 < 32; ++c2) r0 += G[l][half * 32 + c2];
    r0 += __shfl_xor(r0, 32);
    float u = p_l / (r0 + 1e-16f);
    float s0 = 0.f, s1 = 0.f, s2 = 0.f, s3 = 0.f;
#pragma unroll
    for (int r2 = 0; r2 < 16; r2 += 4) {
      s0 += Kt16[r2]     * __shfl(u, cb + r2);
      s1 += Kt16[r2 + 1] * __shfl(u, cb + r2 + 1);
      s2 += Kt16[r2 + 2] * __shfl(u, cb + r2 + 2);
      s3 += Kt16[r2 + 3] * __shfl(u, cb + r2 + 3);
    }
    float sv = (s0 + s1) + (s2 + s3);
    sv += __shfl_xor(sv, 32);
    float v = q_l / (sv + 1e-16f);
    float pu = u, pv = v;       // state(it-1)
    float ppu = 0.f, ppv = 0.f; // state(it-2), valid for it >= 2
    for (int it = 1; it < 200; ++it) {
      float a0 = 0.f, a1 = 0.f, a2 = 0.f, a3 = 0.f;
#pragma unroll
      for (int c2 = 0; c2 < 16; c2 += 4) {
        a0 += Kr16[c2]     * __shfl(v, cb + c2);
        a1 += Kr16[c2 + 1] * __shfl(v, cb + c2 + 1);
        a2 += Kr16[c2 + 2] * __shfl(v, cb + c2 + 2);
        a3 += Kr16[c2 + 3] * __shfl(v, cb + c2 + 3);
      }
      float au = (a0 + a1) + (a2 + a3);
      au += __shfl_xor(au, 32);
      u = p_l / (au + 1e-16f);
      a0 = 0.f; a1 = 0.f; a2 = 0.f; a3 = 0.f;
#pragma unroll
      for (int r2 = 0; r2 < 16; r2 += 4) {
        a0 += Kt16[r2]     * __shfl(u, cb + r2);
        a1 += Kt16[r2 + 1] * __shfl(u, cb + r2 + 1);
        a2 += Kt16[r2 + 2] * __shfl(u, cb + r2 + 2);
        a3 += Kt16[r2 + 3] * __shfl(u, cb + r2 + 3);
      }
      float bv = (a0 + a1) + (a2 + a3);
      bv += __shfl_xor(bv, 32);
      v = q_l / (bv + 1e-16f);
      if (__all(u == pu && v == pv)) break;           // period-1 fixed point
      if (it >= 2 && __all(u == ppu && v == ppv)) {   // period-2 cycle
        if ((199 - it) & 1) { u = pu; v = pv; }       // pick state(199) parity
        break;
      }
      ppu = pu; ppv = pv; pu = u; pv = v;
    }
    if (t < 32) { uuS[t] = u; vvS[t] = v; }
  }
  __syncthreads();
  // ---- loss over the nonzero 32x32 block ----
  float lacc = 0.f;
#pragma unroll
  for (int q8 = 0; q8 < 4; ++q8) {
    int l = q8 * 256 + t;
    int i = l >> 5, j = l & 31;
    lacc += uuS[i] * G[i][32 + j] * vvS[j] * Cm[i][32 + j];
  }
  lacc = waveSum(lacc);
  if ((t & 63) == 0) red[t >> 6] = lacc;
  __syncthreads();
  if (t == 0)
    atomicAdd(&scal[3], (red[0] + red[1] + red[2] + red[3]) * (1.0f / 256.0f));
}

// ---------------- sum(W^2) ----------------
__global__ void k_wreg(const float* __restrict__ W, float* __restrict__ scal) {
  __shared__ float red[4];
  int t = threadIdx.x;
  int base = blockIdx.x * 2048;
  float ss = 0.f;
#pragma unroll
  for (int p = 0; p < 8; ++p) {
    float v = W[base + p * 256 + t];
    ss += v * v;
  }
  ss = waveSum(ss);
  if ((t & 63) == 0) red[t >> 6] = ss;
  __syncthreads();
  if (t == 0) atomicAdd(&scal[4], red[0] + red[1] + red[2] + red[3]);
}

// ---------------- final combine ----------------
__global__ void k_combine(const float* __restrict__ mu_t, const float* __restrict__ colsum,
                          const float* __restrict__ scal, float* __restrict__ out) {
  __shared__ float red[8];
  int t = threadIdx.x;  // 512
  float dm = mu_t[t] * (1.0f / 256.0f) - colsum[t] * (1.0f / 50000.0f);
  float v = dm * dm;
  v = waveSum(v);
  if ((t & 63) == 0) red[t >> 6] = v;
  __syncthreads();
  if (t == 0) {
    float term_mean = 0.f;
    for (int i = 0; i < 8; ++i) term_mean += red[i];
    float trCT = scal[0] * (1.0f / 255.0f);
    float trCX = scal[1];
    float S = scal[2];
    float term_cov = trCX * 1.001f + trCT * 1.001f - 2.0f * S;
    term_cov = fmaxf(term_cov, 0.f);
    float loss_dist = term_mean + term_cov;
    float loss_knn = scal[3];
    float loss_reg = 0.5f * scal[4];
    out[0] = loss_dist + loss_knn + 1e-4f * loss_reg;
    out[1] = loss_dist;
    out[2] = loss_knn;
  }
}

extern "C" void kernel_launch(void* const* d_in, const int* in_sizes, int n_in,
                              void* d_out, int out_size, void* d_ws, size_t ws_size,
                              hipStream_t stream) {
  const float* q = (const float*)d_in[0];
  const int* qidx = (const int*)d_in[1];
  const float* W = (const float*)d_in[2];
  const float* X = (const float*)d_in[3];
  const int* pre_idx = (const int*)d_in[4];
  const float* prew = (const float*)d_in[5];
  float* out = (float*)d_out;
  float* ws = (float*)d_ws;

  float* scal = ws + OFF_SC;
  float* colsum = ws + OFF_CS;
  float* colss = ws + OFF_CSS;
  float* T = ws + OFF_T;
  float* Tc = ws + OFF_TC;
  float* H = ws + OFF_H;
  float* mu_t = ws + OFF_MUT;
  float* xsq = ws + OFF_XSQ;
  int* runi = (int*)(ws + OFF_RUNI);
  float* postw = ws + OFF_PW;
  float* prewn = ws + OFF_PRW;
  float* V = ws + OFF_D2;
  float* UUT = ws + OFF_UUT;
  float* TcTc = ws + OFF_TCTC;
  float* wv = ws + OFF_W;
  float* m = ws + OFF_M;
  float* candv = ws + OFF_P;              // 256*256 floats; dead before NS Y2/Z2
  int* candi = (int*)(ws + OFF_P + 65536);

  hipMemsetAsync(d_ws, 0, (size_t)ZERO_F * 4, stream);

  // T = q @ W (+ fused raw column sums of T into mu_t)
  k_g64_nn<<<dim3(8, 4), 256, 0, stream>>>(q, W, T, 512, 512, 512, 512, 1.0f, mu_t);
  // X stats (column sums/sumsq + row sq-norms in ONE pass)
  k_colstatX<<<250, 256, 0, stream>>>(X, colsum, colss, xsq);
  // T stats
  k_centerT<<<128, 256, 0, stream>>>(T, mu_t, Tc, scal);
  k_trCX<<<1, 512, 0, stream>>>(colsum, colss, scal);
  // V = T @ X^T (MFMA, prefetch, + fused colmeans -> m)
  k_vgemm<<<dim3(391, 2), 256, 0, stream>>>(T, X, V, m);
  // kNN top-32 from d2 = xsq - 2V (threshold-filter)
  k_topk_part<<<dim3(PARTS, 256), 256, 0, stream>>>(V, xsq, candv, candi);
  k_topk_final<<<256, 128, 0, stream>>>(candv, candi, runi);
  // H assembly
  k_g64_nt<<<dim3(4, 4), 256, 0, stream>>>(Tc, Tc, TcTc, 512, 512, 512, 256, 1.0f);
  k_wvec<<<8, 256, 0, stream>>>(T, colsum, wv, scal);
  k_uut<<<dim3(3, 50), 256, 0, stream>>>(V, m, UUT);
  k_hfix<<<256, 256, 0, stream>>>(UUT, TcTc, wv, scal, H);
  // spectral sum via coupled Newton-Schulz, power-iter scaling
  {
    float* Y = ws + OFF_TC;
    float* Z = ws + OFF_TC + 65536;
    float* Y2 = ws + OFF_P;
    float* Z2 = ws + OFF_P + 65536;
    float* Pm = ws + OFF_G;
    k_power<<<1, 256, 0, stream>>>(H, scal);
    k_nsinit<<<256, 256, 0, stream>>>(H, scal, Y, Z);
    for (int it = 0; it < NS_ITERS; ++it) {
      k_nsp<<<dim3(4, 4), 256, 0, stream>>>(Z, Y, Pm);
      k_nsu<<<dim3(4, 4, 2), 256, 0, stream>>>(Y, Z, Pm, Y2, Z2);
      float* tmp = Y; Y = Y2; Y2 = tmp;
      tmp = Z; Z = Z2; Z2 = tmp;
    }
    k_ns_trace<<<1, 256, 0, stream>>>(Y, scal);
  }
  // kNN OT loss
  k_l2soft<<<256, 256, 0, stream>>>(T, X, runi, qidx, prew, postw, prewn);
  k_batch<<<256, 256, 0, stream>>>(X, qidx, pre_idx, runi, prewn, postw, scal);
  k_wreg<<<128, 256, 0, stream>>>(W, scal);
  k_combine<<<1, 512, 0, stream>>>(mu_t, colsum, scal, out);
}